// Round 12
// baseline (208.916 us; speedup 1.0000x reference)
//
#include <hip/hip_runtime.h>

// SBSM block: B=2, C=48, H=W=64, L=4096, DI=96, DS=16, DCONV=4, DTR=3, HF=96
#define DEV __device__ __forceinline__

DEV float siluf(float x){ return x / (1.f + __expf(-x)); }
DEV float softplusf(float x){ return fmaxf(x, 0.f) + log1pf(expf(-fabsf(x))); }
DEV float geluf(float x){ return 0.5f * x * (1.f + erff(x * 0.70710678118654752440f)); }

// ---------------- kA: snake gather + LN(n1) + posenc(inline) + LN(mln) -> Vg(48) ; inproj xm-half -> xmg(96)
__global__ __launch_bounds__(256) void kA_front(const float* __restrict__ x,
    const float* __restrict__ n1w, const float* __restrict__ n1b,
    const float* __restrict__ mw0, const float* __restrict__ mb0,
    const float* __restrict__ mw1, const float* __restrict__ mb1,
    const float* __restrict__ ip0, const float* __restrict__ ip1,
    float* __restrict__ xmg, float* __restrict__ Vg){
  __shared__ alignas(16) float Vl[48*36];   // [c][r]
  __shared__ float Wt[48*97];               // transposed inproj xm-half
  __shared__ float mu_s[32], rs_s[32];
  int bd = blockIdx.x >> 7, tile = blockIdx.x & 127;
  int dir = bd >> 1, b = bd & 1;
  int t0 = tile*32;
  int tid = threadIdx.x;
  const float* ip = dir ? ip1 : ip0;
  const float* mw = dir ? mw1 : mw0;
  const float* mb = dir ? mb1 : mb0;
  for (int i = tid; i < 96*48; i += 256){
    int j = i / 48, c = i % 48;
    Wt[c*97 + j] = ip[i];
  }
  for (int i = tid; i < 48*32; i += 256){
    int c = i >> 5, r = i & 31;
    int t = t0 + r;
    int h, w;
    if (dir == 0){ h = t >> 6; int wp = t & 63; w = (h & 1) ? 63 - wp : wp; }
    else         { w = t >> 6; int hp = t & 63; h = (w & 1) ? 63 - hp : hp; }
    Vl[c*36 + r] = x[(size_t)b*48*4096 + c*4096 + h*64 + w];
  }
  __syncthreads();
  {
    int r = tid >> 3, k = tid & 7;
    float s1 = 0.f, s2 = 0.f;
    #pragma unroll
    for (int cc = 0; cc < 6; cc++){
      float v = Vl[(k*6+cc)*36 + r];
      s1 += v; s2 += v*v;
    }
    s1 += __shfl_xor(s1,1); s2 += __shfl_xor(s2,1);
    s1 += __shfl_xor(s1,2); s2 += __shfl_xor(s2,2);
    s1 += __shfl_xor(s1,4); s2 += __shfl_xor(s2,4);
    if (k == 0){
      float m = s1*(1.f/48.f);
      mu_s[r] = m;
      rs_s[r] = rsqrtf(s2*(1.f/48.f) - m*m + 1e-5f);
    }
  }
  __syncthreads();
  for (int i = tid; i < 32*48; i += 256){
    int r = i / 48, c = i % 48;
    int t = t0 + r;
    float v = Vl[c*36 + r];
    float xn = (v - mu_s[r])*rs_s[r]*n1w[c] + n1b[c];
    float ang = (float)t * __expf(-(float)(c & ~1) * (9.210340371976184f/48.f));
    float pe = (c & 1) ? cosf(ang) : sinf(ang);
    Vl[c*36 + r] = xn + pe;
  }
  __syncthreads();
  {
    int r = tid >> 3, k = tid & 7;
    float s1 = 0.f, s2 = 0.f;
    #pragma unroll
    for (int cc = 0; cc < 6; cc++){
      float v = Vl[(k*6+cc)*36 + r];
      s1 += v; s2 += v*v;
    }
    s1 += __shfl_xor(s1,1); s2 += __shfl_xor(s2,1);
    s1 += __shfl_xor(s1,2); s2 += __shfl_xor(s2,2);
    s1 += __shfl_xor(s1,4); s2 += __shfl_xor(s2,4);
    if (k == 0){
      float m = s1*(1.f/48.f);
      mu_s[r] = m;
      rs_s[r] = rsqrtf(s2*(1.f/48.f) - m*m + 1e-5f);
    }
  }
  __syncthreads();
  for (int i = tid; i < 32*48; i += 256){
    int r = i / 48, c = i % 48;
    float v = Vl[c*36 + r];
    float v2 = (v - mu_s[r])*rs_s[r]*mw[c] + mb[c];
    Vl[c*36 + r] = v2;
    Vg[((size_t)bd*4096 + t0 + r)*48 + c] = v2;
  }
  __syncthreads();
  for (int k = 0; k < 3; k++){
    int i = tid + k*256;
    int j = i % 96, rb = i / 96;
    float a0=0.f, a1=0.f, a2=0.f, a3=0.f;
    #pragma unroll 4
    for (int c = 0; c < 48; c++){
      float wv = Wt[c*97 + j];
      const float4 v4 = *(const float4*)&Vl[c*36 + rb*4];
      a0 += wv*v4.x; a1 += wv*v4.y; a2 += wv*v4.z; a3 += wv*v4.w;
    }
    size_t g = ((size_t)bd*4096 + t0 + rb*4)*96 + j;
    xmg[g] = a0; xmg[g+96] = a1; xmg[g+192] = a2; xmg[g+288] = a3;
  }
}

// ---------------- kB: causal conv4+silu + xproj + dt/B/C + scan pass-1 (chunk=32)
__global__ __launch_bounds__(384) void kB_convscan(const float* __restrict__ xmg,
    const float* __restrict__ cwp0, const float* __restrict__ cwp1,
    const float* __restrict__ cbp0, const float* __restrict__ cbp1,
    const float* __restrict__ xpp0, const float* __restrict__ xpp1,
    const float* __restrict__ dwp0, const float* __restrict__ dwp1,
    const float* __restrict__ dbp0, const float* __restrict__ dbp1,
    const float* __restrict__ Alog0, const float* __restrict__ Alog1,
    float* __restrict__ xcg, float* __restrict__ dtg,
    float* __restrict__ Bmg, float* __restrict__ Cmg,
    float* __restrict__ P, float* __restrict__ S){
  __shared__ union UB {
    float xml[96*36];                               // [d][tl] tl 0..34 (3 halo)
    struct { float xwl[35*96]; float xdbl[35*33]; } p;
  } ub;
  __shared__ float xcl[96*33];
  __shared__ float dtl[96*33];
  __shared__ alignas(16) float Bl[32*16], Cl[32*16];
  __shared__ float cw[96*4], cbv[96], dwl[96*3], dbl[96];
  int bd = blockIdx.x >> 7, tile = blockIdx.x & 127;
  int dir = bd >> 1;
  int t0 = tile*32;
  int tid = threadIdx.x;
  const float* cwp = dir ? cwp1 : cwp0;
  const float* cbp = dir ? cbp1 : cbp0;
  const float* xpp = dir ? xpp1 : xpp0;
  const float* dwp = dir ? dwp1 : dwp0;
  const float* dbp = dir ? dbp1 : dbp0;
  const float* Alog = dir ? Alog1 : Alog0;
  for (int i = tid; i < 35*96; i += 384){
    int tl = i / 96, d = i % 96;
    int t = t0 - 3 + tl;
    ub.xml[d*36 + tl] = (t >= 0) ? xmg[((size_t)bd*4096 + t)*96 + d] : 0.f;
  }
  for (int i = tid; i < 96*4;  i += 384) cw[i] = cwp[i];
  for (int i = tid; i < 96*3;  i += 384) dwl[i] = dwp[i];
  for (int i = tid; i < 96;    i += 384){ cbv[i] = cbp[i]; dbl[i] = dbp[i]; }
  __syncthreads();
  for (int i = tid; i < 96*32; i += 384){
    int d = i >> 5, t = i & 31;
    float acc = cbv[d];
    #pragma unroll
    for (int k = 0; k < 4; k++) acc += cw[d*4+k]*ub.xml[d*36 + t + k];
    xcl[d*33 + t] = siluf(acc);
  }
  __syncthreads();
  for (int i = tid; i < 35*96; i += 384) ub.p.xwl[i] = xpp[i];
  __syncthreads();
  for (int i = tid; i < 35*32; i += 384){
    int j = i / 32, t = i % 32;
    float acc = 0.f;
    #pragma unroll 4
    for (int d = 0; d < 96; d++) acc += xcl[d*33 + t]*ub.p.xwl[j*96 + d];
    ub.p.xdbl[j*33 + t] = acc;
  }
  __syncthreads();
  for (int i = tid; i < 96*32; i += 384){
    int d = i >> 5, t = i & 31;
    float v = dbl[d];
    #pragma unroll
    for (int r = 0; r < 3; r++) v += ub.p.xdbl[r*33 + t]*dwl[d*3 + r];
    dtl[d*33 + t] = softplusf(v);
  }
  for (int i = tid; i < 32*16; i += 384){
    int t = i / 16, s = i % 16;
    Bl[t*16 + s] = ub.p.xdbl[(3+s)*33 + t];
    Cl[t*16 + s] = ub.p.xdbl[(19+s)*33 + t];
  }
  __syncthreads();
  for (int i = tid; i < 32*96; i += 384){
    int t = i / 96, d = i % 96;
    size_t g = ((size_t)bd*4096 + t0 + t)*96 + d;
    xcg[g] = xcl[d*33 + t];
    dtg[g] = dtl[d*33 + t];
  }
  for (int i = tid; i < 32*16; i += 384){
    int t = i / 16, s = i % 16;
    size_t g = ((size_t)bd*4096 + t0 + t)*16 + s;
    Bmg[g] = Bl[t*16 + s];
    Cmg[g] = Cl[t*16 + s];
  }
  {
    int d = tid >> 2, q = tid & 3;
    float A0 = -__expf(Alog[d*16 + q*4 + 0]);
    float A1 = -__expf(Alog[d*16 + q*4 + 1]);
    float A2 = -__expf(Alog[d*16 + q*4 + 2]);
    float A3 = -__expf(Alog[d*16 + q*4 + 3]);
    float h0=0.f,h1=0.f,h2=0.f,h3=0.f, p0=1.f,p1=1.f,p2=1.f,p3=1.f;
    #pragma unroll 4
    for (int t = 0; t < 32; t++){
      float dtd = dtl[d*33 + t];
      float u = dtd * xcl[d*33 + t];
      const float4 b4 = *(const float4*)&Bl[t*16 + q*4];
      float a0 = __expf(dtd*A0), a1 = __expf(dtd*A1), a2 = __expf(dtd*A2), a3 = __expf(dtd*A3);
      h0 = a0*h0 + u*b4.x; p0 *= a0;
      h1 = a1*h1 + u*b4.y; p1 *= a1;
      h2 = a2*h2 + u*b4.z; p2 *= a2;
      h3 = a3*h3 + u*b4.w; p3 *= a3;
    }
    size_t ob = (size_t)blockIdx.x*1536 + d*16 + q*4;
    *(float4*)&P[ob] = make_float4(p0,p1,p2,p3);
    *(float4*)&S[ob] = make_float4(h0,h1,h2,h3);
  }
}

// ---------------- k4: sequential chunk combine over 128 chunks, IN PLACE (Hin = P).
__global__ __launch_bounds__(256) void k4_comb(float* __restrict__ P, const float* __restrict__ S){
  int tid2 = blockIdx.x*256 + threadIdx.x;   // 6144 lanes
  int bd = tid2 / 1536, r = tid2 % 1536;
  size_t idx = (size_t)bd*128*1536 + r;
  const int ST = 1536;
  float pb0,pb1,pb2,pb3,pb4,pb5,pb6,pb7, sb0,sb1,sb2,sb3,sb4,sb5,sb6,sb7;
  pb0=P[idx+0*ST]; sb0=S[idx+0*ST]; pb1=P[idx+1*ST]; sb1=S[idx+1*ST];
  pb2=P[idx+2*ST]; sb2=S[idx+2*ST]; pb3=P[idx+3*ST]; sb3=S[idx+3*ST];
  pb4=P[idx+4*ST]; sb4=S[idx+4*ST]; pb5=P[idx+5*ST]; sb5=S[idx+5*ST];
  pb6=P[idx+6*ST]; sb6=S[idx+6*ST]; pb7=P[idx+7*ST]; sb7=S[idx+7*ST];
  float h = 0.f;
  for (int c0 = 0; c0 < 128; c0 += 8){
    float pn0=0,sn0=0,pn1=0,sn1=0,pn2=0,sn2=0,pn3=0,sn3=0;
    float pn4=0,sn4=0,pn5=0,sn5=0,pn6=0,sn6=0,pn7=0,sn7=0;
    if (c0 + 8 < 128){
      pn0=P[idx+(size_t)(c0+8)*ST];  sn0=S[idx+(size_t)(c0+8)*ST];
      pn1=P[idx+(size_t)(c0+9)*ST];  sn1=S[idx+(size_t)(c0+9)*ST];
      pn2=P[idx+(size_t)(c0+10)*ST]; sn2=S[idx+(size_t)(c0+10)*ST];
      pn3=P[idx+(size_t)(c0+11)*ST]; sn3=S[idx+(size_t)(c0+11)*ST];
      pn4=P[idx+(size_t)(c0+12)*ST]; sn4=S[idx+(size_t)(c0+12)*ST];
      pn5=P[idx+(size_t)(c0+13)*ST]; sn5=S[idx+(size_t)(c0+13)*ST];
      pn6=P[idx+(size_t)(c0+14)*ST]; sn6=S[idx+(size_t)(c0+14)*ST];
      pn7=P[idx+(size_t)(c0+15)*ST]; sn7=S[idx+(size_t)(c0+15)*ST];
    }
    P[idx+(size_t)(c0+0)*ST] = h; h = pb0*h + sb0;
    P[idx+(size_t)(c0+1)*ST] = h; h = pb1*h + sb1;
    P[idx+(size_t)(c0+2)*ST] = h; h = pb2*h + sb2;
    P[idx+(size_t)(c0+3)*ST] = h; h = pb3*h + sb3;
    P[idx+(size_t)(c0+4)*ST] = h; h = pb4*h + sb4;
    P[idx+(size_t)(c0+5)*ST] = h; h = pb5*h + sb5;
    P[idx+(size_t)(c0+6)*ST] = h; h = pb6*h + sb6;
    P[idx+(size_t)(c0+7)*ST] = h; h = pb7*h + sb7;
    pb0=pn0;sb0=sn0;pb1=pn1;sb1=sn1;pb2=pn2;sb2=sn2;pb3=pn3;sb3=sn3;
    pb4=pn4;sb4=sn4;pb5=pn5;sb5=sn5;pb6=pn6;sb6=sn6;pb7=pn7;sb7=sn7;
  }
}

// ---------------- k5: pass-3 rescan (+D term) -> yl ; then z GEMV + gate, LDS phase-union.
__global__ __launch_bounds__(384) void k5_scan2(const float* __restrict__ dtg,
    const float* __restrict__ xcg, const float* __restrict__ Bmg, const float* __restrict__ Cmg,
    const float* __restrict__ Alog0, const float* __restrict__ Alog1,
    const float* __restrict__ Dp0, const float* __restrict__ Dp1,
    const float* __restrict__ ip0, const float* __restrict__ ip1,
    const float* __restrict__ Vg, const float* __restrict__ Hin, float* __restrict__ yout){
  __shared__ union U5 {
    struct { float dts[32*96]; float xcs[32*96]; } s;   // scan phase
    struct { float Wzt[48*96]; float Vgs[32*48]; } e;   // epilogue phase
  } u;
  __shared__ alignas(16) float Bl[32*16], Cl[32*16];
  __shared__ float yl[32*96];
  int task = blockIdx.x;
  int bd = task >> 7, ch = task & 127;
  int t0 = ch*32;
  int tid = threadIdx.x;
  const float* ip   = (bd >= 2) ? ip1 : ip0;
  const float* Alog = (bd >= 2) ? Alog1 : Alog0;
  const float* Dp   = (bd >= 2) ? Dp1 : Dp0;
  for (int i = tid; i < 32*96; i += 384){
    int t = i / 96, dd = i % 96;
    size_t g = ((size_t)bd*4096 + t0 + t)*96 + dd;
    u.s.dts[i] = dtg[g];
    u.s.xcs[i] = xcg[g];
  }
  for (int i = tid; i < 32*16; i += 384){
    size_t g = ((size_t)bd*4096 + t0)*16 + i;
    Bl[i] = Bmg[g];
    Cl[i] = Cmg[g];
  }
  __syncthreads();
  {
    int d = tid >> 2, q = tid & 3;
    float A0 = -__expf(Alog[d*16 + q*4 + 0]);
    float A1 = -__expf(Alog[d*16 + q*4 + 1]);
    float A2 = -__expf(Alog[d*16 + q*4 + 2]);
    float A3 = -__expf(Alog[d*16 + q*4 + 3]);
    float Dd = Dp[d];
    const float4 h4 = *(const float4*)&Hin[(size_t)task*1536 + d*16 + q*4];
    float h0 = h4.x, h1 = h4.y, h2 = h4.z, h3 = h4.w;
    for (int t = 0; t < 32; t += 2){
      float dtdA = u.s.dts[t*96 + d];
      float xcvA = u.s.xcs[t*96 + d];
      float dtdB = u.s.dts[(t+1)*96 + d];
      float xcvB = u.s.xcs[(t+1)*96 + d];
      float uA = dtdA * xcvA, uB = dtdB * xcvB;
      const float4 b4A = *(const float4*)&Bl[t*16 + q*4];
      const float4 c4A = *(const float4*)&Cl[t*16 + q*4];
      const float4 b4B = *(const float4*)&Bl[(t+1)*16 + q*4];
      const float4 c4B = *(const float4*)&Cl[(t+1)*16 + q*4];
      float a0 = __expf(dtdA*A0), a1 = __expf(dtdA*A1), a2 = __expf(dtdA*A2), a3 = __expf(dtdA*A3);
      float e0 = __expf(dtdB*A0), e1 = __expf(dtdB*A1), e2 = __expf(dtdB*A2), e3 = __expf(dtdB*A3);
      h0 = a0*h0 + uA*b4A.x;
      h1 = a1*h1 + uA*b4A.y;
      h2 = a2*h2 + uA*b4A.z;
      h3 = a3*h3 + uA*b4A.w;
      float pyA = (h0*c4A.x + h1*c4A.y) + (h2*c4A.z + h3*c4A.w);
      h0 = e0*h0 + uB*b4B.x;
      h1 = e1*h1 + uB*b4B.y;
      h2 = e2*h2 + uB*b4B.z;
      h3 = e3*h3 + uB*b4B.w;
      float pyB = (h0*c4B.x + h1*c4B.y) + (h2*c4B.z + h3*c4B.w);
      pyA += __shfl_xor(pyA, 1);  pyB += __shfl_xor(pyB, 1);
      pyA += __shfl_xor(pyA, 2);  pyB += __shfl_xor(pyB, 2);
      if (q == 0){
        yl[t*96 + d]     = pyA + xcvA*Dd;
        yl[(t+1)*96 + d] = pyB + xcvB*Dd;
      }
    }
  }
  __syncthreads();
  for (int i = tid; i < 96*48; i += 384){
    int j = i % 96, c = i / 96;
    u.e.Wzt[c*96 + j] = ip[(96 + j)*48 + c];
  }
  for (int i = tid; i < 32*48; i += 384){
    int t = i / 48, c = i % 48;
    u.e.Vgs[i] = Vg[((size_t)bd*4096 + t0 + t)*48 + c];
  }
  __syncthreads();
  for (int i = tid; i < 32*96; i += 384){
    int t = i / 96, dd = i % 96;
    float z = 0.f;
    #pragma unroll 4
    for (int c = 0; c < 48; c++) z += u.e.Wzt[c*96 + dd] * u.e.Vgs[t*48 + c];
    size_t g = ((size_t)bd*4096 + t0 + t)*96 + dd;
    yout[g] = yl[i] * siluf(z);
  }
}

// ---------------- k67: w-split 16 (512 blocks x 384 thr): un-snake + outproj + residual -> xmid ; LN(n2)+pin -> xp
__global__ __launch_bounds__(384) void k67_mid(const float* __restrict__ x,
    const float* __restrict__ y1, const float* __restrict__ y2,
    const float* __restrict__ op1, const float* __restrict__ op2,
    const float* __restrict__ nw, const float* __restrict__ nb,
    const float* __restrict__ pin,
    float* __restrict__ xmid, float* __restrict__ xp){
  __shared__ float bufW[192*49];        // op view: [48][97]; pin view: [192][49]
  __shared__ union UL { float ylds[16*97]; struct { float xl[48*17]; float mu[16]; float rs[16]; } l; } ul;
  int bid = blockIdx.x;                 // b*256 + h*4 + wq
  int b = bid >> 8, h = (bid >> 2) & 63, wq = bid & 3;
  int w0 = wq << 4;
  int tid = threadIdx.x;
  int w = tid & 15, cg = tid >> 4;      // cg 0..23, 2 channels each
  float acc0 = 0.f, acc1 = 0.f;
  for (int pass = 0; pass < 2; pass++){
    __syncthreads();
    const float* op = pass ? op2 : op1;
    const float* y  = pass ? y2  : y1;
    for (int i = tid; i < 48*96; i += 384){
      int c = i / 96, d = i % 96;
      bufW[c*97 + d] = op[i];
    }
    if (pass == 0){
      for (int i = tid; i < 16*96; i += 384){
        int wl_ = i / 96, d = i % 96;
        int wsp = w0 + wl_;
        int wp = (h & 1) ? 63 - wsp : wsp;
        ul.ylds[wl_*97 + d] = y[((size_t)b*4096 + h*64 + wp)*96 + d];
      }
    } else {
      for (int i = tid; i < 16*96; i += 384){
        int wl_ = i / 96, d = i % 96;
        int wsp = w0 + wl_;
        int t = wsp*64 + ((wsp & 1) ? 63 - h : h);
        ul.ylds[wl_*97 + d] = y[((size_t)b*4096 + t)*96 + d];
      }
    }
    __syncthreads();
    #pragma unroll 4
    for (int d = 0; d < 96; d++){
      float yv = ul.ylds[w*97 + d];
      acc0 += yv * bufW[(cg*2+0)*97 + d];
      acc1 += yv * bufW[(cg*2+1)*97 + d];
    }
  }
  __syncthreads();   // GEMVs done: safe to overwrite ylds and bufW
  {
    int c0 = cg*2;
    size_t idx0 = (((size_t)b*48 + c0)*64 + h)*64 + w0 + w;
    float v0 = x[idx0] + acc0;
    xmid[idx0] = v0;
    ul.l.xl[c0*17 + w] = v0;
    size_t idx1 = idx0 + 4096;
    float v1 = x[idx1] + acc1;
    xmid[idx1] = v1;
    ul.l.xl[(c0+1)*17 + w] = v1;
  }
  for (int i = tid; i < 192*48; i += 384){
    int r = i / 48, c = i % 48;
    bufW[r*49 + c] = pin[i];
  }
  __syncthreads();
  if (tid < 128){
    int r = tid >> 3, k = tid & 7;
    float s1 = 0.f, s2 = 0.f;
    #pragma unroll
    for (int cc = 0; cc < 6; cc++){
      float v = ul.l.xl[(k*6+cc)*17 + r];
      s1 += v; s2 += v*v;
    }
    s1 += __shfl_xor(s1,1); s2 += __shfl_xor(s2,1);
    s1 += __shfl_xor(s1,2); s2 += __shfl_xor(s2,2);
    s1 += __shfl_xor(s1,4); s2 += __shfl_xor(s2,4);
    if (k == 0){
      float m = s1*(1.f/48.f);
      ul.l.mu[r] = m;
      ul.l.rs[r] = rsqrtf(s2*(1.f/48.f) - m*m + 1e-5f);
    }
  }
  __syncthreads();
  for (int i = tid; i < 48*16; i += 384){
    int c = i >> 4, ww = i & 15;
    ul.l.xl[c*17 + ww] = (ul.l.xl[c*17 + ww] - ul.l.mu[ww])*ul.l.rs[ww]*nw[c] + nb[c];
  }
  __syncthreads();
  for (int it = 0; it < 2; it++){
    int i = tid + it*384;
    int ww = i & 15, oq = i >> 4;   // oq 0..47
    int o0 = oq*4;
    float a0=0,a1=0,a2=0,a3=0;
    #pragma unroll 4
    for (int c = 0; c < 48; c++){
      float xv = ul.l.xl[c*17 + ww];
      a0 += xv*bufW[(o0+0)*49 + c];
      a1 += xv*bufW[(o0+1)*49 + c];
      a2 += xv*bufW[(o0+2)*49 + c];
      a3 += xv*bufW[(o0+3)*49 + c];
    }
    xp[(((size_t)b*192 + o0+0)*64 + h)*64 + w0 + ww] = a0;
    xp[(((size_t)b*192 + o0+1)*64 + h)*64 + w0 + ww] = a1;
    xp[(((size_t)b*192 + o0+2)*64 + h)*64 + w0 + ww] = a2;
    xp[(((size_t)b*192 + o0+3)*64 + h)*64 + w0 + ww] = a3;
  }
}

// ---------------- K9: 3x3 conv 48->48 on 32x32, out-channel quarters.
// pooled=1: input is (B,48,64,64), 2x2-avg-pool inline.  lnin=1: apply LN(lnw,lnb)+ReLU to staged input.
__global__ __launch_bounds__(384) void k9_conv3(const float* __restrict__ in,
    const float* __restrict__ wgt, const float* __restrict__ bias,
    const float* __restrict__ lnw, const float* __restrict__ lnb,
    float* __restrict__ out, int pooled, int lnin){
  __shared__ float wl[12*48*9];      // 20.7 KB
  __shared__ float sin_[48*3*34];    // 19.6 KB
  __shared__ float mu_i[104], rs_i[104];
  int bid = blockIdx.x;
  int cq = bid & 3, i0 = (bid >> 2) & 31, b = bid >> 7;
  int tid = threadIdx.x;
  for (int i = tid; i < 12*48*9; i += 384) wl[i] = wgt[cq*12*48*9 + i];
  for (int i = tid; i < 48*3*34; i += 384){
    int jx = i % 34, ky = (i/34) % 3, ci = i/102;
    int r = i0 + ky - 1, j = jx - 1;
    float v = 0.f;
    if (r >= 0 && r < 32 && j >= 0 && j < 32){
      if (pooled){
        const float* xb = in + (((size_t)b*48 + ci)*64 + 2*r)*64 + 2*j;
        v = 0.25f*(xb[0] + xb[1] + xb[64] + xb[65]);
      } else {
        v = in[(((size_t)b*48 + ci)*32 + r)*32 + j];
      }
    }
    sin_[i] = v;
  }
  __syncthreads();
  if (lnin){
    if (tid < 102){
      int jx = tid % 34, ky = tid / 34;
      int r = i0 + ky - 1, j = jx - 1;
      if (r >= 0 && r < 32 && j >= 0 && j < 32){
        float s1 = 0.f, s2 = 0.f;
        #pragma unroll 4
        for (int ci = 0; ci < 48; ci++){ float v = sin_[ci*102 + tid]; s1 += v; s2 += v*v; }
        float m = s1*(1.f/48.f);
        mu_i[tid] = m;
        rs_i[tid] = rsqrtf(s2*(1.f/48.f) - m*m + 1e-5f);
      }
    }
    __syncthreads();
    for (int i = tid; i < 48*102; i += 384){
      int ci = i / 102, p = i % 102;
      int jx = p % 34, ky = p / 34;
      int r = i0 + ky - 1, j = jx - 1;
      if (r >= 0 && r < 32 && j >= 0 && j < 32){
        float v = (sin_[i] - mu_i[p])*rs_i[p]*lnw[ci] + lnb[ci];
        sin_[i] = fmaxf(v, 0.f);
      }
    }
    __syncthreads();
  }
  int j = tid & 31, col = tid >> 5;    // col 0..11
  float acc = bias[cq*12 + col];
  for (int ci = 0; ci < 48; ci++){
    const float* wp = wl + ((size_t)col*48 + ci)*9;
    const float* sp = sin_ + ci*102;
    #pragma unroll
    for (int ky = 0; ky < 3; ky++)
      #pragma unroll
      for (int kx = 0; kx < 3; kx++)
        acc += sp[ky*34 + j + kx] * wp[ky*3 + kx];
  }
  out[(((size_t)b*48 + cq*12 + col)*32 + i0)*32 + j] = acc;
}

// ---------------- K14: w-split 16 (1024 blocks x 256 thr): inline dw(xp ch0..95) + LN/ReLU(conv2)
//                  + 1x1 f_fus GEMV -> x1 (oh half of 96 ch)
__global__ __launch_bounds__(256) void k14_fus(const float* __restrict__ xp,
    const float* __restrict__ cv2, const float* __restrict__ lnw, const float* __restrict__ lnb,
    const float* __restrict__ dww, const float* __restrict__ fus, float* __restrict__ x1){
  __shared__ float wl[48*145];     // padded fus weights
  __shared__ float xps[96*54];     // xp ch0..95, rows h-1..h+1, cols w0-1..w0+16
  __shared__ float dwl[96*9];
  __shared__ float ylq[48*9];      // conv2 cols j0..j0+7, pad 9
  __shared__ float gl[96*17];
  __shared__ float muy[8], rsy[8];
  int bid = blockIdx.x;            // ((b*2 + oh)*64 + h)*4 + wq
  int wq = bid & 3, h = (bid >> 2) & 63, oh = (bid >> 8) & 1, b = bid >> 9;
  int w0 = wq << 4;
  int tid = threadIdx.x;
  for (int i = tid; i < 48*144; i += 256){
    int r = i / 144, c = i % 144;
    wl[r*145 + c] = fus[(size_t)oh*48*144 + i];
  }
  for (int i = tid; i < 96*9; i += 256) dwl[i] = dww[i];
  for (int i = tid; i < 96*54; i += 256){
    int jx = i % 18, ky = (i/18) % 3, ci = i/54;
    int hh = h + ky - 1, ww_ = w0 + jx - 1;
    float v = 0.f;
    if (hh >= 0 && hh < 64 && ww_ >= 0 && ww_ < 64)
      v = xp[(((size_t)b*192 + ci)*64 + hh)*64 + ww_];
    xps[i] = v;
  }
  {
    int hp = h >> 1, j0 = w0 >> 1;
    for (int i = tid; i < 48*8; i += 256){
      int cj = i >> 3, jl = i & 7;
      ylq[cj*9 + jl] = cv2[(((size_t)b*48 + cj)*32 + hp)*32 + j0 + jl];
    }
  }
  __syncthreads();
  if (tid < 8){
    float s1 = 0.f, s2 = 0.f;
    #pragma unroll 4
    for (int cj = 0; cj < 48; cj++){ float v = ylq[cj*9 + tid]; s1 += v; s2 += v*v; }
    float m = s1*(1.f/48.f);
    muy[tid] = m;
    rsy[tid] = rsqrtf(s2*(1.f/48.f) - m*m + 1e-5f);
  }
  for (int i = tid; i < 96*16; i += 256){
    int ci = i >> 4, ww = i & 15;
    const float* wp = dwl + ci*9;
    const float* sp = xps + ci*54;
    float a = 0.f;
    #pragma unroll
    for (int ky = 0; ky < 3; ky++)
      #pragma unroll
      for (int kx = 0; kx < 3; kx++)
        a += sp[ky*18 + ww + kx] * wp[ky*3 + kx];
    gl[ci*17 + ww] = a;
  }
  __syncthreads();
  for (int i = tid; i < 48*8; i += 256){
    int cj = i >> 3, jl = i & 7;
    ylq[cj*9 + jl] = fmaxf((ylq[cj*9 + jl] - muy[jl])*rsy[jl]*lnw[cj] + lnb[cj], 0.f);
  }
  __syncthreads();
  for (int it = 0; it < 3; it++){
    int i = tid + it*256;
    int ww = i & 15, o = i >> 4;   // o 0..47
    float a = 0.f;
    #pragma unroll 4
    for (int ci = 0; ci < 96; ci++) a += gl[ci*17 + ww] * wl[o*145 + ci];
    int jl = ww >> 1;
    #pragma unroll 4
    for (int cj = 0; cj < 48; cj++) a += ylq[cj*9 + jl] * wl[o*145 + 96 + cj];
    x1[(((size_t)b*96 + oh*48 + o)*64 + h)*64 + w0 + ww] = a;
  }
}

// ---------------- K16: w-split 16 (512 blocks x 384 thr): inline dwa(x1) AND dw(xp ch96..191)
//                  -> gelu*x2 -> pout GEMV -> + xmid -> out
__global__ __launch_bounds__(384) void k16_out(const float* __restrict__ x1,
    const float* __restrict__ xp, const float* __restrict__ dwa, const float* __restrict__ dwf2,
    const float* __restrict__ pout, const float* __restrict__ xmid, float* __restrict__ out){
  __shared__ float wl[48*97];        // padded pout
  __shared__ float xs[96*54];        // x1 halo
  __shared__ float xs2[96*54];       // xp ch96..191 halo
  __shared__ float gl[96*17];
  __shared__ float dwl[96*9], dwl2[96*9];
  int bid = blockIdx.x;              // b*256 + h*4 + wq
  int b = bid >> 8, h = (bid >> 2) & 63, wq = bid & 3;
  int w0 = wq << 4;
  int tid = threadIdx.x;
  for (int i = tid; i < 48*96; i += 384){
    int r = i / 96, c = i % 96;
    wl[r*97 + c] = pout[i];
  }
  for (int i = tid; i < 96*9; i += 384){ dwl[i] = dwa[i]; dwl2[i] = dwf2[i]; }
  for (int i = tid; i < 96*54; i += 384){
    int jx = i % 18, ky = (i/18) % 3, ch = i/54;
    int hh = h + ky - 1, ww_ = w0 + jx - 1;
    float v1 = 0.f, v2 = 0.f;
    if (hh >= 0 && hh < 64 && ww_ >= 0 && ww_ < 64){
      v1 = x1[(((size_t)b*96 + ch)*64 + hh)*64 + ww_];
      v2 = xp[(((size_t)b*192 + 96 + ch)*64 + hh)*64 + ww_];
    }
    xs[i] = v1;
    xs2[i] = v2;
  }
  __syncthreads();
  for (int i = tid; i < 96*16; i += 384){
    int ch = i >> 4, ww = i & 15;
    const float* wp = dwl + ch*9;
    const float* sp = xs + ch*54;
    const float* wp2 = dwl2 + ch*9;
    const float* sp2 = xs2 + ch*54;
    float a = 0.f, x2 = 0.f;
    #pragma unroll
    for (int ky = 0; ky < 3; ky++)
      #pragma unroll
      for (int kx = 0; kx < 3; kx++){
        a  += sp [ky*18 + ww + kx] * wp [ky*3 + kx];
        x2 += sp2[ky*18 + ww + kx] * wp2[ky*3 + kx];
      }
    gl[ch*17 + ww] = geluf(a) * x2;
  }
  __syncthreads();
  int ww = tid & 15, cg = tid >> 4;  // cg 0..23, 2 channels each
  float a0=0.f, a1=0.f;
  #pragma unroll 4
  for (int ch = 0; ch < 96; ch++){
    float gv = gl[ch*17 + ww];
    a0 += gv * wl[(cg*2+0)*97 + ch];
    a1 += gv * wl[(cg*2+1)*97 + ch];
  }
  {
    int c0 = cg*2;
    size_t idx0 = (((size_t)b*48 + c0)*64 + h)*64 + w0 + ww;
    out[idx0] = xmid[idx0] + a0;
    size_t idx1 = idx0 + 4096;
    out[idx1] = xmid[idx1] + a1;
  }
}

extern "C" void kernel_launch(void* const* d_in, const int* in_sizes, int n_in,
                              void* d_out, int out_size, void* d_ws, size_t ws_size,
                              hipStream_t stream){
  (void)in_sizes; (void)n_in; (void)out_size; (void)ws_size;
  const float* x    = (const float*)d_in[0];
  const float* n1w  = (const float*)d_in[1];
  const float* n1b  = (const float*)d_in[2];
  const float* n2w  = (const float*)d_in[3];
  const float* n2b  = (const float*)d_in[4];
  const float* mlnw[2] = {(const float*)d_in[5], (const float*)d_in[7]};
  const float* mlnb[2] = {(const float*)d_in[6], (const float*)d_in[8]};
  const float* fln1w = (const float*)d_in[9];
  const float* fln1b = (const float*)d_in[10];
  const float* fln2w = (const float*)d_in[11];
  const float* fln2b = (const float*)d_in[12];
  const float* inproj[2]  = {(const float*)d_in[13], (const float*)d_in[22]};
  const float* convw[2]   = {(const float*)d_in[14], (const float*)d_in[23]};
  const float* convb[2]   = {(const float*)d_in[15], (const float*)d_in[24]};
  const float* xproj[2]   = {(const float*)d_in[16], (const float*)d_in[25]};
  const float* dtw[2]     = {(const float*)d_in[17], (const float*)d_in[26]};
  const float* dtbp[2]    = {(const float*)d_in[18], (const float*)d_in[27]};
  const float* Alog[2]    = {(const float*)d_in[19], (const float*)d_in[28]};
  const float* Dp[2]      = {(const float*)d_in[20], (const float*)d_in[29]};
  const float* outproj[2] = {(const float*)d_in[21], (const float*)d_in[30]};
  const float* fpin  = (const float*)d_in[31];
  const float* fdw   = (const float*)d_in[32];
  const float* ffus  = (const float*)d_in[33];
  const float* fdwa  = (const float*)d_in[34];
  const float* fpout = (const float*)d_in[35];
  const float* fc1w  = (const float*)d_in[36];
  const float* fc1b  = (const float*)d_in[37];
  const float* fc2w  = (const float*)d_in[38];
  const float* fc2b  = (const float*)d_in[39];

  // workspace (floats), total 7,995,392 (= 32.0 MB)
  float* ws = (float*)d_ws;
  float* xmg = ws + 0;         // (4,4096,96)  -> later yall
  float* Vgb = ws + 1572864;   // (4,4096,48)
  float* xcg = ws + 2359296;   // (4,4096,96)  -> later xpb (B,192,64,64)
  float* dtg = ws + 3932160;   // (4,4096,96)
  float* Bmg = ws + 5505024;   // (4,4096,16)
  float* Cmg = ws + 5767168;   // (4,4096,16)
  float* Pb  = ws + 6029312;   // (512,1536)   -> Hin in-place, later x1b
  float* Sb  = ws + 6815744;   // (512,1536)   -> later pool bufs
  float* xmid= ws + 7602176;   // (B,48,64,64)
  float* yall = xmg;
  float* Hin  = Pb;
  float* ta   = Sb;            // conv1 raw out
  float* tbuf = Sb + 98304;    // conv2 raw out
  float* xpb  = xcg;
  float* x1b  = Pb;

  kA_front<<<512,256,0,stream>>>(x, n1w, n1b,
      mlnw[0], mlnb[0], mlnw[1], mlnb[1], inproj[0], inproj[1], xmg, Vgb);
  kB_convscan<<<512,384,0,stream>>>(xmg,
      convw[0], convw[1], convb[0], convb[1], xproj[0], xproj[1],
      dtw[0], dtw[1], dtbp[0], dtbp[1], Alog[0], Alog[1],
      xcg, dtg, Bmg, Cmg, Pb, Sb);
  k4_comb  <<<24,256,0,stream>>>(Pb, Sb);
  k5_scan2 <<<512,384,0,stream>>>(dtg, xcg, Bmg, Cmg, Alog[0], Alog[1],
      Dp[0], Dp[1], inproj[0], inproj[1], Vgb, Hin, yall);
  k67_mid  <<<512,384,0,stream>>>(x, yall, yall + 786432, outproj[0], outproj[1],
      n2w, n2b, fpin, xmid, xpb);
  k9_conv3 <<<256,384,0,stream>>>(x,  fc1w, fc1b, fln1w, fln1b, ta,   1, 0);
  k9_conv3 <<<256,384,0,stream>>>(ta, fc2w, fc2b, fln1w, fln1b, tbuf, 0, 1);
  k14_fus  <<<1024,256,0,stream>>>(xpb, tbuf, fln2w, fln2b, fdw, ffus, x1b);
  k16_out  <<<512,384,0,stream>>>(x1b, xpb, fdwa, fdw + 96*9, fpout, xmid, (float*)d_out);
}

// Round 14
// 167.314 us; speedup vs baseline: 1.2486x; 1.2486x over previous
//
#include <hip/hip_runtime.h>

// SBSM block: B=2, C=48, H=W=64, L=4096, DI=96, DS=16, DCONV=4, DTR=3, HF=96
#define DEV __device__ __forceinline__

DEV float siluf(float x){ return x / (1.f + __expf(-x)); }
DEV float softplusf(float x){ return fmaxf(x, 0.f) + log1pf(expf(-fabsf(x))); }
DEV float geluf(float x){ return 0.5f * x * (1.f + erff(x * 0.70710678118654752440f)); }

// ---------------- kA9: blocks 0..511 = snake gather + LN(n1) + posenc + LN(mln) -> Vg ; inproj xm-half -> xmg
//                  blocks 512..767 = 2x2-pool(x) + 3x3 conv fc1 -> ta (out-channel quarters)
__global__ __launch_bounds__(256) void kA9(const float* __restrict__ x,
    const float* __restrict__ n1w, const float* __restrict__ n1b,
    const float* __restrict__ mw0, const float* __restrict__ mb0,
    const float* __restrict__ mw1, const float* __restrict__ mb1,
    const float* __restrict__ ip0, const float* __restrict__ ip1,
    const float* __restrict__ fc1w, const float* __restrict__ fc1b,
    float* __restrict__ xmg, float* __restrict__ Vg, float* __restrict__ ta){
  __shared__ union alignas(16) UA {
    struct { float Vl[48*36]; float Wt[48*97]; float mu_s[32]; float rs_s[32]; } a;
    struct { float wl[12*48*9]; float sin_[48*102]; } c;
  } u;
  int tid = threadIdx.x;
  if (blockIdx.x < 512){
    int bd = blockIdx.x >> 7, tile = blockIdx.x & 127;
    int dir = bd >> 1, b = bd & 1;
    int t0 = tile*32;
    const float* ip = dir ? ip1 : ip0;
    const float* mw = dir ? mw1 : mw0;
    const float* mb = dir ? mb1 : mb0;
    for (int i = tid; i < 96*48; i += 256){
      int j = i / 48, c = i % 48;
      u.a.Wt[c*97 + j] = ip[i];
    }
    for (int i = tid; i < 48*32; i += 256){
      int c = i >> 5, r = i & 31;
      int t = t0 + r;
      int h, w;
      if (dir == 0){ h = t >> 6; int wp = t & 63; w = (h & 1) ? 63 - wp : wp; }
      else         { w = t >> 6; int hp = t & 63; h = (w & 1) ? 63 - hp : hp; }
      u.a.Vl[c*36 + r] = x[(size_t)b*48*4096 + c*4096 + h*64 + w];
    }
    __syncthreads();
    {
      int r = tid >> 3, k = tid & 7;
      float s1 = 0.f, s2 = 0.f;
      #pragma unroll
      for (int cc = 0; cc < 6; cc++){
        float v = u.a.Vl[(k*6+cc)*36 + r];
        s1 += v; s2 += v*v;
      }
      s1 += __shfl_xor(s1,1); s2 += __shfl_xor(s2,1);
      s1 += __shfl_xor(s1,2); s2 += __shfl_xor(s2,2);
      s1 += __shfl_xor(s1,4); s2 += __shfl_xor(s2,4);
      if (k == 0){
        float m = s1*(1.f/48.f);
        u.a.mu_s[r] = m;
        u.a.rs_s[r] = rsqrtf(s2*(1.f/48.f) - m*m + 1e-5f);
      }
    }
    __syncthreads();
    for (int i = tid; i < 32*48; i += 256){
      int r = i / 48, c = i % 48;
      int t = t0 + r;
      float v = u.a.Vl[c*36 + r];
      float xn = (v - u.a.mu_s[r])*u.a.rs_s[r]*n1w[c] + n1b[c];
      float ang = (float)t * __expf(-(float)(c & ~1) * (9.210340371976184f/48.f));
      float pe = (c & 1) ? cosf(ang) : sinf(ang);
      u.a.Vl[c*36 + r] = xn + pe;
    }
    __syncthreads();
    {
      int r = tid >> 3, k = tid & 7;
      float s1 = 0.f, s2 = 0.f;
      #pragma unroll
      for (int cc = 0; cc < 6; cc++){
        float v = u.a.Vl[(k*6+cc)*36 + r];
        s1 += v; s2 += v*v;
      }
      s1 += __shfl_xor(s1,1); s2 += __shfl_xor(s2,1);
      s1 += __shfl_xor(s1,2); s2 += __shfl_xor(s2,2);
      s1 += __shfl_xor(s1,4); s2 += __shfl_xor(s2,4);
      if (k == 0){
        float m = s1*(1.f/48.f);
        u.a.mu_s[r] = m;
        u.a.rs_s[r] = rsqrtf(s2*(1.f/48.f) - m*m + 1e-5f);
      }
    }
    __syncthreads();
    for (int i = tid; i < 32*48; i += 256){
      int r = i / 48, c = i % 48;
      float v = u.a.Vl[c*36 + r];
      float v2 = (v - u.a.mu_s[r])*u.a.rs_s[r]*mw[c] + mb[c];
      u.a.Vl[c*36 + r] = v2;
      Vg[((size_t)bd*4096 + t0 + r)*48 + c] = v2;
    }
    __syncthreads();
    for (int k = 0; k < 3; k++){
      int i = tid + k*256;
      int j = i % 96, rb = i / 96;
      float a0=0.f, a1=0.f, a2=0.f, a3=0.f;
      #pragma unroll 4
      for (int c = 0; c < 48; c++){
        float wv = u.a.Wt[c*97 + j];
        const float4 v4 = *(const float4*)&u.a.Vl[c*36 + rb*4];
        a0 += wv*v4.x; a1 += wv*v4.y; a2 += wv*v4.z; a3 += wv*v4.w;
      }
      size_t g = ((size_t)bd*4096 + t0 + rb*4)*96 + j;
      xmg[g] = a0; xmg[g+96] = a1; xmg[g+192] = a2; xmg[g+288] = a3;
    }
  } else {
    // pool + conv1 (fc1), out-channel quarters, 256 blocks
    int bid = blockIdx.x - 512;
    int cq = bid & 3, i0 = (bid >> 2) & 31, b2 = bid >> 7;
    for (int i = tid; i < 12*48*9; i += 256) u.c.wl[i] = fc1w[cq*12*48*9 + i];
    for (int i = tid; i < 48*102; i += 256){
      int jx = i % 34, ky = (i/34) % 3, ci = i/102;
      int r = i0 + ky - 1, j = jx - 1;
      float v = 0.f;
      if (r >= 0 && r < 32 && j >= 0 && j < 32){
        const float* xb = x + (((size_t)b2*48 + ci)*64 + 2*r)*64 + 2*j;
        v = 0.25f*(xb[0] + xb[1] + xb[64] + xb[65]);
      }
      u.c.sin_[i] = v;
    }
    __syncthreads();
    for (int i = tid; i < 12*32; i += 256){
      int j = i & 31, col = i >> 5;
      float acc = fc1b[cq*12 + col];
      for (int ci = 0; ci < 48; ci++){
        const float* wp = u.c.wl + ((size_t)col*48 + ci)*9;
        const float* sp = u.c.sin_ + ci*102;
        #pragma unroll
        for (int ky = 0; ky < 3; ky++)
          #pragma unroll
          for (int kx = 0; kx < 3; kx++)
            acc += sp[ky*34 + j + kx] * wp[ky*3 + kx];
      }
      ta[(((size_t)b2*48 + cq*12 + col)*32 + i0)*32 + j] = acc;
    }
  }
}

// ---------------- kB9: blocks 0..511 = causal conv4+silu + xproj + dt/B/C + scan pass-1
//                  blocks 512..767 = LN(fln1)+ReLU(ta) + 3x3 conv fc2 -> tbuf
__global__ __launch_bounds__(384) void kB9(const float* __restrict__ xmg,
    const float* __restrict__ cwp0, const float* __restrict__ cwp1,
    const float* __restrict__ cbp0, const float* __restrict__ cbp1,
    const float* __restrict__ xpp0, const float* __restrict__ xpp1,
    const float* __restrict__ dwp0, const float* __restrict__ dwp1,
    const float* __restrict__ dbp0, const float* __restrict__ dbp1,
    const float* __restrict__ Alog0, const float* __restrict__ Alog1,
    const float* __restrict__ ta, const float* __restrict__ fc2w, const float* __restrict__ fc2b,
    const float* __restrict__ fln1w, const float* __restrict__ fln1b,
    float* __restrict__ xcg, float* __restrict__ dtg,
    float* __restrict__ Bmg, float* __restrict__ Cmg,
    float* __restrict__ P, float* __restrict__ S, float* __restrict__ tbuf){
  __shared__ union alignas(16) UBB {
    struct {
      float Bl[32*16]; float Cl[32*16];
      union { float xml[96*36]; struct { float xwl[35*96]; float xdbl[35*33]; } p; } ub;
      float xcl[96*33]; float dtl[96*33];
      float cw[96*4]; float cbv[96]; float dwl[96*3]; float dbl[96];
    } b;
    struct { float wl[12*48*9]; float sin_[48*102]; float mu_i[104]; float rs_i[104]; } c;
  } u;
  int tid = threadIdx.x;
  if (blockIdx.x < 512){
    int bd = blockIdx.x >> 7, tile = blockIdx.x & 127;
    int dir = bd >> 1;
    int t0 = tile*32;
    const float* cwp = dir ? cwp1 : cwp0;
    const float* cbp = dir ? cbp1 : cbp0;
    const float* xpp = dir ? xpp1 : xpp0;
    const float* dwp = dir ? dwp1 : dwp0;
    const float* dbp = dir ? dbp1 : dbp0;
    const float* Alog = dir ? Alog1 : Alog0;
    for (int i = tid; i < 35*96; i += 384){
      int tl = i / 96, d = i % 96;
      int t = t0 - 3 + tl;
      u.b.ub.xml[d*36 + tl] = (t >= 0) ? xmg[((size_t)bd*4096 + t)*96 + d] : 0.f;
    }
    for (int i = tid; i < 96*4;  i += 384) u.b.cw[i] = cwp[i];
    for (int i = tid; i < 96*3;  i += 384) u.b.dwl[i] = dwp[i];
    for (int i = tid; i < 96;    i += 384){ u.b.cbv[i] = cbp[i]; u.b.dbl[i] = dbp[i]; }
    __syncthreads();
    for (int i = tid; i < 96*32; i += 384){
      int d = i >> 5, t = i & 31;
      float acc = u.b.cbv[d];
      #pragma unroll
      for (int k = 0; k < 4; k++) acc += u.b.cw[d*4+k]*u.b.ub.xml[d*36 + t + k];
      u.b.xcl[d*33 + t] = siluf(acc);
    }
    __syncthreads();
    for (int i = tid; i < 35*96; i += 384) u.b.ub.p.xwl[i] = xpp[i];
    __syncthreads();
    for (int i = tid; i < 35*32; i += 384){
      int j = i / 32, t = i % 32;
      float acc = 0.f;
      #pragma unroll 4
      for (int d = 0; d < 96; d++) acc += u.b.xcl[d*33 + t]*u.b.ub.p.xwl[j*96 + d];
      u.b.ub.p.xdbl[j*33 + t] = acc;
    }
    __syncthreads();
    for (int i = tid; i < 96*32; i += 384){
      int d = i >> 5, t = i & 31;
      float v = u.b.dbl[d];
      #pragma unroll
      for (int r = 0; r < 3; r++) v += u.b.ub.p.xdbl[r*33 + t]*u.b.dwl[d*3 + r];
      u.b.dtl[d*33 + t] = softplusf(v);
    }
    for (int i = tid; i < 32*16; i += 384){
      int t = i / 16, s = i % 16;
      u.b.Bl[t*16 + s] = u.b.ub.p.xdbl[(3+s)*33 + t];
      u.b.Cl[t*16 + s] = u.b.ub.p.xdbl[(19+s)*33 + t];
    }
    __syncthreads();
    for (int i = tid; i < 32*96; i += 384){
      int t = i / 96, d = i % 96;
      size_t g = ((size_t)bd*4096 + t0 + t)*96 + d;
      xcg[g] = u.b.xcl[d*33 + t];
      dtg[g] = u.b.dtl[d*33 + t];
    }
    for (int i = tid; i < 32*16; i += 384){
      int t = i / 16, s = i % 16;
      size_t g = ((size_t)bd*4096 + t0 + t)*16 + s;
      Bmg[g] = u.b.Bl[t*16 + s];
      Cmg[g] = u.b.Cl[t*16 + s];
    }
    {
      int d = tid >> 2, q = tid & 3;
      float A0 = -__expf(Alog[d*16 + q*4 + 0]);
      float A1 = -__expf(Alog[d*16 + q*4 + 1]);
      float A2 = -__expf(Alog[d*16 + q*4 + 2]);
      float A3 = -__expf(Alog[d*16 + q*4 + 3]);
      float h0=0.f,h1=0.f,h2=0.f,h3=0.f, p0=1.f,p1=1.f,p2=1.f,p3=1.f;
      #pragma unroll 4
      for (int t = 0; t < 32; t++){
        float dtd = u.b.dtl[d*33 + t];
        float uu = dtd * u.b.xcl[d*33 + t];
        const float4 b4 = *(const float4*)&u.b.Bl[t*16 + q*4];
        float a0 = __expf(dtd*A0), a1 = __expf(dtd*A1), a2 = __expf(dtd*A2), a3 = __expf(dtd*A3);
        h0 = a0*h0 + uu*b4.x; p0 *= a0;
        h1 = a1*h1 + uu*b4.y; p1 *= a1;
        h2 = a2*h2 + uu*b4.z; p2 *= a2;
        h3 = a3*h3 + uu*b4.w; p3 *= a3;
      }
      size_t ob = (size_t)blockIdx.x*1536 + d*16 + q*4;
      *(float4*)&P[ob] = make_float4(p0,p1,p2,p3);
      *(float4*)&S[ob] = make_float4(h0,h1,h2,h3);
    }
  } else {
    // LN(fln1)+ReLU on ta, then conv fc2 -> tbuf
    int bid = blockIdx.x - 512;
    int cq = bid & 3, i0 = (bid >> 2) & 31, b2 = bid >> 7;
    for (int i = tid; i < 12*48*9; i += 384) u.c.wl[i] = fc2w[cq*12*48*9 + i];
    for (int i = tid; i < 48*102; i += 384){
      int jx = i % 34, ky = (i/34) % 3, ci = i/102;
      int r = i0 + ky - 1, j = jx - 1;
      float v = 0.f;
      if (r >= 0 && r < 32 && j >= 0 && j < 32)
        v = ta[(((size_t)b2*48 + ci)*32 + r)*32 + j];
      u.c.sin_[i] = v;
    }
    __syncthreads();
    if (tid < 102){
      int jx = tid % 34, ky = tid / 34;
      int r = i0 + ky - 1, j = jx - 1;
      if (r >= 0 && r < 32 && j >= 0 && j < 32){
        float s1 = 0.f, s2 = 0.f;
        #pragma unroll 4
        for (int ci = 0; ci < 48; ci++){ float v = u.c.sin_[ci*102 + tid]; s1 += v; s2 += v*v; }
        float m = s1*(1.f/48.f);
        u.c.mu_i[tid] = m;
        u.c.rs_i[tid] = rsqrtf(s2*(1.f/48.f) - m*m + 1e-5f);
      }
    }
    __syncthreads();
    for (int i = tid; i < 48*102; i += 384){
      int ci = i / 102, p = i % 102;
      int jx = p % 34, ky = p / 34;
      int r = i0 + ky - 1, j = jx - 1;
      if (r >= 0 && r < 32 && j >= 0 && j < 32){
        float v = (u.c.sin_[i] - u.c.mu_i[p])*u.c.rs_i[p]*fln1w[ci] + fln1b[ci];
        u.c.sin_[i] = fmaxf(v, 0.f);
      }
    }
    __syncthreads();
    int j = tid & 31, col = tid >> 5;    // col 0..11
    float acc = fc2b[cq*12 + col];
    for (int ci = 0; ci < 48; ci++){
      const float* wp = u.c.wl + ((size_t)col*48 + ci)*9;
      const float* sp = u.c.sin_ + ci*102;
      #pragma unroll
      for (int ky = 0; ky < 3; ky++)
        #pragma unroll
        for (int kx = 0; kx < 3; kx++)
          acc += sp[ky*34 + j + kx] * wp[ky*3 + kx];
    }
    tbuf[(((size_t)b2*48 + cq*12 + col)*32 + i0)*32 + j] = acc;
  }
}

// ---------------- k4: sequential chunk combine over 128 chunks, IN PLACE (Hin = P).
__global__ __launch_bounds__(256) void k4_comb(float* __restrict__ P, const float* __restrict__ S){
  int tid2 = blockIdx.x*256 + threadIdx.x;   // 6144 lanes
  int bd = tid2 / 1536, r = tid2 % 1536;
  size_t idx = (size_t)bd*128*1536 + r;
  const int ST = 1536;
  float pb0,pb1,pb2,pb3,pb4,pb5,pb6,pb7, sb0,sb1,sb2,sb3,sb4,sb5,sb6,sb7;
  pb0=P[idx+0*ST]; sb0=S[idx+0*ST]; pb1=P[idx+1*ST]; sb1=S[idx+1*ST];
  pb2=P[idx+2*ST]; sb2=S[idx+2*ST]; pb3=P[idx+3*ST]; sb3=S[idx+3*ST];
  pb4=P[idx+4*ST]; sb4=S[idx+4*ST]; pb5=P[idx+5*ST]; sb5=S[idx+5*ST];
  pb6=P[idx+6*ST]; sb6=S[idx+6*ST]; pb7=P[idx+7*ST]; sb7=S[idx+7*ST];
  float h = 0.f;
  for (int c0 = 0; c0 < 128; c0 += 8){
    float pn0=0,sn0=0,pn1=0,sn1=0,pn2=0,sn2=0,pn3=0,sn3=0;
    float pn4=0,sn4=0,pn5=0,sn5=0,pn6=0,sn6=0,pn7=0,sn7=0;
    if (c0 + 8 < 128){
      pn0=P[idx+(size_t)(c0+8)*ST];  sn0=S[idx+(size_t)(c0+8)*ST];
      pn1=P[idx+(size_t)(c0+9)*ST];  sn1=S[idx+(size_t)(c0+9)*ST];
      pn2=P[idx+(size_t)(c0+10)*ST]; sn2=S[idx+(size_t)(c0+10)*ST];
      pn3=P[idx+(size_t)(c0+11)*ST]; sn3=S[idx+(size_t)(c0+11)*ST];
      pn4=P[idx+(size_t)(c0+12)*ST]; sn4=S[idx+(size_t)(c0+12)*ST];
      pn5=P[idx+(size_t)(c0+13)*ST]; sn5=S[idx+(size_t)(c0+13)*ST];
      pn6=P[idx+(size_t)(c0+14)*ST]; sn6=S[idx+(size_t)(c0+14)*ST];
      pn7=P[idx+(size_t)(c0+15)*ST]; sn7=S[idx+(size_t)(c0+15)*ST];
    }
    P[idx+(size_t)(c0+0)*ST] = h; h = pb0*h + sb0;
    P[idx+(size_t)(c0+1)*ST] = h; h = pb1*h + sb1;
    P[idx+(size_t)(c0+2)*ST] = h; h = pb2*h + sb2;
    P[idx+(size_t)(c0+3)*ST] = h; h = pb3*h + sb3;
    P[idx+(size_t)(c0+4)*ST] = h; h = pb4*h + sb4;
    P[idx+(size_t)(c0+5)*ST] = h; h = pb5*h + sb5;
    P[idx+(size_t)(c0+6)*ST] = h; h = pb6*h + sb6;
    P[idx+(size_t)(c0+7)*ST] = h; h = pb7*h + sb7;
    pb0=pn0;sb0=sn0;pb1=pn1;sb1=sn1;pb2=pn2;sb2=sn2;pb3=pn3;sb3=sn3;
    pb4=pn4;sb4=sn4;pb5=pn5;sb5=sn5;pb6=pn6;sb6=sn6;pb7=pn7;sb7=sn7;
  }
}

// ---------------- k5: pass-3 rescan (+D term) -> yl ; then z GEMV + gate, LDS phase-union.
__global__ __launch_bounds__(384) void k5_scan2(const float* __restrict__ dtg,
    const float* __restrict__ xcg, const float* __restrict__ Bmg, const float* __restrict__ Cmg,
    const float* __restrict__ Alog0, const float* __restrict__ Alog1,
    const float* __restrict__ Dp0, const float* __restrict__ Dp1,
    const float* __restrict__ ip0, const float* __restrict__ ip1,
    const float* __restrict__ Vg, const float* __restrict__ Hin, float* __restrict__ yout){
  __shared__ union U5 {
    struct { float dts[32*96]; float xcs[32*96]; } s;   // scan phase
    struct { float Wzt[48*96]; float Vgs[32*48]; } e;   // epilogue phase
  } u;
  __shared__ alignas(16) float Bl[32*16], Cl[32*16];
  __shared__ float yl[32*96];
  int task = blockIdx.x;
  int bd = task >> 7, ch = task & 127;
  int t0 = ch*32;
  int tid = threadIdx.x;
  const float* ip   = (bd >= 2) ? ip1 : ip0;
  const float* Alog = (bd >= 2) ? Alog1 : Alog0;
  const float* Dp   = (bd >= 2) ? Dp1 : Dp0;
  for (int i = tid; i < 32*96; i += 384){
    int t = i / 96, dd = i % 96;
    size_t g = ((size_t)bd*4096 + t0 + t)*96 + dd;
    u.s.dts[i] = dtg[g];
    u.s.xcs[i] = xcg[g];
  }
  for (int i = tid; i < 32*16; i += 384){
    size_t g = ((size_t)bd*4096 + t0)*16 + i;
    Bl[i] = Bmg[g];
    Cl[i] = Cmg[g];
  }
  __syncthreads();
  {
    int d = tid >> 2, q = tid & 3;
    float A0 = -__expf(Alog[d*16 + q*4 + 0]);
    float A1 = -__expf(Alog[d*16 + q*4 + 1]);
    float A2 = -__expf(Alog[d*16 + q*4 + 2]);
    float A3 = -__expf(Alog[d*16 + q*4 + 3]);
    float Dd = Dp[d];
    const float4 h4 = *(const float4*)&Hin[(size_t)task*1536 + d*16 + q*4];
    float h0 = h4.x, h1 = h4.y, h2 = h4.z, h3 = h4.w;
    for (int t = 0; t < 32; t += 2){
      float dtdA = u.s.dts[t*96 + d];
      float xcvA = u.s.xcs[t*96 + d];
      float dtdB = u.s.dts[(t+1)*96 + d];
      float xcvB = u.s.xcs[(t+1)*96 + d];
      float uA = dtdA * xcvA, uB = dtdB * xcvB;
      const float4 b4A = *(const float4*)&Bl[t*16 + q*4];
      const float4 c4A = *(const float4*)&Cl[t*16 + q*4];
      const float4 b4B = *(const float4*)&Bl[(t+1)*16 + q*4];
      const float4 c4B = *(const float4*)&Cl[(t+1)*16 + q*4];
      float a0 = __expf(dtdA*A0), a1 = __expf(dtdA*A1), a2 = __expf(dtdA*A2), a3 = __expf(dtdA*A3);
      float e0 = __expf(dtdB*A0), e1 = __expf(dtdB*A1), e2 = __expf(dtdB*A2), e3 = __expf(dtdB*A3);
      h0 = a0*h0 + uA*b4A.x;
      h1 = a1*h1 + uA*b4A.y;
      h2 = a2*h2 + uA*b4A.z;
      h3 = a3*h3 + uA*b4A.w;
      float pyA = (h0*c4A.x + h1*c4A.y) + (h2*c4A.z + h3*c4A.w);
      h0 = e0*h0 + uB*b4B.x;
      h1 = e1*h1 + uB*b4B.y;
      h2 = e2*h2 + uB*b4B.z;
      h3 = e3*h3 + uB*b4B.w;
      float pyB = (h0*c4B.x + h1*c4B.y) + (h2*c4B.z + h3*c4B.w);
      pyA += __shfl_xor(pyA, 1);  pyB += __shfl_xor(pyB, 1);
      pyA += __shfl_xor(pyA, 2);  pyB += __shfl_xor(pyB, 2);
      if (q == 0){
        yl[t*96 + d]     = pyA + xcvA*Dd;
        yl[(t+1)*96 + d] = pyB + xcvB*Dd;
      }
    }
  }
  __syncthreads();
  for (int i = tid; i < 96*48; i += 384){
    int j = i % 96, c = i / 96;
    u.e.Wzt[c*96 + j] = ip[(96 + j)*48 + c];
  }
  for (int i = tid; i < 32*48; i += 384){
    int t = i / 48, c = i % 48;
    u.e.Vgs[i] = Vg[((size_t)bd*4096 + t0 + t)*48 + c];
  }
  __syncthreads();
  for (int i = tid; i < 32*96; i += 384){
    int t = i / 96, dd = i % 96;
    float z = 0.f;
    #pragma unroll 4
    for (int c = 0; c < 48; c++) z += u.e.Wzt[c*96 + dd] * u.e.Vgs[t*48 + c];
    size_t g = ((size_t)bd*4096 + t0 + t)*96 + dd;
    yout[g] = yl[i] * siluf(z);
  }
}

// ---------------- k67: w-split 16 (512 blocks x 384 thr): un-snake + outproj + residual -> xmid ; LN(n2)+pin -> xp
__global__ __launch_bounds__(384) void k67_mid(const float* __restrict__ x,
    const float* __restrict__ y1, const float* __restrict__ y2,
    const float* __restrict__ op1, const float* __restrict__ op2,
    const float* __restrict__ nw, const float* __restrict__ nb,
    const float* __restrict__ pin,
    float* __restrict__ xmid, float* __restrict__ xp){
  __shared__ float bufW[192*49];        // op view: [48][97]; pin view: [192][49]
  __shared__ union UL { float ylds[16*97]; struct { float xl[48*17]; float mu[16]; float rs[16]; } l; } ul;
  int bid = blockIdx.x;                 // b*256 + h*4 + wq
  int b = bid >> 8, h = (bid >> 2) & 63, wq = bid & 3;
  int w0 = wq << 4;
  int tid = threadIdx.x;
  int w = tid & 15, cg = tid >> 4;      // cg 0..23, 2 channels each
  float acc0 = 0.f, acc1 = 0.f;
  for (int pass = 0; pass < 2; pass++){
    __syncthreads();
    const float* op = pass ? op2 : op1;
    const float* y  = pass ? y2  : y1;
    for (int i = tid; i < 48*96; i += 384){
      int c = i / 96, d = i % 96;
      bufW[c*97 + d] = op[i];
    }
    if (pass == 0){
      for (int i = tid; i < 16*96; i += 384){
        int wl_ = i / 96, d = i % 96;
        int wsp = w0 + wl_;
        int wp = (h & 1) ? 63 - wsp : wsp;
        ul.ylds[wl_*97 + d] = y[((size_t)b*4096 + h*64 + wp)*96 + d];
      }
    } else {
      for (int i = tid; i < 16*96; i += 384){
        int wl_ = i / 96, d = i % 96;
        int wsp = w0 + wl_;
        int t = wsp*64 + ((wsp & 1) ? 63 - h : h);
        ul.ylds[wl_*97 + d] = y[((size_t)b*4096 + t)*96 + d];
      }
    }
    __syncthreads();
    #pragma unroll 4
    for (int d = 0; d < 96; d++){
      float yv = ul.ylds[w*97 + d];
      acc0 += yv * bufW[(cg*2+0)*97 + d];
      acc1 += yv * bufW[(cg*2+1)*97 + d];
    }
  }
  __syncthreads();   // GEMVs done: safe to overwrite ylds and bufW
  {
    int c0 = cg*2;
    size_t idx0 = (((size_t)b*48 + c0)*64 + h)*64 + w0 + w;
    float v0 = x[idx0] + acc0;
    xmid[idx0] = v0;
    ul.l.xl[c0*17 + w] = v0;
    size_t idx1 = idx0 + 4096;
    float v1 = x[idx1] + acc1;
    xmid[idx1] = v1;
    ul.l.xl[(c0+1)*17 + w] = v1;
  }
  for (int i = tid; i < 192*48; i += 384){
    int r = i / 48, c = i % 48;
    bufW[r*49 + c] = pin[i];
  }
  __syncthreads();
  if (tid < 128){
    int r = tid >> 3, k = tid & 7;
    float s1 = 0.f, s2 = 0.f;
    #pragma unroll
    for (int cc = 0; cc < 6; cc++){
      float v = ul.l.xl[(k*6+cc)*17 + r];
      s1 += v; s2 += v*v;
    }
    s1 += __shfl_xor(s1,1); s2 += __shfl_xor(s2,1);
    s1 += __shfl_xor(s1,2); s2 += __shfl_xor(s2,2);
    s1 += __shfl_xor(s1,4); s2 += __shfl_xor(s2,4);
    if (k == 0){
      float m = s1*(1.f/48.f);
      ul.l.mu[r] = m;
      ul.l.rs[r] = rsqrtf(s2*(1.f/48.f) - m*m + 1e-5f);
    }
  }
  __syncthreads();
  for (int i = tid; i < 48*16; i += 384){
    int c = i >> 4, ww = i & 15;
    ul.l.xl[c*17 + ww] = (ul.l.xl[c*17 + ww] - ul.l.mu[ww])*ul.l.rs[ww]*nw[c] + nb[c];
  }
  __syncthreads();
  for (int it = 0; it < 2; it++){
    int i = tid + it*384;
    int ww = i & 15, oq = i >> 4;   // oq 0..47
    int o0 = oq*4;
    float a0=0,a1=0,a2=0,a3=0;
    #pragma unroll 4
    for (int c = 0; c < 48; c++){
      float xv = ul.l.xl[c*17 + ww];
      a0 += xv*bufW[(o0+0)*49 + c];
      a1 += xv*bufW[(o0+1)*49 + c];
      a2 += xv*bufW[(o0+2)*49 + c];
      a3 += xv*bufW[(o0+3)*49 + c];
    }
    xp[(((size_t)b*192 + o0+0)*64 + h)*64 + w0 + ww] = a0;
    xp[(((size_t)b*192 + o0+1)*64 + h)*64 + w0 + ww] = a1;
    xp[(((size_t)b*192 + o0+2)*64 + h)*64 + w0 + ww] = a2;
    xp[(((size_t)b*192 + o0+3)*64 + h)*64 + w0 + ww] = a3;
  }
}

// ---------------- K13: depthwise 3x3, pad 1, CH channels, 64x64; 4 outputs/thread along w
__global__ __launch_bounds__(256) void k13_dw(const float* __restrict__ in,
    const float* __restrict__ wgt, float* __restrict__ out, int CH){
  int idx = blockIdx.x*256 + threadIdx.x;
  if (idx >= 2*CH*1024) return;
  int wq = idx & 15, h = (idx >> 4) & 63, c = (idx >> 10) % CH, b = idx / (CH*1024);
  int w0 = wq*4;
  const float* ip = in + ((size_t)b*CH + c)*4096;
  const float* wp = wgt + c*9;
  float a0=0.f,a1=0.f,a2=0.f,a3=0.f;
  #pragma unroll
  for (int ky = 0; ky < 3; ky++){
    int hh = h + ky - 1;
    if (hh < 0 || hh > 63) continue;
    const float* rp = ip + hh*64;
    float v0 = (w0 > 0)  ? rp[w0-1] : 0.f;
    float v1 = rp[w0+0], v2 = rp[w0+1], v3 = rp[w0+2], v4 = rp[w0+3];
    float v5 = (w0 < 60) ? rp[w0+4] : 0.f;
    float k0 = wp[ky*3+0], k1 = wp[ky*3+1], k2 = wp[ky*3+2];
    a0 += k0*v0 + k1*v1 + k2*v2;
    a1 += k0*v1 + k1*v2 + k2*v3;
    a2 += k0*v2 + k1*v3 + k2*v4;
    a3 += k0*v3 + k1*v4 + k2*v5;
  }
  float* op = out + (((size_t)b*CH + c)*64 + h)*64 + w0;
  op[0]=a0; op[1]=a1; op[2]=a2; op[3]=a3;
}

// ---------------- K14: 1x1 conv f_fus over concat(xd[:96], upsample(relu(ln(conv2_raw)))) -> x1 (96 ch)
__global__ __launch_bounds__(256) void k14_fus(const float* __restrict__ xd,
    const float* __restrict__ cv2, const float* __restrict__ lnw, const float* __restrict__ lnb,
    const float* __restrict__ fus, float* __restrict__ x1){
  __shared__ float wl[48*144];
  __shared__ float al[96][64];
  __shared__ float yl[48][32];
  __shared__ float muy[32], rsy[32];
  int bid = blockIdx.x;
  int oh = bid & 1, h = (bid >> 1) & 63, b = bid >> 7;
  int tid = threadIdx.x;
  for (int i = tid; i < 48*144; i += 256) wl[i] = fus[(size_t)oh*48*144 + i];
  for (int i = tid; i < 96*64; i += 256){
    int ci = i >> 6, w = i & 63;
    al[ci][w] = xd[(((size_t)b*192 + ci)*64 + h)*64 + w];
  }
  for (int i = tid; i < 48*32; i += 256){
    int cj = i >> 5, j = i & 31;
    yl[cj][j] = cv2[(((size_t)b*48 + cj)*32 + (h >> 1))*32 + j];
  }
  __syncthreads();
  if (tid < 32){
    float s1 = 0.f, s2 = 0.f;
    #pragma unroll 4
    for (int cj = 0; cj < 48; cj++){ float v = yl[cj][tid]; s1 += v; s2 += v*v; }
    float m = s1*(1.f/48.f);
    muy[tid] = m;
    rsy[tid] = rsqrtf(s2*(1.f/48.f) - m*m + 1e-5f);
  }
  __syncthreads();
  for (int i = tid; i < 48*32; i += 256){
    int cj = i >> 5, j = i & 31;
    yl[cj][j] = fmaxf((yl[cj][j] - muy[j])*rsy[j]*lnw[cj] + lnb[cj], 0.f);
  }
  __syncthreads();
  for (int it = 0; it < 3; it++){
    int i = tid + it*256;
    int w = i & 63, ob = i >> 6; int o0 = ob*4;
    float a[4] = {0,0,0,0};
    #pragma unroll 4
    for (int ci = 0; ci < 96; ci++){
      float xv = al[ci][w];
      #pragma unroll
      for (int q = 0; q < 4; q++) a[q] += xv * wl[(o0+q)*144 + ci];
    }
    int w2 = w >> 1;
    #pragma unroll 4
    for (int cj = 0; cj < 48; cj++){
      float yv = yl[cj][w2];
      #pragma unroll
      for (int q = 0; q < 4; q++) a[q] += yv * wl[(o0+q)*144 + 96 + cj];
    }
    #pragma unroll
    for (int q = 0; q < 4; q++)
      x1[(((size_t)b*96 + oh*48 + o0 + q)*64 + h)*64 + w] = a[q];
  }
}

// ---------------- K16: w-split 16 (512 blocks x 384 thr): fused dwa 3x3 on x1 -> gelu * x2 -> pout GEMV -> + xmid -> out
__global__ __launch_bounds__(384) void k16_out(const float* __restrict__ x1,
    const float* __restrict__ xd, const float* __restrict__ dww,
    const float* __restrict__ pout, const float* __restrict__ xmid, float* __restrict__ out){
  __shared__ float wl[48*97];        // padded pout
  __shared__ float xs[96*54];        // [ch][ky 0..2][jx 0..17]
  __shared__ float gl[96*17];
  __shared__ float dwl[96*9];
  int bid = blockIdx.x;              // b*256 + h*4 + wq
  int b = bid >> 8, h = (bid >> 2) & 63, wq = bid & 3;
  int w0 = wq << 4;
  int tid = threadIdx.x;
  for (int i = tid; i < 48*96; i += 384){
    int r = i / 96, c = i % 96;
    wl[r*97 + c] = pout[i];
  }
  for (int i = tid; i < 96*9; i += 384) dwl[i] = dww[i];
  for (int i = tid; i < 96*54; i += 384){
    int jx = i % 18, ky = (i/18) % 3, ch = i/54;
    int hh = h + ky - 1, ww_ = w0 + jx - 1;
    float v = 0.f;
    if (hh >= 0 && hh < 64 && ww_ >= 0 && ww_ < 64)
      v = x1[(((size_t)b*96 + ch)*64 + hh)*64 + ww_];
    xs[i] = v;
  }
  __syncthreads();
  for (int i = tid; i < 96*16; i += 384){
    int ch = i >> 4, ww = i & 15;
    const float* wp = dwl + ch*9;
    const float* sp = xs + ch*54;
    float a = 0.f;
    #pragma unroll
    for (int ky = 0; ky < 3; ky++)
      #pragma unroll
      for (int kx = 0; kx < 3; kx++)
        a += sp[ky*18 + ww + kx] * wp[ky*3 + kx];
    float x2 = xd[(((size_t)b*192 + 96 + ch)*64 + h)*64 + w0 + ww];
    gl[ch*17 + ww] = geluf(a) * x2;
  }
  __syncthreads();
  int ww = tid & 15, cg = tid >> 4;  // cg 0..23, 2 channels each
  float a0=0.f, a1=0.f;
  #pragma unroll 4
  for (int ch = 0; ch < 96; ch++){
    float gv = gl[ch*17 + ww];
    a0 += gv * wl[(cg*2+0)*97 + ch];
    a1 += gv * wl[(cg*2+1)*97 + ch];
  }
  {
    int c0 = cg*2;
    size_t idx0 = (((size_t)b*48 + c0)*64 + h)*64 + w0 + ww;
    out[idx0] = xmid[idx0] + a0;
    size_t idx1 = idx0 + 4096;
    out[idx1] = xmid[idx1] + a1;
  }
}

extern "C" void kernel_launch(void* const* d_in, const int* in_sizes, int n_in,
                              void* d_out, int out_size, void* d_ws, size_t ws_size,
                              hipStream_t stream){
  (void)in_sizes; (void)n_in; (void)out_size; (void)ws_size;
  const float* x    = (const float*)d_in[0];
  const float* n1w  = (const float*)d_in[1];
  const float* n1b  = (const float*)d_in[2];
  const float* n2w  = (const float*)d_in[3];
  const float* n2b  = (const float*)d_in[4];
  const float* mlnw[2] = {(const float*)d_in[5], (const float*)d_in[7]};
  const float* mlnb[2] = {(const float*)d_in[6], (const float*)d_in[8]};
  const float* fln1w = (const float*)d_in[9];
  const float* fln1b = (const float*)d_in[10];
  const float* fln2w = (const float*)d_in[11];
  const float* fln2b = (const float*)d_in[12];
  const float* inproj[2]  = {(const float*)d_in[13], (const float*)d_in[22]};
  const float* convw[2]   = {(const float*)d_in[14], (const float*)d_in[23]};
  const float* convb[2]   = {(const float*)d_in[15], (const float*)d_in[24]};
  const float* xproj[2]   = {(const float*)d_in[16], (const float*)d_in[25]};
  const float* dtw[2]     = {(const float*)d_in[17], (const float*)d_in[26]};
  const float* dtbp[2]    = {(const float*)d_in[18], (const float*)d_in[27]};
  const float* Alog[2]    = {(const float*)d_in[19], (const float*)d_in[28]};
  const float* Dp[2]      = {(const float*)d_in[20], (const float*)d_in[29]};
  const float* outproj[2] = {(const float*)d_in[21], (const float*)d_in[30]};
  const float* fpin  = (const float*)d_in[31];
  const float* fdw   = (const float*)d_in[32];
  const float* ffus  = (const float*)d_in[33];
  const float* fdwa  = (const float*)d_in[34];
  const float* fpout = (const float*)d_in[35];
  const float* fc1w  = (const float*)d_in[36];
  const float* fc1b  = (const float*)d_in[37];
  const float* fc2w  = (const float*)d_in[38];
  const float* fc2b  = (const float*)d_in[39];

  // workspace (floats), total 7,995,392 (= 32.0 MB)
  float* ws = (float*)d_ws;
  float* xmg = ws + 0;         // (4,4096,96)  -> later yall
  float* Vgb = ws + 1572864;   // (4,4096,48)
  float* xcg = ws + 2359296;   // (4,4096,96)  -> later xpb (B,192,64,64)
  float* dtg = ws + 3932160;   // (4,4096,96)  -> later xdb
  float* Bmg = ws + 5505024;   // (4,4096,16)
  float* Cmg = ws + 5767168;   // (4,4096,16)
  float* Pb  = ws + 6029312;   // (512,1536)   -> Hin in-place, later x1b
  float* Sb  = ws + 6815744;   // (512,1536)
  float* xmid= ws + 7602176;   // (B,48,64,64)
  float* yall = xmg;
  float* Hin  = Pb;
  float* xpb  = xcg;
  float* xdb  = dtg;
  float* x1b  = Pb;
  // conv-chain temporaries live in d_out (dead until the final k16 write):
  float* outf = (float*)d_out;
  float* ta   = outf;            // (B,48,32,32) = 98,304 floats
  float* tbuf = outf + 98304;    // (B,48,32,32)

  kA9<<<768,256,0,stream>>>(x, n1w, n1b,
      mlnw[0], mlnb[0], mlnw[1], mlnb[1], inproj[0], inproj[1],
      fc1w, fc1b, xmg, Vgb, ta);
  kB9<<<768,384,0,stream>>>(xmg,
      convw[0], convw[1], convb[0], convb[1], xproj[0], xproj[1],
      dtw[0], dtw[1], dtbp[0], dtbp[1], Alog[0], Alog[1],
      ta, fc2w, fc2b, fln1w, fln1b,
      xcg, dtg, Bmg, Cmg, Pb, Sb, tbuf);
  k4_comb  <<<24,256,0,stream>>>(Pb, Sb);
  k5_scan2 <<<512,384,0,stream>>>(dtg, xcg, Bmg, Cmg, Alog[0], Alog[1],
      Dp[0], Dp[1], inproj[0], inproj[1], Vgb, Hin, yall);
  k67_mid  <<<512,384,0,stream>>>(x, yall, yall + 786432, outproj[0], outproj[1],
      n2w, n2b, fpin, xmid, xpb);
  k13_dw   <<<1536,256,0,stream>>>(xpb, fdw, xdb, 192);
  k14_fus  <<<256,256,0,stream>>>(xdb, tbuf, fln2w, fln2b, ffus, x1b);
  k16_out  <<<512,384,0,stream>>>(x1b, xdb, fdwa, fpout, xmid, (float*)d_out);
}

// Round 15
// 163.216 us; speedup vs baseline: 1.2800x; 1.0251x over previous
//
#include <hip/hip_runtime.h>

// SBSM block: B=2, C=48, H=W=64, L=4096, DI=96, DS=16, DCONV=4, DTR=3, HF=96
#define DEV __device__ __forceinline__

DEV float siluf(float x){ return x / (1.f + __expf(-x)); }
DEV float softplusf(float x){ return fmaxf(x, 0.f) + log1pf(expf(-fabsf(x))); }
DEV float geluf(float x){ return 0.5f * x * (1.f + erff(x * 0.70710678118654752440f)); }

// ---------------- kA9: blocks 0..511 = snake gather + LN(n1) + posenc + LN(mln) -> Vg ; inproj xm-half -> xmg
//                  blocks 512..767 = 2x2-pool(x) + 3x3 conv fc1 -> ta (out-channel quarters)
__global__ __launch_bounds__(256) void kA9(const float* __restrict__ x,
    const float* __restrict__ n1w, const float* __restrict__ n1b,
    const float* __restrict__ mw0, const float* __restrict__ mb0,
    const float* __restrict__ mw1, const float* __restrict__ mb1,
    const float* __restrict__ ip0, const float* __restrict__ ip1,
    const float* __restrict__ fc1w, const float* __restrict__ fc1b,
    float* __restrict__ xmg, float* __restrict__ Vg, float* __restrict__ ta){
  __shared__ union alignas(16) UA {
    struct { float Vl[48*36]; float Wt[48*97]; float mu_s[32]; float rs_s[32]; } a;
    struct { float wl[12*48*9]; float sin_[48*102]; } c;
  } u;
  int tid = threadIdx.x;
  if (blockIdx.x < 512){
    int bd = blockIdx.x >> 7, tile = blockIdx.x & 127;
    int dir = bd >> 1, b = bd & 1;
    int t0 = tile*32;
    const float* ip = dir ? ip1 : ip0;
    const float* mw = dir ? mw1 : mw0;
    const float* mb = dir ? mb1 : mb0;
    for (int i = tid; i < 96*48; i += 256){
      int j = i / 48, c = i % 48;
      u.a.Wt[c*97 + j] = ip[i];
    }
    for (int i = tid; i < 48*32; i += 256){
      int c = i >> 5, r = i & 31;
      int t = t0 + r;
      int h, w;
      if (dir == 0){ h = t >> 6; int wp = t & 63; w = (h & 1) ? 63 - wp : wp; }
      else         { w = t >> 6; int hp = t & 63; h = (w & 1) ? 63 - hp : hp; }
      u.a.Vl[c*36 + r] = x[(size_t)b*48*4096 + c*4096 + h*64 + w];
    }
    __syncthreads();
    {
      int r = tid >> 3, k = tid & 7;
      float s1 = 0.f, s2 = 0.f;
      #pragma unroll
      for (int cc = 0; cc < 6; cc++){
        float v = u.a.Vl[(k*6+cc)*36 + r];
        s1 += v; s2 += v*v;
      }
      s1 += __shfl_xor(s1,1); s2 += __shfl_xor(s2,1);
      s1 += __shfl_xor(s1,2); s2 += __shfl_xor(s2,2);
      s1 += __shfl_xor(s1,4); s2 += __shfl_xor(s2,4);
      if (k == 0){
        float m = s1*(1.f/48.f);
        u.a.mu_s[r] = m;
        u.a.rs_s[r] = rsqrtf(s2*(1.f/48.f) - m*m + 1e-5f);
      }
    }
    __syncthreads();
    for (int i = tid; i < 32*48; i += 256){
      int r = i / 48, c = i % 48;
      int t = t0 + r;
      float v = u.a.Vl[c*36 + r];
      float xn = (v - u.a.mu_s[r])*u.a.rs_s[r]*n1w[c] + n1b[c];
      float ang = (float)t * __expf(-(float)(c & ~1) * (9.210340371976184f/48.f));
      float pe = (c & 1) ? cosf(ang) : sinf(ang);
      u.a.Vl[c*36 + r] = xn + pe;
    }
    __syncthreads();
    {
      int r = tid >> 3, k = tid & 7;
      float s1 = 0.f, s2 = 0.f;
      #pragma unroll
      for (int cc = 0; cc < 6; cc++){
        float v = u.a.Vl[(k*6+cc)*36 + r];
        s1 += v; s2 += v*v;
      }
      s1 += __shfl_xor(s1,1); s2 += __shfl_xor(s2,1);
      s1 += __shfl_xor(s1,2); s2 += __shfl_xor(s2,2);
      s1 += __shfl_xor(s1,4); s2 += __shfl_xor(s2,4);
      if (k == 0){
        float m = s1*(1.f/48.f);
        u.a.mu_s[r] = m;
        u.a.rs_s[r] = rsqrtf(s2*(1.f/48.f) - m*m + 1e-5f);
      }
    }
    __syncthreads();
    for (int i = tid; i < 32*48; i += 256){
      int r = i / 48, c = i % 48;
      float v = u.a.Vl[c*36 + r];
      float v2 = (v - u.a.mu_s[r])*u.a.rs_s[r]*mw[c] + mb[c];
      u.a.Vl[c*36 + r] = v2;
      Vg[((size_t)bd*4096 + t0 + r)*48 + c] = v2;
    }
    __syncthreads();
    for (int k = 0; k < 3; k++){
      int i = tid + k*256;
      int j = i % 96, rb = i / 96;
      float a0=0.f, a1=0.f, a2=0.f, a3=0.f;
      #pragma unroll 4
      for (int c = 0; c < 48; c++){
        float wv = u.a.Wt[c*97 + j];
        const float4 v4 = *(const float4*)&u.a.Vl[c*36 + rb*4];
        a0 += wv*v4.x; a1 += wv*v4.y; a2 += wv*v4.z; a3 += wv*v4.w;
      }
      size_t g = ((size_t)bd*4096 + t0 + rb*4)*96 + j;
      xmg[g] = a0; xmg[g+96] = a1; xmg[g+192] = a2; xmg[g+288] = a3;
    }
  } else {
    // pool + conv1 (fc1), out-channel quarters, 256 blocks
    int bid = blockIdx.x - 512;
    int cq = bid & 3, i0 = (bid >> 2) & 31, b2 = bid >> 7;
    for (int i = tid; i < 12*48*9; i += 256) u.c.wl[i] = fc1w[cq*12*48*9 + i];
    for (int i = tid; i < 48*102; i += 256){
      int jx = i % 34, ky = (i/34) % 3, ci = i/102;
      int r = i0 + ky - 1, j = jx - 1;
      float v = 0.f;
      if (r >= 0 && r < 32 && j >= 0 && j < 32){
        const float* xb = x + (((size_t)b2*48 + ci)*64 + 2*r)*64 + 2*j;
        v = 0.25f*(xb[0] + xb[1] + xb[64] + xb[65]);
      }
      u.c.sin_[i] = v;
    }
    __syncthreads();
    for (int i = tid; i < 12*32; i += 256){
      int j = i & 31, col = i >> 5;
      float acc = fc1b[cq*12 + col];
      for (int ci = 0; ci < 48; ci++){
        const float* wp = u.c.wl + ((size_t)col*48 + ci)*9;
        const float* sp = u.c.sin_ + ci*102;
        #pragma unroll
        for (int ky = 0; ky < 3; ky++)
          #pragma unroll
          for (int kx = 0; kx < 3; kx++)
            acc += sp[ky*34 + j + kx] * wp[ky*3 + kx];
      }
      ta[(((size_t)b2*48 + cq*12 + col)*32 + i0)*32 + j] = acc;
    }
  }
}

// ---------------- kB9: blocks 0..511 = causal conv4+silu + xproj + dt/B/C + scan pass-1
//                  blocks 512..767 = LN(fln1)+ReLU(ta) + 3x3 conv fc2 -> tbuf
__global__ __launch_bounds__(384) void kB9(const float* __restrict__ xmg,
    const float* __restrict__ cwp0, const float* __restrict__ cwp1,
    const float* __restrict__ cbp0, const float* __restrict__ cbp1,
    const float* __restrict__ xpp0, const float* __restrict__ xpp1,
    const float* __restrict__ dwp0, const float* __restrict__ dwp1,
    const float* __restrict__ dbp0, const float* __restrict__ dbp1,
    const float* __restrict__ Alog0, const float* __restrict__ Alog1,
    const float* __restrict__ ta, const float* __restrict__ fc2w, const float* __restrict__ fc2b,
    const float* __restrict__ fln1w, const float* __restrict__ fln1b,
    float* __restrict__ xcg, float* __restrict__ dtg,
    float* __restrict__ Bmg, float* __restrict__ Cmg,
    float* __restrict__ P, float* __restrict__ S, float* __restrict__ tbuf){
  __shared__ union alignas(16) UBB {
    struct {
      float Bl[32*16]; float Cl[32*16];
      union { float xml[96*36]; struct { float xwl[35*96]; float xdbl[35*33]; } p; } ub;
      float xcl[96*33]; float dtl[96*33];
      float cw[96*4]; float cbv[96]; float dwl[96*3]; float dbl[96];
    } b;
    struct { float wl[12*48*9]; float sin_[48*102]; float mu_i[104]; float rs_i[104]; } c;
  } u;
  int tid = threadIdx.x;
  if (blockIdx.x < 512){
    int bd = blockIdx.x >> 7, tile = blockIdx.x & 127;
    int dir = bd >> 1;
    int t0 = tile*32;
    const float* cwp = dir ? cwp1 : cwp0;
    const float* cbp = dir ? cbp1 : cbp0;
    const float* xpp = dir ? xpp1 : xpp0;
    const float* dwp = dir ? dwp1 : dwp0;
    const float* dbp = dir ? dbp1 : dbp0;
    const float* Alog = dir ? Alog1 : Alog0;
    for (int i = tid; i < 35*96; i += 384){
      int tl = i / 96, d = i % 96;
      int t = t0 - 3 + tl;
      u.b.ub.xml[d*36 + tl] = (t >= 0) ? xmg[((size_t)bd*4096 + t)*96 + d] : 0.f;
    }
    for (int i = tid; i < 96*4;  i += 384) u.b.cw[i] = cwp[i];
    for (int i = tid; i < 96*3;  i += 384) u.b.dwl[i] = dwp[i];
    for (int i = tid; i < 96;    i += 384){ u.b.cbv[i] = cbp[i]; u.b.dbl[i] = dbp[i]; }
    __syncthreads();
    for (int i = tid; i < 96*32; i += 384){
      int d = i >> 5, t = i & 31;
      float acc = u.b.cbv[d];
      #pragma unroll
      for (int k = 0; k < 4; k++) acc += u.b.cw[d*4+k]*u.b.ub.xml[d*36 + t + k];
      u.b.xcl[d*33 + t] = siluf(acc);
    }
    __syncthreads();
    for (int i = tid; i < 35*96; i += 384) u.b.ub.p.xwl[i] = xpp[i];
    __syncthreads();
    for (int i = tid; i < 35*32; i += 384){
      int j = i / 32, t = i % 32;
      float acc = 0.f;
      #pragma unroll 4
      for (int d = 0; d < 96; d++) acc += u.b.xcl[d*33 + t]*u.b.ub.p.xwl[j*96 + d];
      u.b.ub.p.xdbl[j*33 + t] = acc;
    }
    __syncthreads();
    for (int i = tid; i < 96*32; i += 384){
      int d = i >> 5, t = i & 31;
      float v = u.b.dbl[d];
      #pragma unroll
      for (int r = 0; r < 3; r++) v += u.b.ub.p.xdbl[r*33 + t]*u.b.dwl[d*3 + r];
      u.b.dtl[d*33 + t] = softplusf(v);
    }
    for (int i = tid; i < 32*16; i += 384){
      int t = i / 16, s = i % 16;
      u.b.Bl[t*16 + s] = u.b.ub.p.xdbl[(3+s)*33 + t];
      u.b.Cl[t*16 + s] = u.b.ub.p.xdbl[(19+s)*33 + t];
    }
    __syncthreads();
    for (int i = tid; i < 32*96; i += 384){
      int t = i / 96, d = i % 96;
      size_t g = ((size_t)bd*4096 + t0 + t)*96 + d;
      xcg[g] = u.b.xcl[d*33 + t];
      dtg[g] = u.b.dtl[d*33 + t];
    }
    for (int i = tid; i < 32*16; i += 384){
      int t = i / 16, s = i % 16;
      size_t g = ((size_t)bd*4096 + t0 + t)*16 + s;
      Bmg[g] = u.b.Bl[t*16 + s];
      Cmg[g] = u.b.Cl[t*16 + s];
    }
    {
      int d = tid >> 2, q = tid & 3;
      float A0 = -__expf(Alog[d*16 + q*4 + 0]);
      float A1 = -__expf(Alog[d*16 + q*4 + 1]);
      float A2 = -__expf(Alog[d*16 + q*4 + 2]);
      float A3 = -__expf(Alog[d*16 + q*4 + 3]);
      float h0=0.f,h1=0.f,h2=0.f,h3=0.f, p0=1.f,p1=1.f,p2=1.f,p3=1.f;
      #pragma unroll 4
      for (int t = 0; t < 32; t++){
        float dtd = u.b.dtl[d*33 + t];
        float uu = dtd * u.b.xcl[d*33 + t];
        const float4 b4 = *(const float4*)&u.b.Bl[t*16 + q*4];
        float a0 = __expf(dtd*A0), a1 = __expf(dtd*A1), a2 = __expf(dtd*A2), a3 = __expf(dtd*A3);
        h0 = a0*h0 + uu*b4.x; p0 *= a0;
        h1 = a1*h1 + uu*b4.y; p1 *= a1;
        h2 = a2*h2 + uu*b4.z; p2 *= a2;
        h3 = a3*h3 + uu*b4.w; p3 *= a3;
      }
      size_t ob = (size_t)blockIdx.x*1536 + d*16 + q*4;
      *(float4*)&P[ob] = make_float4(p0,p1,p2,p3);
      *(float4*)&S[ob] = make_float4(h0,h1,h2,h3);
    }
  } else {
    // LN(fln1)+ReLU on ta, then conv fc2 -> tbuf
    int bid = blockIdx.x - 512;
    int cq = bid & 3, i0 = (bid >> 2) & 31, b2 = bid >> 7;
    for (int i = tid; i < 12*48*9; i += 384) u.c.wl[i] = fc2w[cq*12*48*9 + i];
    for (int i = tid; i < 48*102; i += 384){
      int jx = i % 34, ky = (i/34) % 3, ci = i/102;
      int r = i0 + ky - 1, j = jx - 1;
      float v = 0.f;
      if (r >= 0 && r < 32 && j >= 0 && j < 32)
        v = ta[(((size_t)b2*48 + ci)*32 + r)*32 + j];
      u.c.sin_[i] = v;
    }
    __syncthreads();
    if (tid < 102){
      int jx = tid % 34, ky = tid / 34;
      int r = i0 + ky - 1, j = jx - 1;
      if (r >= 0 && r < 32 && j >= 0 && j < 32){
        float s1 = 0.f, s2 = 0.f;
        #pragma unroll 4
        for (int ci = 0; ci < 48; ci++){ float v = u.c.sin_[ci*102 + tid]; s1 += v; s2 += v*v; }
        float m = s1*(1.f/48.f);
        u.c.mu_i[tid] = m;
        u.c.rs_i[tid] = rsqrtf(s2*(1.f/48.f) - m*m + 1e-5f);
      }
    }
    __syncthreads();
    for (int i = tid; i < 48*102; i += 384){
      int ci = i / 102, p = i % 102;
      int jx = p % 34, ky = p / 34;
      int r = i0 + ky - 1, j = jx - 1;
      if (r >= 0 && r < 32 && j >= 0 && j < 32){
        float v = (u.c.sin_[i] - u.c.mu_i[p])*u.c.rs_i[p]*fln1w[ci] + fln1b[ci];
        u.c.sin_[i] = fmaxf(v, 0.f);
      }
    }
    __syncthreads();
    int j = tid & 31, col = tid >> 5;    // col 0..11
    float acc = fc2b[cq*12 + col];
    for (int ci = 0; ci < 48; ci++){
      const float* wp = u.c.wl + ((size_t)col*48 + ci)*9;
      const float* sp = u.c.sin_ + ci*102;
      #pragma unroll
      for (int ky = 0; ky < 3; ky++)
        #pragma unroll
        for (int kx = 0; kx < 3; kx++)
          acc += sp[ky*34 + j + kx] * wp[ky*3 + kx];
    }
    tbuf[(((size_t)b2*48 + cq*12 + col)*32 + i0)*32 + j] = acc;
  }
}

// ---------------- k4: sequential chunk combine over 128 chunks, IN PLACE (Hin = P).
// 96 blocks x 64 threads (spreads the latency chain over 96 CUs).
__global__ __launch_bounds__(64) void k4_comb(float* __restrict__ P, const float* __restrict__ S){
  int tid2 = blockIdx.x*64 + threadIdx.x;   // 6144 lanes
  int bd = tid2 / 1536, r = tid2 % 1536;
  size_t idx = (size_t)bd*128*1536 + r;
  const int ST = 1536;
  float pb0,pb1,pb2,pb3,pb4,pb5,pb6,pb7, sb0,sb1,sb2,sb3,sb4,sb5,sb6,sb7;
  pb0=P[idx+0*ST]; sb0=S[idx+0*ST]; pb1=P[idx+1*ST]; sb1=S[idx+1*ST];
  pb2=P[idx+2*ST]; sb2=S[idx+2*ST]; pb3=P[idx+3*ST]; sb3=S[idx+3*ST];
  pb4=P[idx+4*ST]; sb4=S[idx+4*ST]; pb5=P[idx+5*ST]; sb5=S[idx+5*ST];
  pb6=P[idx+6*ST]; sb6=S[idx+6*ST]; pb7=P[idx+7*ST]; sb7=S[idx+7*ST];
  float h = 0.f;
  for (int c0 = 0; c0 < 128; c0 += 8){
    float pn0=0,sn0=0,pn1=0,sn1=0,pn2=0,sn2=0,pn3=0,sn3=0;
    float pn4=0,sn4=0,pn5=0,sn5=0,pn6=0,sn6=0,pn7=0,sn7=0;
    if (c0 + 8 < 128){
      pn0=P[idx+(size_t)(c0+8)*ST];  sn0=S[idx+(size_t)(c0+8)*ST];
      pn1=P[idx+(size_t)(c0+9)*ST];  sn1=S[idx+(size_t)(c0+9)*ST];
      pn2=P[idx+(size_t)(c0+10)*ST]; sn2=S[idx+(size_t)(c0+10)*ST];
      pn3=P[idx+(size_t)(c0+11)*ST]; sn3=S[idx+(size_t)(c0+11)*ST];
      pn4=P[idx+(size_t)(c0+12)*ST]; sn4=S[idx+(size_t)(c0+12)*ST];
      pn5=P[idx+(size_t)(c0+13)*ST]; sn5=S[idx+(size_t)(c0+13)*ST];
      pn6=P[idx+(size_t)(c0+14)*ST]; sn6=S[idx+(size_t)(c0+14)*ST];
      pn7=P[idx+(size_t)(c0+15)*ST]; sn7=S[idx+(size_t)(c0+15)*ST];
    }
    P[idx+(size_t)(c0+0)*ST] = h; h = pb0*h + sb0;
    P[idx+(size_t)(c0+1)*ST] = h; h = pb1*h + sb1;
    P[idx+(size_t)(c0+2)*ST] = h; h = pb2*h + sb2;
    P[idx+(size_t)(c0+3)*ST] = h; h = pb3*h + sb3;
    P[idx+(size_t)(c0+4)*ST] = h; h = pb4*h + sb4;
    P[idx+(size_t)(c0+5)*ST] = h; h = pb5*h + sb5;
    P[idx+(size_t)(c0+6)*ST] = h; h = pb6*h + sb6;
    P[idx+(size_t)(c0+7)*ST] = h; h = pb7*h + sb7;
    pb0=pn0;sb0=sn0;pb1=pn1;sb1=sn1;pb2=pn2;sb2=sn2;pb3=pn3;sb3=sn3;
    pb4=pn4;sb4=sn4;pb5=pn5;sb5=sn5;pb6=pn6;sb6=sn6;pb7=pn7;sb7=sn7;
  }
}

// ---------------- k5: pass-3 rescan (+D term) -> yl ; then z GEMV + gate, LDS phase-union.
__global__ __launch_bounds__(384) void k5_scan2(const float* __restrict__ dtg,
    const float* __restrict__ xcg, const float* __restrict__ Bmg, const float* __restrict__ Cmg,
    const float* __restrict__ Alog0, const float* __restrict__ Alog1,
    const float* __restrict__ Dp0, const float* __restrict__ Dp1,
    const float* __restrict__ ip0, const float* __restrict__ ip1,
    const float* __restrict__ Vg, const float* __restrict__ Hin, float* __restrict__ yout){
  __shared__ union U5 {
    struct { float dts[32*96]; float xcs[32*96]; } s;   // scan phase
    struct { float Wzt[48*96]; float Vgs[32*48]; } e;   // epilogue phase
  } u;
  __shared__ alignas(16) float Bl[32*16], Cl[32*16];
  __shared__ float yl[32*96];
  int task = blockIdx.x;
  int bd = task >> 7, ch = task & 127;
  int t0 = ch*32;
  int tid = threadIdx.x;
  const float* ip   = (bd >= 2) ? ip1 : ip0;
  const float* Alog = (bd >= 2) ? Alog1 : Alog0;
  const float* Dp   = (bd >= 2) ? Dp1 : Dp0;
  for (int i = tid; i < 32*96; i += 384){
    int t = i / 96, dd = i % 96;
    size_t g = ((size_t)bd*4096 + t0 + t)*96 + dd;
    u.s.dts[i] = dtg[g];
    u.s.xcs[i] = xcg[g];
  }
  for (int i = tid; i < 32*16; i += 384){
    size_t g = ((size_t)bd*4096 + t0)*16 + i;
    Bl[i] = Bmg[g];
    Cl[i] = Cmg[g];
  }
  __syncthreads();
  {
    int d = tid >> 2, q = tid & 3;
    float A0 = -__expf(Alog[d*16 + q*4 + 0]);
    float A1 = -__expf(Alog[d*16 + q*4 + 1]);
    float A2 = -__expf(Alog[d*16 + q*4 + 2]);
    float A3 = -__expf(Alog[d*16 + q*4 + 3]);
    float Dd = Dp[d];
    const float4 h4 = *(const float4*)&Hin[(size_t)task*1536 + d*16 + q*4];
    float h0 = h4.x, h1 = h4.y, h2 = h4.z, h3 = h4.w;
    for (int t = 0; t < 32; t += 2){
      float dtdA = u.s.dts[t*96 + d];
      float xcvA = u.s.xcs[t*96 + d];
      float dtdB = u.s.dts[(t+1)*96 + d];
      float xcvB = u.s.xcs[(t+1)*96 + d];
      float uA = dtdA * xcvA, uB = dtdB * xcvB;
      const float4 b4A = *(const float4*)&Bl[t*16 + q*4];
      const float4 c4A = *(const float4*)&Cl[t*16 + q*4];
      const float4 b4B = *(const float4*)&Bl[(t+1)*16 + q*4];
      const float4 c4B = *(const float4*)&Cl[(t+1)*16 + q*4];
      float a0 = __expf(dtdA*A0), a1 = __expf(dtdA*A1), a2 = __expf(dtdA*A2), a3 = __expf(dtdA*A3);
      float e0 = __expf(dtdB*A0), e1 = __expf(dtdB*A1), e2 = __expf(dtdB*A2), e3 = __expf(dtdB*A3);
      h0 = a0*h0 + uA*b4A.x;
      h1 = a1*h1 + uA*b4A.y;
      h2 = a2*h2 + uA*b4A.z;
      h3 = a3*h3 + uA*b4A.w;
      float pyA = (h0*c4A.x + h1*c4A.y) + (h2*c4A.z + h3*c4A.w);
      h0 = e0*h0 + uB*b4B.x;
      h1 = e1*h1 + uB*b4B.y;
      h2 = e2*h2 + uB*b4B.z;
      h3 = e3*h3 + uB*b4B.w;
      float pyB = (h0*c4B.x + h1*c4B.y) + (h2*c4B.z + h3*c4B.w);
      pyA += __shfl_xor(pyA, 1);  pyB += __shfl_xor(pyB, 1);
      pyA += __shfl_xor(pyA, 2);  pyB += __shfl_xor(pyB, 2);
      if (q == 0){
        yl[t*96 + d]     = pyA + xcvA*Dd;
        yl[(t+1)*96 + d] = pyB + xcvB*Dd;
      }
    }
  }
  __syncthreads();
  for (int i = tid; i < 96*48; i += 384){
    int j = i % 96, c = i / 96;
    u.e.Wzt[c*96 + j] = ip[(96 + j)*48 + c];
  }
  for (int i = tid; i < 32*48; i += 384){
    int t = i / 48, c = i % 48;
    u.e.Vgs[i] = Vg[((size_t)bd*4096 + t0 + t)*48 + c];
  }
  __syncthreads();
  for (int i = tid; i < 32*96; i += 384){
    int t = i / 96, dd = i % 96;
    float z = 0.f;
    #pragma unroll 4
    for (int c = 0; c < 48; c++) z += u.e.Wzt[c*96 + dd] * u.e.Vgs[t*48 + c];
    size_t g = ((size_t)bd*4096 + t0 + t)*96 + dd;
    yout[g] = yl[i] * siluf(z);
  }
}

// ---------------- k67: w-split 16 (512 blocks x 384 thr): un-snake + outproj + residual -> xmid ; LN(n2)+pin -> xp
__global__ __launch_bounds__(384) void k67_mid(const float* __restrict__ x,
    const float* __restrict__ y1, const float* __restrict__ y2,
    const float* __restrict__ op1, const float* __restrict__ op2,
    const float* __restrict__ nw, const float* __restrict__ nb,
    const float* __restrict__ pin,
    float* __restrict__ xmid, float* __restrict__ xp){
  __shared__ float bufW[192*49];        // op view: [48][97]; pin view: [192][49]
  __shared__ union UL { float ylds[16*97]; struct { float xl[48*17]; float mu[16]; float rs[16]; } l; } ul;
  int bid = blockIdx.x;                 // b*256 + h*4 + wq
  int b = bid >> 8, h = (bid >> 2) & 63, wq = bid & 3;
  int w0 = wq << 4;
  int tid = threadIdx.x;
  int w = tid & 15, cg = tid >> 4;      // cg 0..23, 2 channels each
  float acc0 = 0.f, acc1 = 0.f;
  for (int pass = 0; pass < 2; pass++){
    __syncthreads();
    const float* op = pass ? op2 : op1;
    const float* y  = pass ? y2  : y1;
    for (int i = tid; i < 48*96; i += 384){
      int c = i / 96, d = i % 96;
      bufW[c*97 + d] = op[i];
    }
    if (pass == 0){
      for (int i = tid; i < 16*96; i += 384){
        int wl_ = i / 96, d = i % 96;
        int wsp = w0 + wl_;
        int wp = (h & 1) ? 63 - wsp : wsp;
        ul.ylds[wl_*97 + d] = y[((size_t)b*4096 + h*64 + wp)*96 + d];
      }
    } else {
      for (int i = tid; i < 16*96; i += 384){
        int wl_ = i / 96, d = i % 96;
        int wsp = w0 + wl_;
        int t = wsp*64 + ((wsp & 1) ? 63 - h : h);
        ul.ylds[wl_*97 + d] = y[((size_t)b*4096 + t)*96 + d];
      }
    }
    __syncthreads();
    #pragma unroll 4
    for (int d = 0; d < 96; d++){
      float yv = ul.ylds[w*97 + d];
      acc0 += yv * bufW[(cg*2+0)*97 + d];
      acc1 += yv * bufW[(cg*2+1)*97 + d];
    }
  }
  __syncthreads();   // GEMVs done: safe to overwrite ylds and bufW
  {
    int c0 = cg*2;
    size_t idx0 = (((size_t)b*48 + c0)*64 + h)*64 + w0 + w;
    float v0 = x[idx0] + acc0;
    xmid[idx0] = v0;
    ul.l.xl[c0*17 + w] = v0;
    size_t idx1 = idx0 + 4096;
    float v1 = x[idx1] + acc1;
    xmid[idx1] = v1;
    ul.l.xl[(c0+1)*17 + w] = v1;
  }
  for (int i = tid; i < 192*48; i += 384){
    int r = i / 48, c = i % 48;
    bufW[r*49 + c] = pin[i];
  }
  __syncthreads();
  if (tid < 128){
    int r = tid >> 3, k = tid & 7;
    float s1 = 0.f, s2 = 0.f;
    #pragma unroll
    for (int cc = 0; cc < 6; cc++){
      float v = ul.l.xl[(k*6+cc)*17 + r];
      s1 += v; s2 += v*v;
    }
    s1 += __shfl_xor(s1,1); s2 += __shfl_xor(s2,1);
    s1 += __shfl_xor(s1,2); s2 += __shfl_xor(s2,2);
    s1 += __shfl_xor(s1,4); s2 += __shfl_xor(s2,4);
    if (k == 0){
      float m = s1*(1.f/48.f);
      ul.l.mu[r] = m;
      ul.l.rs[r] = rsqrtf(s2*(1.f/48.f) - m*m + 1e-5f);
    }
  }
  __syncthreads();
  for (int i = tid; i < 48*16; i += 384){
    int c = i >> 4, ww = i & 15;
    ul.l.xl[c*17 + ww] = (ul.l.xl[c*17 + ww] - ul.l.mu[ww])*ul.l.rs[ww]*nw[c] + nb[c];
  }
  __syncthreads();
  for (int it = 0; it < 2; it++){
    int i = tid + it*384;
    int ww = i & 15, oq = i >> 4;   // oq 0..47
    int o0 = oq*4;
    float a0=0,a1=0,a2=0,a3=0;
    #pragma unroll 4
    for (int c = 0; c < 48; c++){
      float xv = ul.l.xl[c*17 + ww];
      a0 += xv*bufW[(o0+0)*49 + c];
      a1 += xv*bufW[(o0+1)*49 + c];
      a2 += xv*bufW[(o0+2)*49 + c];
      a3 += xv*bufW[(o0+3)*49 + c];
    }
    xp[(((size_t)b*192 + o0+0)*64 + h)*64 + w0 + ww] = a0;
    xp[(((size_t)b*192 + o0+1)*64 + h)*64 + w0 + ww] = a1;
    xp[(((size_t)b*192 + o0+2)*64 + h)*64 + w0 + ww] = a2;
    xp[(((size_t)b*192 + o0+3)*64 + h)*64 + w0 + ww] = a3;
  }
}

// ---------------- K13: depthwise 3x3, pad 1, CH channels, 64x64; 4 outputs/thread along w
__global__ __launch_bounds__(256) void k13_dw(const float* __restrict__ in,
    const float* __restrict__ wgt, float* __restrict__ out, int CH){
  int idx = blockIdx.x*256 + threadIdx.x;
  if (idx >= 2*CH*1024) return;
  int wq = idx & 15, h = (idx >> 4) & 63, c = (idx >> 10) % CH, b = idx / (CH*1024);
  int w0 = wq*4;
  const float* ip = in + ((size_t)b*CH + c)*4096;
  const float* wp = wgt + c*9;
  float a0=0.f,a1=0.f,a2=0.f,a3=0.f;
  #pragma unroll
  for (int ky = 0; ky < 3; ky++){
    int hh = h + ky - 1;
    if (hh < 0 || hh > 63) continue;
    const float* rp = ip + hh*64;
    float v0 = (w0 > 0)  ? rp[w0-1] : 0.f;
    float v1 = rp[w0+0], v2 = rp[w0+1], v3 = rp[w0+2], v4 = rp[w0+3];
    float v5 = (w0 < 60) ? rp[w0+4] : 0.f;
    float k0 = wp[ky*3+0], k1 = wp[ky*3+1], k2 = wp[ky*3+2];
    a0 += k0*v0 + k1*v1 + k2*v2;
    a1 += k0*v1 + k1*v2 + k2*v3;
    a2 += k0*v2 + k1*v3 + k2*v4;
    a3 += k0*v3 + k1*v4 + k2*v5;
  }
  float* op = out + (((size_t)b*CH + c)*64 + h)*64 + w0;
  op[0]=a0; op[1]=a1; op[2]=a2; op[3]=a3;
}

// ---------------- K14: w-split 32 (512 blocks x 256 thr): 1x1 f_fus over concat(xd[:96], up(relu(ln(cv2)))) -> x1
__global__ __launch_bounds__(256) void k14_fus(const float* __restrict__ xd,
    const float* __restrict__ cv2, const float* __restrict__ lnw, const float* __restrict__ lnb,
    const float* __restrict__ fus, float* __restrict__ x1){
  __shared__ float wl[48*144];
  __shared__ float al[96*33];
  __shared__ float yl[48*17];
  __shared__ float muy[16], rsy[16];
  int bid = blockIdx.x;              // ((b*2 + oh)*64 + h)*2 + wh
  int wh = bid & 1, h = (bid >> 1) & 63, oh = (bid >> 7) & 1, b = bid >> 8;
  int w0 = wh << 5;
  int tid = threadIdx.x;
  for (int i = tid; i < 48*144; i += 256) wl[i] = fus[(size_t)oh*48*144 + i];
  for (int i = tid; i < 96*32; i += 256){
    int ci = i >> 5, w = i & 31;
    al[ci*33 + w] = xd[(((size_t)b*192 + ci)*64 + h)*64 + w0 + w];
  }
  {
    int hp = h >> 1, j0 = w0 >> 1;
    for (int i = tid; i < 48*16; i += 256){
      int cj = i >> 4, jl = i & 15;
      yl[cj*17 + jl] = cv2[(((size_t)b*48 + cj)*32 + hp)*32 + j0 + jl];
    }
  }
  __syncthreads();
  if (tid < 16){
    float s1 = 0.f, s2 = 0.f;
    #pragma unroll 4
    for (int cj = 0; cj < 48; cj++){ float v = yl[cj*17 + tid]; s1 += v; s2 += v*v; }
    float m = s1*(1.f/48.f);
    muy[tid] = m;
    rsy[tid] = rsqrtf(s2*(1.f/48.f) - m*m + 1e-5f);
  }
  __syncthreads();
  for (int i = tid; i < 48*16; i += 256){
    int cj = i >> 4, jl = i & 15;
    yl[cj*17 + jl] = fmaxf((yl[cj*17 + jl] - muy[jl])*rsy[jl]*lnw[cj] + lnb[cj], 0.f);
  }
  __syncthreads();
  for (int it = 0; it < 2; it++){
    int i = tid + it*256;
    int w = i & 31, og = i >> 5;   // og 0..15, 3 outputs each
    int o0 = og*3;
    float a0=0.f, a1=0.f, a2=0.f;
    #pragma unroll 4
    for (int ci = 0; ci < 96; ci++){
      float xv = al[ci*33 + w];
      a0 += xv * wl[(o0+0)*144 + ci];
      a1 += xv * wl[(o0+1)*144 + ci];
      a2 += xv * wl[(o0+2)*144 + ci];
    }
    int jl = w >> 1;
    #pragma unroll 4
    for (int cj = 0; cj < 48; cj++){
      float yv = yl[cj*17 + jl];
      a0 += yv * wl[(o0+0)*144 + 96 + cj];
      a1 += yv * wl[(o0+1)*144 + 96 + cj];
      a2 += yv * wl[(o0+2)*144 + 96 + cj];
    }
    x1[(((size_t)b*96 + oh*48 + o0+0)*64 + h)*64 + w0 + w] = a0;
    x1[(((size_t)b*96 + oh*48 + o0+1)*64 + h)*64 + w0 + w] = a1;
    x1[(((size_t)b*96 + oh*48 + o0+2)*64 + h)*64 + w0 + w] = a2;
  }
}

// ---------------- K16: w-split 16 (512 blocks x 384 thr): fused dwa 3x3 on x1 -> gelu * x2 -> pout GEMV -> + xmid -> out
__global__ __launch_bounds__(384) void k16_out(const float* __restrict__ x1,
    const float* __restrict__ xd, const float* __restrict__ dww,
    const float* __restrict__ pout, const float* __restrict__ xmid, float* __restrict__ out){
  __shared__ float wl[48*97];        // padded pout
  __shared__ float xs[96*54];        // [ch][ky 0..2][jx 0..17]
  __shared__ float gl[96*17];
  __shared__ float dwl[96*9];
  int bid = blockIdx.x;              // b*256 + h*4 + wq
  int b = bid >> 8, h = (bid >> 2) & 63, wq = bid & 3;
  int w0 = wq << 4;
  int tid = threadIdx.x;
  for (int i = tid; i < 48*96; i += 384){
    int r = i / 96, c = i % 96;
    wl[r*97 + c] = pout[i];
  }
  for (int i = tid; i < 96*9; i += 384) dwl[i] = dww[i];
  for (int i = tid; i < 96*54; i += 384){
    int jx = i % 18, ky = (i/18) % 3, ch = i/54;
    int hh = h + ky - 1, ww_ = w0 + jx - 1;
    float v = 0.f;
    if (hh >= 0 && hh < 64 && ww_ >= 0 && ww_ < 64)
      v = x1[(((size_t)b*96 + ch)*64 + hh)*64 + ww_];
    xs[i] = v;
  }
  __syncthreads();
  for (int i = tid; i < 96*16; i += 384){
    int ch = i >> 4, ww = i & 15;
    const float* wp = dwl + ch*9;
    const float* sp = xs + ch*54;
    float a = 0.f;
    #pragma unroll
    for (int ky = 0; ky < 3; ky++)
      #pragma unroll
      for (int kx = 0; kx < 3; kx++)
        a += sp[ky*18 + ww + kx] * wp[ky*3 + kx];
    float x2 = xd[(((size_t)b*192 + 96 + ch)*64 + h)*64 + w0 + ww];
    gl[ch*17 + ww] = geluf(a) * x2;
  }
  __syncthreads();
  int ww = tid & 15, cg = tid >> 4;  // cg 0..23, 2 channels each
  float a0=0.f, a1=0.f;
  #pragma unroll 4
  for (int ch = 0; ch < 96; ch++){
    float gv = gl[ch*17 + ww];
    a0 += gv * wl[(cg*2+0)*97 + ch];
    a1 += gv * wl[(cg*2+1)*97 + ch];
  }
  {
    int c0 = cg*2;
    size_t idx0 = (((size_t)b*48 + c0)*64 + h)*64 + w0 + ww;
    out[idx0] = xmid[idx0] + a0;
    size_t idx1 = idx0 + 4096;
    out[idx1] = xmid[idx1] + a1;
  }
}

extern "C" void kernel_launch(void* const* d_in, const int* in_sizes, int n_in,
                              void* d_out, int out_size, void* d_ws, size_t ws_size,
                              hipStream_t stream){
  (void)in_sizes; (void)n_in; (void)out_size; (void)ws_size;
  const float* x    = (const float*)d_in[0];
  const float* n1w  = (const float*)d_in[1];
  const float* n1b  = (const float*)d_in[2];
  const float* n2w  = (const float*)d_in[3];
  const float* n2b  = (const float*)d_in[4];
  const float* mlnw[2] = {(const float*)d_in[5], (const float*)d_in[7]};
  const float* mlnb[2] = {(const float*)d_in[6], (const float*)d_in[8]};
  const float* fln1w = (const float*)d_in[9];
  const float* fln1b = (const float*)d_in[10];
  const float* fln2w = (const float*)d_in[11];
  const float* fln2b = (const float*)d_in[12];
  const float* inproj[2]  = {(const float*)d_in[13], (const float*)d_in[22]};
  const float* convw[2]   = {(const float*)d_in[14], (const float*)d_in[23]};
  const float* convb[2]   = {(const float*)d_in[15], (const float*)d_in[24]};
  const float* xproj[2]   = {(const float*)d_in[16], (const float*)d_in[25]};
  const float* dtw[2]     = {(const float*)d_in[17], (const float*)d_in[26]};
  const float* dtbp[2]    = {(const float*)d_in[18], (const float*)d_in[27]};
  const float* Alog[2]    = {(const float*)d_in[19], (const float*)d_in[28]};
  const float* Dp[2]      = {(const float*)d_in[20], (const float*)d_in[29]};
  const float* outproj[2] = {(const float*)d_in[21], (const float*)d_in[30]};
  const float* fpin  = (const float*)d_in[31];
  const float* fdw   = (const float*)d_in[32];
  const float* ffus  = (const float*)d_in[33];
  const float* fdwa  = (const float*)d_in[34];
  const float* fpout = (const float*)d_in[35];
  const float* fc1w  = (const float*)d_in[36];
  const float* fc1b  = (const float*)d_in[37];
  const float* fc2w  = (const float*)d_in[38];
  const float* fc2b  = (const float*)d_in[39];

  // workspace (floats), total 7,995,392 (= 32.0 MB)
  float* ws = (float*)d_ws;
  float* xmg = ws + 0;         // (4,4096,96)  -> later yall
  float* Vgb = ws + 1572864;   // (4,4096,48)
  float* xcg = ws + 2359296;   // (4,4096,96)  -> later xpb (B,192,64,64)
  float* dtg = ws + 3932160;   // (4,4096,96)  -> later xdb
  float* Bmg = ws + 5505024;   // (4,4096,16)
  float* Cmg = ws + 5767168;   // (4,4096,16)
  float* Pb  = ws + 6029312;   // (512,1536)   -> Hin in-place, later x1b
  float* Sb  = ws + 6815744;   // (512,1536)
  float* xmid= ws + 7602176;   // (B,48,64,64)
  float* yall = xmg;
  float* Hin  = Pb;
  float* xpb  = xcg;
  float* xdb  = dtg;
  float* x1b  = Pb;
  // conv-chain temporaries live in d_out (dead until the final k16 write):
  float* outf = (float*)d_out;
  float* ta   = outf;            // (B,48,32,32) = 98,304 floats
  float* tbuf = outf + 98304;    // (B,48,32,32)

  kA9<<<768,256,0,stream>>>(x, n1w, n1b,
      mlnw[0], mlnb[0], mlnw[1], mlnb[1], inproj[0], inproj[1],
      fc1w, fc1b, xmg, Vgb, ta);
  kB9<<<768,384,0,stream>>>(xmg,
      convw[0], convw[1], convb[0], convb[1], xproj[0], xproj[1],
      dtw[0], dtw[1], dtbp[0], dtbp[1], Alog[0], Alog[1],
      ta, fc2w, fc2b, fln1w, fln1b,
      xcg, dtg, Bmg, Cmg, Pb, Sb, tbuf);
  k4_comb  <<<96,64,0,stream>>>(Pb, Sb);
  k5_scan2 <<<512,384,0,stream>>>(dtg, xcg, Bmg, Cmg, Alog[0], Alog[1],
      Dp[0], Dp[1], inproj[0], inproj[1], Vgb, Hin, yall);
  k67_mid  <<<512,384,0,stream>>>(x, yall, yall + 786432, outproj[0], outproj[1],
      n2w, n2b, fpin, xmid, xpb);
  k13_dw   <<<1536,256,0,stream>>>(xpb, fdw, xdb, 192);
  k14_fus  <<<512,256,0,stream>>>(xdb, tbuf, fln2w, fln2b, ffus, x1b);
  k16_out  <<<512,384,0,stream>>>(x1b, xdb, fdwa, fpout, xmid, (float*)d_out);
}

// Round 16
// 156.984 us; speedup vs baseline: 1.3308x; 1.0397x over previous
//
#include <hip/hip_runtime.h>

// SBSM block: B=2, C=48, H=W=64, L=4096, DI=96, DS=16, DCONV=4, DTR=3, HF=96
#define DEV __device__ __forceinline__

DEV float siluf(float x){ return x / (1.f + __expf(-x)); }
DEV float softplusf(float x){ return fmaxf(x, 0.f) + log1pf(expf(-fabsf(x))); }
DEV float geluf(float x){ return 0.5f * x * (1.f + erff(x * 0.70710678118654752440f)); }

// ---------------- kA9: blocks 0..511 = snake gather + LN(n1) + posenc + LN(mln) -> Vg ; inproj xm-half -> xmg
//                  blocks 512..767 = 2x2-pool(x) + 3x3 conv fc1 -> ta (out-channel quarters)
__global__ __launch_bounds__(256) void kA9(const float* __restrict__ x,
    const float* __restrict__ n1w, const float* __restrict__ n1b,
    const float* __restrict__ mw0, const float* __restrict__ mb0,
    const float* __restrict__ mw1, const float* __restrict__ mb1,
    const float* __restrict__ ip0, const float* __restrict__ ip1,
    const float* __restrict__ fc1w, const float* __restrict__ fc1b,
    float* __restrict__ xmg, float* __restrict__ Vg, float* __restrict__ ta){
  __shared__ union alignas(16) UA {
    struct { float Vl[48*36]; float Wt[48*97]; float mu_s[32]; float rs_s[32]; } a;
    struct { float wl[12*48*9]; float sin_[48*102]; } c;
  } u;
  int tid = threadIdx.x;
  if (blockIdx.x < 512){
    int bd = blockIdx.x >> 7, tile = blockIdx.x & 127;
    int dir = bd >> 1, b = bd & 1;
    int t0 = tile*32;
    const float* ip = dir ? ip1 : ip0;
    const float* mw = dir ? mw1 : mw0;
    const float* mb = dir ? mb1 : mb0;
    for (int i = tid; i < 96*48; i += 256){
      int j = i / 48, c = i % 48;
      u.a.Wt[c*97 + j] = ip[i];
    }
    for (int i = tid; i < 48*32; i += 256){
      int c = i >> 5, r = i & 31;
      int t = t0 + r;
      int h, w;
      if (dir == 0){ h = t >> 6; int wp = t & 63; w = (h & 1) ? 63 - wp : wp; }
      else         { w = t >> 6; int hp = t & 63; h = (w & 1) ? 63 - hp : hp; }
      u.a.Vl[c*36 + r] = x[(size_t)b*48*4096 + c*4096 + h*64 + w];
    }
    __syncthreads();
    {
      int r = tid >> 3, k = tid & 7;
      float s1 = 0.f, s2 = 0.f;
      #pragma unroll
      for (int cc = 0; cc < 6; cc++){
        float v = u.a.Vl[(k*6+cc)*36 + r];
        s1 += v; s2 += v*v;
      }
      s1 += __shfl_xor(s1,1); s2 += __shfl_xor(s2,1);
      s1 += __shfl_xor(s1,2); s2 += __shfl_xor(s2,2);
      s1 += __shfl_xor(s1,4); s2 += __shfl_xor(s2,4);
      if (k == 0){
        float m = s1*(1.f/48.f);
        u.a.mu_s[r] = m;
        u.a.rs_s[r] = rsqrtf(s2*(1.f/48.f) - m*m + 1e-5f);
      }
    }
    __syncthreads();
    for (int i = tid; i < 32*48; i += 256){
      int r = i / 48, c = i % 48;
      int t = t0 + r;
      float v = u.a.Vl[c*36 + r];
      float xn = (v - u.a.mu_s[r])*u.a.rs_s[r]*n1w[c] + n1b[c];
      float ang = (float)t * __expf(-(float)(c & ~1) * (9.210340371976184f/48.f));
      float pe = (c & 1) ? cosf(ang) : sinf(ang);
      u.a.Vl[c*36 + r] = xn + pe;
    }
    __syncthreads();
    {
      int r = tid >> 3, k = tid & 7;
      float s1 = 0.f, s2 = 0.f;
      #pragma unroll
      for (int cc = 0; cc < 6; cc++){
        float v = u.a.Vl[(k*6+cc)*36 + r];
        s1 += v; s2 += v*v;
      }
      s1 += __shfl_xor(s1,1); s2 += __shfl_xor(s2,1);
      s1 += __shfl_xor(s1,2); s2 += __shfl_xor(s2,2);
      s1 += __shfl_xor(s1,4); s2 += __shfl_xor(s2,4);
      if (k == 0){
        float m = s1*(1.f/48.f);
        u.a.mu_s[r] = m;
        u.a.rs_s[r] = rsqrtf(s2*(1.f/48.f) - m*m + 1e-5f);
      }
    }
    __syncthreads();
    for (int i = tid; i < 32*48; i += 256){
      int r = i / 48, c = i % 48;
      float v = u.a.Vl[c*36 + r];
      float v2 = (v - u.a.mu_s[r])*u.a.rs_s[r]*mw[c] + mb[c];
      u.a.Vl[c*36 + r] = v2;
      Vg[((size_t)bd*4096 + t0 + r)*48 + c] = v2;
    }
    __syncthreads();
    for (int k = 0; k < 3; k++){
      int i = tid + k*256;
      int j = i % 96, rb = i / 96;
      float a0=0.f, a1=0.f, a2=0.f, a3=0.f;
      #pragma unroll 4
      for (int c = 0; c < 48; c++){
        float wv = u.a.Wt[c*97 + j];
        const float4 v4 = *(const float4*)&u.a.Vl[c*36 + rb*4];
        a0 += wv*v4.x; a1 += wv*v4.y; a2 += wv*v4.z; a3 += wv*v4.w;
      }
      size_t g = ((size_t)bd*4096 + t0 + rb*4)*96 + j;
      xmg[g] = a0; xmg[g+96] = a1; xmg[g+192] = a2; xmg[g+288] = a3;
    }
  } else {
    // pool + conv1 (fc1), out-channel quarters, 256 blocks
    int bid = blockIdx.x - 512;
    int cq = bid & 3, i0 = (bid >> 2) & 31, b2 = bid >> 7;
    for (int i = tid; i < 12*48*9; i += 256) u.c.wl[i] = fc1w[cq*12*48*9 + i];
    for (int i = tid; i < 48*102; i += 256){
      int jx = i % 34, ky = (i/34) % 3, ci = i/102;
      int r = i0 + ky - 1, j = jx - 1;
      float v = 0.f;
      if (r >= 0 && r < 32 && j >= 0 && j < 32){
        const float* xb = x + (((size_t)b2*48 + ci)*64 + 2*r)*64 + 2*j;
        v = 0.25f*(xb[0] + xb[1] + xb[64] + xb[65]);
      }
      u.c.sin_[i] = v;
    }
    __syncthreads();
    for (int i = tid; i < 12*32; i += 256){
      int j = i & 31, col = i >> 5;
      float acc = fc1b[cq*12 + col];
      for (int ci = 0; ci < 48; ci++){
        const float* wp = u.c.wl + ((size_t)col*48 + ci)*9;
        const float* sp = u.c.sin_ + ci*102;
        #pragma unroll
        for (int ky = 0; ky < 3; ky++)
          #pragma unroll
          for (int kx = 0; kx < 3; kx++)
            acc += sp[ky*34 + j + kx] * wp[ky*3 + kx];
      }
      ta[(((size_t)b2*48 + cq*12 + col)*32 + i0)*32 + j] = acc;
    }
  }
}

// ---------------- kB9: blocks 0..511 = causal conv4+silu + xproj(float4) + dt/B/C + scan pass-1
//                  blocks 512..767 = LN(fln1)+ReLU(ta) + 3x3 conv fc2 -> tbuf
__global__ __launch_bounds__(384) void kB9(const float* __restrict__ xmg,
    const float* __restrict__ cwp0, const float* __restrict__ cwp1,
    const float* __restrict__ cbp0, const float* __restrict__ cbp1,
    const float* __restrict__ xpp0, const float* __restrict__ xpp1,
    const float* __restrict__ dwp0, const float* __restrict__ dwp1,
    const float* __restrict__ dbp0, const float* __restrict__ dbp1,
    const float* __restrict__ Alog0, const float* __restrict__ Alog1,
    const float* __restrict__ ta, const float* __restrict__ fc2w, const float* __restrict__ fc2b,
    const float* __restrict__ fln1w, const float* __restrict__ fln1b,
    float* __restrict__ xcg, float* __restrict__ dtg,
    float* __restrict__ Bmg, float* __restrict__ Cmg,
    float* __restrict__ P, float* __restrict__ S, float* __restrict__ tbuf){
  __shared__ union alignas(16) UBB {
    struct {
      float Bl[32*16]; float Cl[32*16];
      union { float xml[96*36]; struct { float xwl[35*96]; float xdbl[35*33]; } p; } ub;
      alignas(16) float xcl[96*36];     // padded for float4 t-quad reads
      float dtl[96*33];
      float cw[96*4]; float cbv[96]; float dwl[96*3]; float dbl[96];
    } b;
    struct { float wl[12*48*9]; float sin_[48*102]; float mu_i[104]; float rs_i[104]; } c;
  } u;
  int tid = threadIdx.x;
  if (blockIdx.x < 512){
    int bd = blockIdx.x >> 7, tile = blockIdx.x & 127;
    int dir = bd >> 1;
    int t0 = tile*32;
    const float* cwp = dir ? cwp1 : cwp0;
    const float* cbp = dir ? cbp1 : cbp0;
    const float* xpp = dir ? xpp1 : xpp0;
    const float* dwp = dir ? dwp1 : dwp0;
    const float* dbp = dir ? dbp1 : dbp0;
    const float* Alog = dir ? Alog1 : Alog0;
    for (int i = tid; i < 35*96; i += 384){
      int tl = i / 96, d = i % 96;
      int t = t0 - 3 + tl;
      u.b.ub.xml[d*36 + tl] = (t >= 0) ? xmg[((size_t)bd*4096 + t)*96 + d] : 0.f;
    }
    for (int i = tid; i < 96*4;  i += 384) u.b.cw[i] = cwp[i];
    for (int i = tid; i < 96*3;  i += 384) u.b.dwl[i] = dwp[i];
    for (int i = tid; i < 96;    i += 384){ u.b.cbv[i] = cbp[i]; u.b.dbl[i] = dbp[i]; }
    __syncthreads();
    for (int i = tid; i < 96*32; i += 384){
      int d = i >> 5, t = i & 31;
      float acc = u.b.cbv[d];
      #pragma unroll
      for (int k = 0; k < 4; k++) acc += u.b.cw[d*4+k]*u.b.ub.xml[d*36 + t + k];
      u.b.xcl[d*36 + t] = siluf(acc);
    }
    __syncthreads();
    for (int i = tid; i < 35*96; i += 384) u.b.ub.p.xwl[i] = xpp[i];
    __syncthreads();
    // xproj (96 -> 35), float4 over t-quads: 35 j x 8 tq = 280 tasks
    if (tid < 280){
      int j = tid / 8, tq = tid % 8;
      float a0=0.f, a1=0.f, a2=0.f, a3=0.f;
      #pragma unroll 4
      for (int d = 0; d < 96; d++){
        float wv = u.b.ub.p.xwl[j*96 + d];
        const float4 v4 = *(const float4*)&u.b.xcl[d*36 + tq*4];
        a0 += wv*v4.x; a1 += wv*v4.y; a2 += wv*v4.z; a3 += wv*v4.w;
      }
      int t = tq*4;
      u.b.ub.p.xdbl[j*33 + t+0] = a0;
      u.b.ub.p.xdbl[j*33 + t+1] = a1;
      u.b.ub.p.xdbl[j*33 + t+2] = a2;
      u.b.ub.p.xdbl[j*33 + t+3] = a3;
    }
    __syncthreads();
    for (int i = tid; i < 96*32; i += 384){
      int d = i >> 5, t = i & 31;
      float v = u.b.dbl[d];
      #pragma unroll
      for (int r = 0; r < 3; r++) v += u.b.ub.p.xdbl[r*33 + t]*u.b.dwl[d*3 + r];
      u.b.dtl[d*33 + t] = softplusf(v);
    }
    for (int i = tid; i < 32*16; i += 384){
      int t = i / 16, s = i % 16;
      u.b.Bl[t*16 + s] = u.b.ub.p.xdbl[(3+s)*33 + t];
      u.b.Cl[t*16 + s] = u.b.ub.p.xdbl[(19+s)*33 + t];
    }
    __syncthreads();
    for (int i = tid; i < 32*96; i += 384){
      int t = i / 96, d = i % 96;
      size_t g = ((size_t)bd*4096 + t0 + t)*96 + d;
      xcg[g] = u.b.xcl[d*36 + t];
      dtg[g] = u.b.dtl[d*33 + t];
    }
    for (int i = tid; i < 32*16; i += 384){
      int t = i / 16, s = i % 16;
      size_t g = ((size_t)bd*4096 + t0 + t)*16 + s;
      Bmg[g] = u.b.Bl[t*16 + s];
      Cmg[g] = u.b.Cl[t*16 + s];
    }
    {
      int d = tid >> 2, q = tid & 3;
      float A0 = -__expf(Alog[d*16 + q*4 + 0]);
      float A1 = -__expf(Alog[d*16 + q*4 + 1]);
      float A2 = -__expf(Alog[d*16 + q*4 + 2]);
      float A3 = -__expf(Alog[d*16 + q*4 + 3]);
      float h0=0.f,h1=0.f,h2=0.f,h3=0.f, p0=1.f,p1=1.f,p2=1.f,p3=1.f;
      #pragma unroll 4
      for (int t = 0; t < 32; t++){
        float dtd = u.b.dtl[d*33 + t];
        float uu = dtd * u.b.xcl[d*36 + t];
        const float4 b4 = *(const float4*)&u.b.Bl[t*16 + q*4];
        float a0 = __expf(dtd*A0), a1 = __expf(dtd*A1), a2 = __expf(dtd*A2), a3 = __expf(dtd*A3);
        h0 = a0*h0 + uu*b4.x; p0 *= a0;
        h1 = a1*h1 + uu*b4.y; p1 *= a1;
        h2 = a2*h2 + uu*b4.z; p2 *= a2;
        h3 = a3*h3 + uu*b4.w; p3 *= a3;
      }
      size_t ob = (size_t)blockIdx.x*1536 + d*16 + q*4;
      *(float4*)&P[ob] = make_float4(p0,p1,p2,p3);
      *(float4*)&S[ob] = make_float4(h0,h1,h2,h3);
    }
  } else {
    // LN(fln1)+ReLU on ta, then conv fc2 -> tbuf
    int bid = blockIdx.x - 512;
    int cq = bid & 3, i0 = (bid >> 2) & 31, b2 = bid >> 7;
    for (int i = tid; i < 12*48*9; i += 384) u.c.wl[i] = fc2w[cq*12*48*9 + i];
    for (int i = tid; i < 48*102; i += 384){
      int jx = i % 34, ky = (i/34) % 3, ci = i/102;
      int r = i0 + ky - 1, j = jx - 1;
      float v = 0.f;
      if (r >= 0 && r < 32 && j >= 0 && j < 32)
        v = ta[(((size_t)b2*48 + ci)*32 + r)*32 + j];
      u.c.sin_[i] = v;
    }
    __syncthreads();
    if (tid < 102){
      int jx = tid % 34, ky = tid / 34;
      int r = i0 + ky - 1, j = jx - 1;
      if (r >= 0 && r < 32 && j >= 0 && j < 32){
        float s1 = 0.f, s2 = 0.f;
        #pragma unroll 4
        for (int ci = 0; ci < 48; ci++){ float v = u.c.sin_[ci*102 + tid]; s1 += v; s2 += v*v; }
        float m = s1*(1.f/48.f);
        u.c.mu_i[tid] = m;
        u.c.rs_i[tid] = rsqrtf(s2*(1.f/48.f) - m*m + 1e-5f);
      }
    }
    __syncthreads();
    for (int i = tid; i < 48*102; i += 384){
      int ci = i / 102, p = i % 102;
      int jx = p % 34, ky = p / 34;
      int r = i0 + ky - 1, j = jx - 1;
      if (r >= 0 && r < 32 && j >= 0 && j < 32){
        float v = (u.c.sin_[i] - u.c.mu_i[p])*u.c.rs_i[p]*fln1w[ci] + fln1b[ci];
        u.c.sin_[i] = fmaxf(v, 0.f);
      }
    }
    __syncthreads();
    int j = tid & 31, col = tid >> 5;    // col 0..11
    float acc = fc2b[cq*12 + col];
    for (int ci = 0; ci < 48; ci++){
      const float* wp = u.c.wl + ((size_t)col*48 + ci)*9;
      const float* sp = u.c.sin_ + ci*102;
      #pragma unroll
      for (int ky = 0; ky < 3; ky++)
        #pragma unroll
        for (int kx = 0; kx < 3; kx++)
          acc += sp[ky*34 + j + kx] * wp[ky*3 + kx];
    }
    tbuf[(((size_t)b2*48 + cq*12 + col)*32 + i0)*32 + j] = acc;
  }
}

// ---------------- k4: sequential chunk combine over 128 chunks, IN PLACE (Hin = P).
__global__ __launch_bounds__(64) void k4_comb(float* __restrict__ P, const float* __restrict__ S){
  int tid2 = blockIdx.x*64 + threadIdx.x;   // 6144 lanes
  int bd = tid2 / 1536, r = tid2 % 1536;
  size_t idx = (size_t)bd*128*1536 + r;
  const int ST = 1536;
  float pb0,pb1,pb2,pb3,pb4,pb5,pb6,pb7, sb0,sb1,sb2,sb3,sb4,sb5,sb6,sb7;
  pb0=P[idx+0*ST]; sb0=S[idx+0*ST]; pb1=P[idx+1*ST]; sb1=S[idx+1*ST];
  pb2=P[idx+2*ST]; sb2=S[idx+2*ST]; pb3=P[idx+3*ST]; sb3=S[idx+3*ST];
  pb4=P[idx+4*ST]; sb4=S[idx+4*ST]; pb5=P[idx+5*ST]; sb5=S[idx+5*ST];
  pb6=P[idx+6*ST]; sb6=S[idx+6*ST]; pb7=P[idx+7*ST]; sb7=S[idx+7*ST];
  float h = 0.f;
  for (int c0 = 0; c0 < 128; c0 += 8){
    float pn0=0,sn0=0,pn1=0,sn1=0,pn2=0,sn2=0,pn3=0,sn3=0;
    float pn4=0,sn4=0,pn5=0,sn5=0,pn6=0,sn6=0,pn7=0,sn7=0;
    if (c0 + 8 < 128){
      pn0=P[idx+(size_t)(c0+8)*ST];  sn0=S[idx+(size_t)(c0+8)*ST];
      pn1=P[idx+(size_t)(c0+9)*ST];  sn1=S[idx+(size_t)(c0+9)*ST];
      pn2=P[idx+(size_t)(c0+10)*ST]; sn2=S[idx+(size_t)(c0+10)*ST];
      pn3=P[idx+(size_t)(c0+11)*ST]; sn3=S[idx+(size_t)(c0+11)*ST];
      pn4=P[idx+(size_t)(c0+12)*ST]; sn4=S[idx+(size_t)(c0+12)*ST];
      pn5=P[idx+(size_t)(c0+13)*ST]; sn5=S[idx+(size_t)(c0+13)*ST];
      pn6=P[idx+(size_t)(c0+14)*ST]; sn6=S[idx+(size_t)(c0+14)*ST];
      pn7=P[idx+(size_t)(c0+15)*ST]; sn7=S[idx+(size_t)(c0+15)*ST];
    }
    P[idx+(size_t)(c0+0)*ST] = h; h = pb0*h + sb0;
    P[idx+(size_t)(c0+1)*ST] = h; h = pb1*h + sb1;
    P[idx+(size_t)(c0+2)*ST] = h; h = pb2*h + sb2;
    P[idx+(size_t)(c0+3)*ST] = h; h = pb3*h + sb3;
    P[idx+(size_t)(c0+4)*ST] = h; h = pb4*h + sb4;
    P[idx+(size_t)(c0+5)*ST] = h; h = pb5*h + sb5;
    P[idx+(size_t)(c0+6)*ST] = h; h = pb6*h + sb6;
    P[idx+(size_t)(c0+7)*ST] = h; h = pb7*h + sb7;
    pb0=pn0;sb0=sn0;pb1=pn1;sb1=sn1;pb2=pn2;sb2=sn2;pb3=pn3;sb3=sn3;
    pb4=pn4;sb4=sn4;pb5=pn5;sb5=sn5;pb6=pn6;sb6=sn6;pb7=pn7;sb7=sn7;
  }
}

// ---------------- k5: pass-3 rescan (+D term) -> yl ; then z GEMV (float4 over d-quads) + gate.
__global__ __launch_bounds__(384) void k5_scan2(const float* __restrict__ dtg,
    const float* __restrict__ xcg, const float* __restrict__ Bmg, const float* __restrict__ Cmg,
    const float* __restrict__ Alog0, const float* __restrict__ Alog1,
    const float* __restrict__ Dp0, const float* __restrict__ Dp1,
    const float* __restrict__ ip0, const float* __restrict__ ip1,
    const float* __restrict__ Vg, const float* __restrict__ Hin, float* __restrict__ yout){
  __shared__ union alignas(16) U5 {
    struct { float dts[32*96]; float xcs[32*96]; } s;   // scan phase
    struct { alignas(16) float Wzt[48*96]; float Vgs[32*48]; } e;   // epilogue phase
  } u;
  __shared__ alignas(16) float Bl[32*16], Cl[32*16];
  __shared__ alignas(16) float yl[32*96];
  int task = blockIdx.x;
  int bd = task >> 7, ch = task & 127;
  int t0 = ch*32;
  int tid = threadIdx.x;
  const float* ip   = (bd >= 2) ? ip1 : ip0;
  const float* Alog = (bd >= 2) ? Alog1 : Alog0;
  const float* Dp   = (bd >= 2) ? Dp1 : Dp0;
  for (int i = tid; i < 32*96; i += 384){
    int t = i / 96, dd = i % 96;
    size_t g = ((size_t)bd*4096 + t0 + t)*96 + dd;
    u.s.dts[i] = dtg[g];
    u.s.xcs[i] = xcg[g];
  }
  for (int i = tid; i < 32*16; i += 384){
    size_t g = ((size_t)bd*4096 + t0)*16 + i;
    Bl[i] = Bmg[g];
    Cl[i] = Cmg[g];
  }
  __syncthreads();
  {
    int d = tid >> 2, q = tid & 3;
    float A0 = -__expf(Alog[d*16 + q*4 + 0]);
    float A1 = -__expf(Alog[d*16 + q*4 + 1]);
    float A2 = -__expf(Alog[d*16 + q*4 + 2]);
    float A3 = -__expf(Alog[d*16 + q*4 + 3]);
    float Dd = Dp[d];
    const float4 h4 = *(const float4*)&Hin[(size_t)task*1536 + d*16 + q*4];
    float h0 = h4.x, h1 = h4.y, h2 = h4.z, h3 = h4.w;
    for (int t = 0; t < 32; t += 2){
      float dtdA = u.s.dts[t*96 + d];
      float xcvA = u.s.xcs[t*96 + d];
      float dtdB = u.s.dts[(t+1)*96 + d];
      float xcvB = u.s.xcs[(t+1)*96 + d];
      float uA = dtdA * xcvA, uB = dtdB * xcvB;
      const float4 b4A = *(const float4*)&Bl[t*16 + q*4];
      const float4 c4A = *(const float4*)&Cl[t*16 + q*4];
      const float4 b4B = *(const float4*)&Bl[(t+1)*16 + q*4];
      const float4 c4B = *(const float4*)&Cl[(t+1)*16 + q*4];
      float a0 = __expf(dtdA*A0), a1 = __expf(dtdA*A1), a2 = __expf(dtdA*A2), a3 = __expf(dtdA*A3);
      float e0 = __expf(dtdB*A0), e1 = __expf(dtdB*A1), e2 = __expf(dtdB*A2), e3 = __expf(dtdB*A3);
      h0 = a0*h0 + uA*b4A.x;
      h1 = a1*h1 + uA*b4A.y;
      h2 = a2*h2 + uA*b4A.z;
      h3 = a3*h3 + uA*b4A.w;
      float pyA = (h0*c4A.x + h1*c4A.y) + (h2*c4A.z + h3*c4A.w);
      h0 = e0*h0 + uB*b4B.x;
      h1 = e1*h1 + uB*b4B.y;
      h2 = e2*h2 + uB*b4B.z;
      h3 = e3*h3 + uB*b4B.w;
      float pyB = (h0*c4B.x + h1*c4B.y) + (h2*c4B.z + h3*c4B.w);
      pyA += __shfl_xor(pyA, 1);  pyB += __shfl_xor(pyB, 1);
      pyA += __shfl_xor(pyA, 2);  pyB += __shfl_xor(pyB, 2);
      if (q == 0){
        yl[t*96 + d]     = pyA + xcvA*Dd;
        yl[(t+1)*96 + d] = pyB + xcvB*Dd;
      }
    }
  }
  __syncthreads();
  for (int i = tid; i < 96*48; i += 384){
    int j = i % 96, c = i / 96;
    u.e.Wzt[c*96 + j] = ip[(96 + j)*48 + c];
  }
  for (int i = tid; i < 32*48; i += 384){
    int t = i / 48, c = i % 48;
    u.e.Vgs[i] = Vg[((size_t)bd*4096 + t0 + t)*48 + c];
  }
  __syncthreads();
  // z GEMV: float4 over d-quads; 32 t x 24 dg = 768 tasks
  for (int it = 0; it < 2; it++){
    int i = tid + it*384;
    int t = i / 24, dg = i % 24;
    float4 z4 = make_float4(0.f,0.f,0.f,0.f);
    #pragma unroll 4
    for (int c = 0; c < 48; c++){
      float vv = u.e.Vgs[t*48 + c];
      const float4 w4 = *(const float4*)&u.e.Wzt[c*96 + dg*4];
      z4.x += vv*w4.x; z4.y += vv*w4.y; z4.z += vv*w4.z; z4.w += vv*w4.w;
    }
    const float4 y4 = *(const float4*)&yl[t*96 + dg*4];
    float4 o4;
    o4.x = y4.x * siluf(z4.x);
    o4.y = y4.y * siluf(z4.y);
    o4.z = y4.z * siluf(z4.z);
    o4.w = y4.w * siluf(z4.w);
    size_t g = ((size_t)bd*4096 + t0 + t)*96 + dg*4;
    *(float4*)&yout[g] = o4;
  }
}

// ---------------- k67: w-split 16 (512 blocks x 384 thr): un-snake + outproj + residual -> xmid ; LN(n2)+pin -> xp
__global__ __launch_bounds__(384) void k67_mid(const float* __restrict__ x,
    const float* __restrict__ y1, const float* __restrict__ y2,
    const float* __restrict__ op1, const float* __restrict__ op2,
    const float* __restrict__ nw, const float* __restrict__ nb,
    const float* __restrict__ pin,
    float* __restrict__ xmid, float* __restrict__ xp){
  __shared__ float bufW[192*49];        // op view: [48][97]; pin view: [192][49]
  __shared__ union UL { float ylds[16*97]; struct { float xl[48*17]; float mu[16]; float rs[16]; } l; } ul;
  int bid = blockIdx.x;                 // b*256 + h*4 + wq
  int b = bid >> 8, h = (bid >> 2) & 63, wq = bid & 3;
  int w0 = wq << 4;
  int tid = threadIdx.x;
  int w = tid & 15, cg = tid >> 4;      // cg 0..23, 2 channels each
  float acc0 = 0.f, acc1 = 0.f;
  for (int pass = 0; pass < 2; pass++){
    __syncthreads();
    const float* op = pass ? op2 : op1;
    const float* y  = pass ? y2  : y1;
    for (int i = tid; i < 48*96; i += 384){
      int c = i / 96, d = i % 96;
      bufW[c*97 + d] = op[i];
    }
    if (pass == 0){
      for (int i = tid; i < 16*96; i += 384){
        int wl_ = i / 96, d = i % 96;
        int wsp = w0 + wl_;
        int wp = (h & 1) ? 63 - wsp : wsp;
        ul.ylds[wl_*97 + d] = y[((size_t)b*4096 + h*64 + wp)*96 + d];
      }
    } else {
      for (int i = tid; i < 16*96; i += 384){
        int wl_ = i / 96, d = i % 96;
        int wsp = w0 + wl_;
        int t = wsp*64 + ((wsp & 1) ? 63 - h : h);
        ul.ylds[wl_*97 + d] = y[((size_t)b*4096 + t)*96 + d];
      }
    }
    __syncthreads();
    #pragma unroll 4
    for (int d = 0; d < 96; d++){
      float yv = ul.ylds[w*97 + d];
      acc0 += yv * bufW[(cg*2+0)*97 + d];
      acc1 += yv * bufW[(cg*2+1)*97 + d];
    }
  }
  __syncthreads();   // GEMVs done: safe to overwrite ylds and bufW
  {
    int c0 = cg*2;
    size_t idx0 = (((size_t)b*48 + c0)*64 + h)*64 + w0 + w;
    float v0 = x[idx0] + acc0;
    xmid[idx0] = v0;
    ul.l.xl[c0*17 + w] = v0;
    size_t idx1 = idx0 + 4096;
    float v1 = x[idx1] + acc1;
    xmid[idx1] = v1;
    ul.l.xl[(c0+1)*17 + w] = v1;
  }
  for (int i = tid; i < 192*48; i += 384){
    int r = i / 48, c = i % 48;
    bufW[r*49 + c] = pin[i];
  }
  __syncthreads();
  if (tid < 128){
    int r = tid >> 3, k = tid & 7;
    float s1 = 0.f, s2 = 0.f;
    #pragma unroll
    for (int cc = 0; cc < 6; cc++){
      float v = ul.l.xl[(k*6+cc)*17 + r];
      s1 += v; s2 += v*v;
    }
    s1 += __shfl_xor(s1,1); s2 += __shfl_xor(s2,1);
    s1 += __shfl_xor(s1,2); s2 += __shfl_xor(s2,2);
    s1 += __shfl_xor(s1,4); s2 += __shfl_xor(s2,4);
    if (k == 0){
      float m = s1*(1.f/48.f);
      ul.l.mu[r] = m;
      ul.l.rs[r] = rsqrtf(s2*(1.f/48.f) - m*m + 1e-5f);
    }
  }
  __syncthreads();
  for (int i = tid; i < 48*16; i += 384){
    int c = i >> 4, ww = i & 15;
    ul.l.xl[c*17 + ww] = (ul.l.xl[c*17 + ww] - ul.l.mu[ww])*ul.l.rs[ww]*nw[c] + nb[c];
  }
  __syncthreads();
  for (int it = 0; it < 2; it++){
    int i = tid + it*384;
    int ww = i & 15, oq = i >> 4;   // oq 0..47
    int o0 = oq*4;
    float a0=0,a1=0,a2=0,a3=0;
    #pragma unroll 4
    for (int c = 0; c < 48; c++){
      float xv = ul.l.xl[c*17 + ww];
      a0 += xv*bufW[(o0+0)*49 + c];
      a1 += xv*bufW[(o0+1)*49 + c];
      a2 += xv*bufW[(o0+2)*49 + c];
      a3 += xv*bufW[(o0+3)*49 + c];
    }
    xp[(((size_t)b*192 + o0+0)*64 + h)*64 + w0 + ww] = a0;
    xp[(((size_t)b*192 + o0+1)*64 + h)*64 + w0 + ww] = a1;
    xp[(((size_t)b*192 + o0+2)*64 + h)*64 + w0 + ww] = a2;
    xp[(((size_t)b*192 + o0+3)*64 + h)*64 + w0 + ww] = a3;
  }
}

// ---------------- K13: depthwise 3x3, pad 1, CH channels, 64x64; 4 outputs/thread along w
__global__ __launch_bounds__(256) void k13_dw(const float* __restrict__ in,
    const float* __restrict__ wgt, float* __restrict__ out, int CH){
  int idx = blockIdx.x*256 + threadIdx.x;
  if (idx >= 2*CH*1024) return;
  int wq = idx & 15, h = (idx >> 4) & 63, c = (idx >> 10) % CH, b = idx / (CH*1024);
  int w0 = wq*4;
  const float* ip = in + ((size_t)b*CH + c)*4096;
  const float* wp = wgt + c*9;
  float a0=0.f,a1=0.f,a2=0.f,a3=0.f;
  #pragma unroll
  for (int ky = 0; ky < 3; ky++){
    int hh = h + ky - 1;
    if (hh < 0 || hh > 63) continue;
    const float* rp = ip + hh*64;
    float v0 = (w0 > 0)  ? rp[w0-1] : 0.f;
    float v1 = rp[w0+0], v2 = rp[w0+1], v3 = rp[w0+2], v4 = rp[w0+3];
    float v5 = (w0 < 60) ? rp[w0+4] : 0.f;
    float k0 = wp[ky*3+0], k1 = wp[ky*3+1], k2 = wp[ky*3+2];
    a0 += k0*v0 + k1*v1 + k2*v2;
    a1 += k0*v1 + k1*v2 + k2*v3;
    a2 += k0*v2 + k1*v3 + k2*v4;
    a3 += k0*v3 + k1*v4 + k2*v5;
  }
  float* op = out + (((size_t)b*CH + c)*64 + h)*64 + w0;
  op[0]=a0; op[1]=a1; op[2]=a2; op[3]=a3;
}

// ---------------- K14: w-split 32 (512 blocks x 256 thr): 1x1 f_fus over concat(xd[:96], up(relu(ln(cv2)))) -> x1
__global__ __launch_bounds__(256) void k14_fus(const float* __restrict__ xd,
    const float* __restrict__ cv2, const float* __restrict__ lnw, const float* __restrict__ lnb,
    const float* __restrict__ fus, float* __restrict__ x1){
  __shared__ float wl[48*144];
  __shared__ float al[96*33];
  __shared__ float yl[48*17];
  __shared__ float muy[16], rsy[16];
  int bid = blockIdx.x;              // ((b*2 + oh)*64 + h)*2 + wh
  int wh = bid & 1, h = (bid >> 1) & 63, oh = (bid >> 7) & 1, b = bid >> 8;
  int w0 = wh << 5;
  int tid = threadIdx.x;
  for (int i = tid; i < 48*144; i += 256) wl[i] = fus[(size_t)oh*48*144 + i];
  for (int i = tid; i < 96*32; i += 256){
    int ci = i >> 5, w = i & 31;
    al[ci*33 + w] = xd[(((size_t)b*192 + ci)*64 + h)*64 + w0 + w];
  }
  {
    int hp = h >> 1, j0 = w0 >> 1;
    for (int i = tid; i < 48*16; i += 256){
      int cj = i >> 4, jl = i & 15;
      yl[cj*17 + jl] = cv2[(((size_t)b*48 + cj)*32 + hp)*32 + j0 + jl];
    }
  }
  __syncthreads();
  if (tid < 16){
    float s1 = 0.f, s2 = 0.f;
    #pragma unroll 4
    for (int cj = 0; cj < 48; cj++){ float v = yl[cj*17 + tid]; s1 += v; s2 += v*v; }
    float m = s1*(1.f/48.f);
    muy[tid] = m;
    rsy[tid] = rsqrtf(s2*(1.f/48.f) - m*m + 1e-5f);
  }
  __syncthreads();
  for (int i = tid; i < 48*16; i += 256){
    int cj = i >> 4, jl = i & 15;
    yl[cj*17 + jl] = fmaxf((yl[cj*17 + jl] - muy[jl])*rsy[jl]*lnw[cj] + lnb[cj], 0.f);
  }
  __syncthreads();
  for (int it = 0; it < 2; it++){
    int i = tid + it*256;
    int w = i & 31, og = i >> 5;   // og 0..15, 3 outputs each
    int o0 = og*3;
    float a0=0.f, a1=0.f, a2=0.f;
    #pragma unroll 4
    for (int ci = 0; ci < 96; ci++){
      float xv = al[ci*33 + w];
      a0 += xv * wl[(o0+0)*144 + ci];
      a1 += xv * wl[(o0+1)*144 + ci];
      a2 += xv * wl[(o0+2)*144 + ci];
    }
    int jl = w >> 1;
    #pragma unroll 4
    for (int cj = 0; cj < 48; cj++){
      float yv = yl[cj*17 + jl];
      a0 += yv * wl[(o0+0)*144 + 96 + cj];
      a1 += yv * wl[(o0+1)*144 + 96 + cj];
      a2 += yv * wl[(o0+2)*144 + 96 + cj];
    }
    x1[(((size_t)b*96 + oh*48 + o0+0)*64 + h)*64 + w0 + w] = a0;
    x1[(((size_t)b*96 + oh*48 + o0+1)*64 + h)*64 + w0 + w] = a1;
    x1[(((size_t)b*96 + oh*48 + o0+2)*64 + h)*64 + w0 + w] = a2;
  }
}

// ---------------- K16: w-split 16 (512 blocks x 384 thr): fused dwa 3x3 on x1 -> gelu * x2 -> pout GEMV -> + xmid -> out
__global__ __launch_bounds__(384) void k16_out(const float* __restrict__ x1,
    const float* __restrict__ xd, const float* __restrict__ dww,
    const float* __restrict__ pout, const float* __restrict__ xmid, float* __restrict__ out){
  __shared__ float wl[48*97];        // padded pout
  __shared__ float xs[96*54];        // [ch][ky 0..2][jx 0..17]
  __shared__ float gl[96*17];
  __shared__ float dwl[96*9];
  int bid = blockIdx.x;              // b*256 + h*4 + wq
  int b = bid >> 8, h = (bid >> 2) & 63, wq = bid & 3;
  int w0 = wq << 4;
  int tid = threadIdx.x;
  for (int i = tid; i < 48*96; i += 384){
    int r = i / 96, c = i % 96;
    wl[r*97 + c] = pout[i];
  }
  for (int i = tid; i < 96*9; i += 384) dwl[i] = dww[i];
  for (int i = tid; i < 96*54; i += 384){
    int jx = i % 18, ky = (i/18) % 3, ch = i/54;
    int hh = h + ky - 1, ww_ = w0 + jx - 1;
    float v = 0.f;
    if (hh >= 0 && hh < 64 && ww_ >= 0 && ww_ < 64)
      v = x1[(((size_t)b*96 + ch)*64 + hh)*64 + ww_];
    xs[i] = v;
  }
  __syncthreads();
  for (int i = tid; i < 96*16; i += 384){
    int ch = i >> 4, ww = i & 15;
    const float* wp = dwl + ch*9;
    const float* sp = xs + ch*54;
    float a = 0.f;
    #pragma unroll
    for (int ky = 0; ky < 3; ky++)
      #pragma unroll
      for (int kx = 0; kx < 3; kx++)
        a += sp[ky*18 + ww + kx] * wp[ky*3 + kx];
    float x2 = xd[(((size_t)b*192 + 96 + ch)*64 + h)*64 + w0 + ww];
    gl[ch*17 + ww] = geluf(a) * x2;
  }
  __syncthreads();
  int ww = tid & 15, cg = tid >> 4;  // cg 0..23, 2 channels each
  float a0=0.f, a1=0.f;
  #pragma unroll 4
  for (int ch = 0; ch < 96; ch++){
    float gv = gl[ch*17 + ww];
    a0 += gv * wl[(cg*2+0)*97 + ch];
    a1 += gv * wl[(cg*2+1)*97 + ch];
  }
  {
    int c0 = cg*2;
    size_t idx0 = (((size_t)b*48 + c0)*64 + h)*64 + w0 + ww;
    out[idx0] = xmid[idx0] + a0;
    size_t idx1 = idx0 + 4096;
    out[idx1] = xmid[idx1] + a1;
  }
}

extern "C" void kernel_launch(void* const* d_in, const int* in_sizes, int n_in,
                              void* d_out, int out_size, void* d_ws, size_t ws_size,
                              hipStream_t stream){
  (void)in_sizes; (void)n_in; (void)out_size; (void)ws_size;
  const float* x    = (const float*)d_in[0];
  const float* n1w  = (const float*)d_in[1];
  const float* n1b  = (const float*)d_in[2];
  const float* n2w  = (const float*)d_in[3];
  const float* n2b  = (const float*)d_in[4];
  const float* mlnw[2] = {(const float*)d_in[5], (const float*)d_in[7]};
  const float* mlnb[2] = {(const float*)d_in[6], (const float*)d_in[8]};
  const float* fln1w = (const float*)d_in[9];
  const float* fln1b = (const float*)d_in[10];
  const float* fln2w = (const float*)d_in[11];
  const float* fln2b = (const float*)d_in[12];
  const float* inproj[2]  = {(const float*)d_in[13], (const float*)d_in[22]};
  const float* convw[2]   = {(const float*)d_in[14], (const float*)d_in[23]};
  const float* convb[2]   = {(const float*)d_in[15], (const float*)d_in[24]};
  const float* xproj[2]   = {(const float*)d_in[16], (const float*)d_in[25]};
  const float* dtw[2]     = {(const float*)d_in[17], (const float*)d_in[26]};
  const float* dtbp[2]    = {(const float*)d_in[18], (const float*)d_in[27]};
  const float* Alog[2]    = {(const float*)d_in[19], (const float*)d_in[28]};
  const float* Dp[2]      = {(const float*)d_in[20], (const float*)d_in[29]};
  const float* outproj[2] = {(const float*)d_in[21], (const float*)d_in[30]};
  const float* fpin  = (const float*)d_in[31];
  const float* fdw   = (const float*)d_in[32];
  const float* ffus  = (const float*)d_in[33];
  const float* fdwa  = (const float*)d_in[34];
  const float* fpout = (const float*)d_in[35];
  const float* fc1w  = (const float*)d_in[36];
  const float* fc1b  = (const float*)d_in[37];
  const float* fc2w  = (const float*)d_in[38];
  const float* fc2b  = (const float*)d_in[39];

  // workspace (floats), total 7,995,392 (= 32.0 MB)
  float* ws = (float*)d_ws;
  float* xmg = ws + 0;         // (4,4096,96)  -> later yall
  float* Vgb = ws + 1572864;   // (4,4096,48)
  float* xcg = ws + 2359296;   // (4,4096,96)  -> later xpb (B,192,64,64)
  float* dtg = ws + 3932160;   // (4,4096,96)  -> later xdb
  float* Bmg = ws + 5505024;   // (4,4096,16)
  float* Cmg = ws + 5767168;   // (4,4096,16)
  float* Pb  = ws + 6029312;   // (512,1536)   -> Hin in-place, later x1b
  float* Sb  = ws + 6815744;   // (512,1536)
  float* xmid= ws + 7602176;   // (B,48,64,64)
  float* yall = xmg;
  float* Hin  = Pb;
  float* xpb  = xcg;
  float* xdb  = dtg;
  float* x1b  = Pb;
  // conv-chain temporaries live in d_out (dead until the final k16 write):
  float* outf = (float*)d_out;
  float* ta   = outf;            // (B,48,32,32) = 98,304 floats
  float* tbuf = outf + 98304;    // (B,48,32,32)

  kA9<<<768,256,0,stream>>>(x, n1w, n1b,
      mlnw[0], mlnb[0], mlnw[1], mlnb[1], inproj[0], inproj[1],
      fc1w, fc1b, xmg, Vgb, ta);
  kB9<<<768,384,0,stream>>>(xmg,
      convw[0], convw[1], convb[0], convb[1], xproj[0], xproj[1],
      dtw[0], dtw[1], dtbp[0], dtbp[1], Alog[0], Alog[1],
      ta, fc2w, fc2b, fln1w, fln1b,
      xcg, dtg, Bmg, Cmg, Pb, Sb, tbuf);
  k4_comb  <<<96,64,0,stream>>>(Pb, Sb);
  k5_scan2 <<<512,384,0,stream>>>(dtg, xcg, Bmg, Cmg, Alog[0], Alog[1],
      Dp[0], Dp[1], inproj[0], inproj[1], Vgb, Hin, yall);
  k67_mid  <<<512,384,0,stream>>>(x, yall, yall + 786432, outproj[0], outproj[1],
      n2w, n2b, fpin, xmid, xpb);
  k13_dw   <<<1536,256,0,stream>>>(xpb, fdw, xdb, 192);
  k14_fus  <<<512,256,0,stream>>>(xdb, tbuf, fln2w, fln2b, ffus, x1b);
  k16_out  <<<512,384,0,stream>>>(x1b, xdb, fdwa, fpout, xmid, (float*)d_out);
}

// Round 17
// 156.042 us; speedup vs baseline: 1.3388x; 1.0060x over previous
//
#include <hip/hip_runtime.h>

// SBSM block: B=2, C=48, H=W=64, L=4096, DI=96, DS=16, DCONV=4, DTR=3, HF=96
#define DEV __device__ __forceinline__

DEV float siluf(float x){ return x / (1.f + __expf(-x)); }
DEV float softplusf(float x){ return fmaxf(x, 0.f) + log1pf(expf(-fabsf(x))); }
DEV float geluf(float x){ return 0.5f * x * (1.f + erff(x * 0.70710678118654752440f)); }

// ---------------- kA9: blocks 0..511 = snake gather + LN(n1) + posenc + LN(mln) -> Vg ; inproj xm-half -> xmg
//                  blocks 512..767 = 2x2-pool(x) + 3x3 conv fc1 -> ta (out-channel quarters)
__global__ __launch_bounds__(256) void kA9(const float* __restrict__ x,
    const float* __restrict__ n1w, const float* __restrict__ n1b,
    const float* __restrict__ mw0, const float* __restrict__ mb0,
    const float* __restrict__ mw1, const float* __restrict__ mb1,
    const float* __restrict__ ip0, const float* __restrict__ ip1,
    const float* __restrict__ fc1w, const float* __restrict__ fc1b,
    float* __restrict__ xmg, float* __restrict__ Vg, float* __restrict__ ta){
  __shared__ union alignas(16) UA {
    struct { float Vl[48*36]; float Wt[48*97]; float mu_s[32]; float rs_s[32]; } a;
    struct { float wl[12*48*9]; float sin_[48*102]; } c;
  } u;
  int tid = threadIdx.x;
  if (blockIdx.x < 512){
    int bd = blockIdx.x >> 7, tile = blockIdx.x & 127;
    int dir = bd >> 1, b = bd & 1;
    int t0 = tile*32;
    const float* ip = dir ? ip1 : ip0;
    const float* mw = dir ? mw1 : mw0;
    const float* mb = dir ? mb1 : mb0;
    for (int i = tid; i < 96*48; i += 256){
      int j = i / 48, c = i % 48;
      u.a.Wt[c*97 + j] = ip[i];
    }
    for (int i = tid; i < 48*32; i += 256){
      int c = i >> 5, r = i & 31;
      int t = t0 + r;
      int h, w;
      if (dir == 0){ h = t >> 6; int wp = t & 63; w = (h & 1) ? 63 - wp : wp; }
      else         { w = t >> 6; int hp = t & 63; h = (w & 1) ? 63 - hp : hp; }
      u.a.Vl[c*36 + r] = x[(size_t)b*48*4096 + c*4096 + h*64 + w];
    }
    __syncthreads();
    {
      int r = tid >> 3, k = tid & 7;
      float s1 = 0.f, s2 = 0.f;
      #pragma unroll
      for (int cc = 0; cc < 6; cc++){
        float v = u.a.Vl[(k*6+cc)*36 + r];
        s1 += v; s2 += v*v;
      }
      s1 += __shfl_xor(s1,1); s2 += __shfl_xor(s2,1);
      s1 += __shfl_xor(s1,2); s2 += __shfl_xor(s2,2);
      s1 += __shfl_xor(s1,4); s2 += __shfl_xor(s2,4);
      if (k == 0){
        float m = s1*(1.f/48.f);
        u.a.mu_s[r] = m;
        u.a.rs_s[r] = rsqrtf(s2*(1.f/48.f) - m*m + 1e-5f);
      }
    }
    __syncthreads();
    for (int i = tid; i < 32*48; i += 256){
      int r = i / 48, c = i % 48;
      int t = t0 + r;
      float v = u.a.Vl[c*36 + r];
      float xn = (v - u.a.mu_s[r])*u.a.rs_s[r]*n1w[c] + n1b[c];
      float ang = (float)t * __expf(-(float)(c & ~1) * (9.210340371976184f/48.f));
      float pe = (c & 1) ? cosf(ang) : sinf(ang);
      u.a.Vl[c*36 + r] = xn + pe;
    }
    __syncthreads();
    {
      int r = tid >> 3, k = tid & 7;
      float s1 = 0.f, s2 = 0.f;
      #pragma unroll
      for (int cc = 0; cc < 6; cc++){
        float v = u.a.Vl[(k*6+cc)*36 + r];
        s1 += v; s2 += v*v;
      }
      s1 += __shfl_xor(s1,1); s2 += __shfl_xor(s2,1);
      s1 += __shfl_xor(s1,2); s2 += __shfl_xor(s2,2);
      s1 += __shfl_xor(s1,4); s2 += __shfl_xor(s2,4);
      if (k == 0){
        float m = s1*(1.f/48.f);
        u.a.mu_s[r] = m;
        u.a.rs_s[r] = rsqrtf(s2*(1.f/48.f) - m*m + 1e-5f);
      }
    }
    __syncthreads();
    for (int i = tid; i < 32*48; i += 256){
      int r = i / 48, c = i % 48;
      float v = u.a.Vl[c*36 + r];
      float v2 = (v - u.a.mu_s[r])*u.a.rs_s[r]*mw[c] + mb[c];
      u.a.Vl[c*36 + r] = v2;
      Vg[((size_t)bd*4096 + t0 + r)*48 + c] = v2;
    }
    __syncthreads();
    for (int k = 0; k < 3; k++){
      int i = tid + k*256;
      int j = i % 96, rb = i / 96;
      float a0=0.f, a1=0.f, a2=0.f, a3=0.f;
      #pragma unroll 4
      for (int c = 0; c < 48; c++){
        float wv = u.a.Wt[c*97 + j];
        const float4 v4 = *(const float4*)&u.a.Vl[c*36 + rb*4];
        a0 += wv*v4.x; a1 += wv*v4.y; a2 += wv*v4.z; a3 += wv*v4.w;
      }
      size_t g = ((size_t)bd*4096 + t0 + rb*4)*96 + j;
      xmg[g] = a0; xmg[g+96] = a1; xmg[g+192] = a2; xmg[g+288] = a3;
    }
  } else {
    // pool + conv1 (fc1), out-channel quarters, 256 blocks
    int bid = blockIdx.x - 512;
    int cq = bid & 3, i0 = (bid >> 2) & 31, b2 = bid >> 7;
    for (int i = tid; i < 12*48*9; i += 256) u.c.wl[i] = fc1w[cq*12*48*9 + i];
    for (int i = tid; i < 48*102; i += 256){
      int jx = i % 34, ky = (i/34) % 3, ci = i/102;
      int r = i0 + ky - 1, j = jx - 1;
      float v = 0.f;
      if (r >= 0 && r < 32 && j >= 0 && j < 32){
        const float* xb = x + (((size_t)b2*48 + ci)*64 + 2*r)*64 + 2*j;
        v = 0.25f*(xb[0] + xb[1] + xb[64] + xb[65]);
      }
      u.c.sin_[i] = v;
    }
    __syncthreads();
    for (int i = tid; i < 12*32; i += 256){
      int j = i & 31, col = i >> 5;
      float acc = fc1b[cq*12 + col];
      for (int ci = 0; ci < 48; ci++){
        const float* wp = u.c.wl + ((size_t)col*48 + ci)*9;
        const float* sp = u.c.sin_ + ci*102;
        #pragma unroll
        for (int ky = 0; ky < 3; ky++)
          #pragma unroll
          for (int kx = 0; kx < 3; kx++)
            acc += sp[ky*34 + j + kx] * wp[ky*3 + kx];
      }
      ta[(((size_t)b2*48 + cq*12 + col)*32 + i0)*32 + j] = acc;
    }
  }
}

// ---------------- kB9: blocks 0..511 = causal conv4+silu + xproj(float4) + dt/B/C + scan pass-1
//                  blocks 512..767 = LN(fln1)+ReLU(ta) + 3x3 conv fc2 -> tbuf
// NOTE: xcg/dtg now laid out (bd, 96, 4096) — d-major, t-minor.
__global__ __launch_bounds__(384) void kB9(const float* __restrict__ xmg,
    const float* __restrict__ cwp0, const float* __restrict__ cwp1,
    const float* __restrict__ cbp0, const float* __restrict__ cbp1,
    const float* __restrict__ xpp0, const float* __restrict__ xpp1,
    const float* __restrict__ dwp0, const float* __restrict__ dwp1,
    const float* __restrict__ dbp0, const float* __restrict__ dbp1,
    const float* __restrict__ Alog0, const float* __restrict__ Alog1,
    const float* __restrict__ ta, const float* __restrict__ fc2w, const float* __restrict__ fc2b,
    const float* __restrict__ fln1w, const float* __restrict__ fln1b,
    float* __restrict__ xcg, float* __restrict__ dtg,
    float* __restrict__ Bmg, float* __restrict__ Cmg,
    float* __restrict__ P, float* __restrict__ S, float* __restrict__ tbuf){
  __shared__ union alignas(16) UBB {
    struct {
      float Bl[32*16]; float Cl[32*16];
      union { float xml[96*36]; struct { float xwl[35*96]; float xdbl[35*33]; } p; } ub;
      alignas(16) float xcl[96*36];     // padded for float4 t-quad reads
      float dtl[96*33];
      float cw[96*4]; float cbv[96]; float dwl[96*3]; float dbl[96];
    } b;
    struct { float wl[12*48*9]; float sin_[48*102]; float mu_i[104]; float rs_i[104]; } c;
  } u;
  int tid = threadIdx.x;
  if (blockIdx.x < 512){
    int bd = blockIdx.x >> 7, tile = blockIdx.x & 127;
    int dir = bd >> 1;
    int t0 = tile*32;
    const float* cwp = dir ? cwp1 : cwp0;
    const float* cbp = dir ? cbp1 : cbp0;
    const float* xpp = dir ? xpp1 : xpp0;
    const float* dwp = dir ? dwp1 : dwp0;
    const float* dbp = dir ? dbp1 : dbp0;
    const float* Alog = dir ? Alog1 : Alog0;
    for (int i = tid; i < 35*96; i += 384){
      int tl = i / 96, d = i % 96;
      int t = t0 - 3 + tl;
      u.b.ub.xml[d*36 + tl] = (t >= 0) ? xmg[((size_t)bd*4096 + t)*96 + d] : 0.f;
    }
    for (int i = tid; i < 96*4;  i += 384) u.b.cw[i] = cwp[i];
    for (int i = tid; i < 96*3;  i += 384) u.b.dwl[i] = dwp[i];
    for (int i = tid; i < 96;    i += 384){ u.b.cbv[i] = cbp[i]; u.b.dbl[i] = dbp[i]; }
    __syncthreads();
    for (int i = tid; i < 96*32; i += 384){
      int d = i >> 5, t = i & 31;
      float acc = u.b.cbv[d];
      #pragma unroll
      for (int k = 0; k < 4; k++) acc += u.b.cw[d*4+k]*u.b.ub.xml[d*36 + t + k];
      u.b.xcl[d*36 + t] = siluf(acc);
    }
    __syncthreads();
    for (int i = tid; i < 35*96; i += 384) u.b.ub.p.xwl[i] = xpp[i];
    __syncthreads();
    // xproj (96 -> 35), float4 over t-quads: 35 j x 8 tq = 280 tasks
    if (tid < 280){
      int j = tid / 8, tq = tid % 8;
      float a0=0.f, a1=0.f, a2=0.f, a3=0.f;
      #pragma unroll 4
      for (int d = 0; d < 96; d++){
        float wv = u.b.ub.p.xwl[j*96 + d];
        const float4 v4 = *(const float4*)&u.b.xcl[d*36 + tq*4];
        a0 += wv*v4.x; a1 += wv*v4.y; a2 += wv*v4.z; a3 += wv*v4.w;
      }
      int t = tq*4;
      u.b.ub.p.xdbl[j*33 + t+0] = a0;
      u.b.ub.p.xdbl[j*33 + t+1] = a1;
      u.b.ub.p.xdbl[j*33 + t+2] = a2;
      u.b.ub.p.xdbl[j*33 + t+3] = a3;
    }
    __syncthreads();
    for (int i = tid; i < 96*32; i += 384){
      int d = i >> 5, t = i & 31;
      float v = u.b.dbl[d];
      #pragma unroll
      for (int r = 0; r < 3; r++) v += u.b.ub.p.xdbl[r*33 + t]*u.b.dwl[d*3 + r];
      u.b.dtl[d*33 + t] = softplusf(v);
    }
    for (int i = tid; i < 32*16; i += 384){
      int t = i / 16, s = i % 16;
      u.b.Bl[t*16 + s] = u.b.ub.p.xdbl[(3+s)*33 + t];
      u.b.Cl[t*16 + s] = u.b.ub.p.xdbl[(19+s)*33 + t];
    }
    __syncthreads();
    // epilogue: t-minor mapping; d-major global layout -> coalesced rows, 2-way LDS (free)
    for (int i = tid; i < 96*32; i += 384){
      int d = i >> 5, t = i & 31;
      size_t g = ((size_t)(bd*96 + d))*4096 + t0 + t;
      xcg[g] = u.b.xcl[d*36 + t];
      dtg[g] = u.b.dtl[d*33 + t];
    }
    for (int i = tid; i < 32*16; i += 384){
      int t = i / 16, s = i % 16;
      size_t g = ((size_t)bd*4096 + t0 + t)*16 + s;
      Bmg[g] = u.b.Bl[t*16 + s];
      Cmg[g] = u.b.Cl[t*16 + s];
    }
    {
      int d = tid >> 2, q = tid & 3;
      float A0 = -__expf(Alog[d*16 + q*4 + 0]);
      float A1 = -__expf(Alog[d*16 + q*4 + 1]);
      float A2 = -__expf(Alog[d*16 + q*4 + 2]);
      float A3 = -__expf(Alog[d*16 + q*4 + 3]);
      float h0=0.f,h1=0.f,h2=0.f,h3=0.f, p0=1.f,p1=1.f,p2=1.f,p3=1.f;
      #pragma unroll 4
      for (int t = 0; t < 32; t++){
        float dtd = u.b.dtl[d*33 + t];
        float uu = dtd * u.b.xcl[d*36 + t];
        const float4 b4 = *(const float4*)&u.b.Bl[t*16 + q*4];
        float a0 = __expf(dtd*A0), a1 = __expf(dtd*A1), a2 = __expf(dtd*A2), a3 = __expf(dtd*A3);
        h0 = a0*h0 + uu*b4.x; p0 *= a0;
        h1 = a1*h1 + uu*b4.y; p1 *= a1;
        h2 = a2*h2 + uu*b4.z; p2 *= a2;
        h3 = a3*h3 + uu*b4.w; p3 *= a3;
      }
      size_t ob = (size_t)blockIdx.x*1536 + d*16 + q*4;
      *(float4*)&P[ob] = make_float4(p0,p1,p2,p3);
      *(float4*)&S[ob] = make_float4(h0,h1,h2,h3);
    }
  } else {
    // LN(fln1)+ReLU on ta, then conv fc2 -> tbuf
    int bid = blockIdx.x - 512;
    int cq = bid & 3, i0 = (bid >> 2) & 31, b2 = bid >> 7;
    for (int i = tid; i < 12*48*9; i += 384) u.c.wl[i] = fc2w[cq*12*48*9 + i];
    for (int i = tid; i < 48*102; i += 384){
      int jx = i % 34, ky = (i/34) % 3, ci = i/102;
      int r = i0 + ky - 1, j = jx - 1;
      float v = 0.f;
      if (r >= 0 && r < 32 && j >= 0 && j < 32)
        v = ta[(((size_t)b2*48 + ci)*32 + r)*32 + j];
      u.c.sin_[i] = v;
    }
    __syncthreads();
    if (tid < 102){
      int jx = tid % 34, ky = tid / 34;
      int r = i0 + ky - 1, j = jx - 1;
      if (r >= 0 && r < 32 && j >= 0 && j < 32){
        float s1 = 0.f, s2 = 0.f;
        #pragma unroll 4
        for (int ci = 0; ci < 48; ci++){ float v = u.c.sin_[ci*102 + tid]; s1 += v; s2 += v*v; }
        float m = s1*(1.f/48.f);
        u.c.mu_i[tid] = m;
        u.c.rs_i[tid] = rsqrtf(s2*(1.f/48.f) - m*m + 1e-5f);
      }
    }
    __syncthreads();
    for (int i = tid; i < 48*102; i += 384){
      int ci = i / 102, p = i % 102;
      int jx = p % 34, ky = p / 34;
      int r = i0 + ky - 1, j = jx - 1;
      if (r >= 0 && r < 32 && j >= 0 && j < 32){
        float v = (u.c.sin_[i] - u.c.mu_i[p])*u.c.rs_i[p]*fln1w[ci] + fln1b[ci];
        u.c.sin_[i] = fmaxf(v, 0.f);
      }
    }
    __syncthreads();
    int j = tid & 31, col = tid >> 5;    // col 0..11
    float acc = fc2b[cq*12 + col];
    for (int ci = 0; ci < 48; ci++){
      const float* wp = u.c.wl + ((size_t)col*48 + ci)*9;
      const float* sp = u.c.sin_ + ci*102;
      #pragma unroll
      for (int ky = 0; ky < 3; ky++)
        #pragma unroll
        for (int kx = 0; kx < 3; kx++)
          acc += sp[ky*34 + j + kx] * wp[ky*3 + kx];
    }
    tbuf[(((size_t)b2*48 + cq*12 + col)*32 + i0)*32 + j] = acc;
  }
}

// ---------------- k4: sequential chunk combine over 128 chunks, IN PLACE (Hin = P).
__global__ __launch_bounds__(64) void k4_comb(float* __restrict__ P, const float* __restrict__ S){
  int tid2 = blockIdx.x*64 + threadIdx.x;   // 6144 lanes
  int bd = tid2 / 1536, r = tid2 % 1536;
  size_t idx = (size_t)bd*128*1536 + r;
  const int ST = 1536;
  float pb0,pb1,pb2,pb3,pb4,pb5,pb6,pb7, sb0,sb1,sb2,sb3,sb4,sb5,sb6,sb7;
  pb0=P[idx+0*ST]; sb0=S[idx+0*ST]; pb1=P[idx+1*ST]; sb1=S[idx+1*ST];
  pb2=P[idx+2*ST]; sb2=S[idx+2*ST]; pb3=P[idx+3*ST]; sb3=S[idx+3*ST];
  pb4=P[idx+4*ST]; sb4=S[idx+4*ST]; pb5=P[idx+5*ST]; sb5=S[idx+5*ST];
  pb6=P[idx+6*ST]; sb6=S[idx+6*ST]; pb7=P[idx+7*ST]; sb7=S[idx+7*ST];
  float h = 0.f;
  for (int c0 = 0; c0 < 128; c0 += 8){
    float pn0=0,sn0=0,pn1=0,sn1=0,pn2=0,sn2=0,pn3=0,sn3=0;
    float pn4=0,sn4=0,pn5=0,sn5=0,pn6=0,sn6=0,pn7=0,sn7=0;
    if (c0 + 8 < 128){
      pn0=P[idx+(size_t)(c0+8)*ST];  sn0=S[idx+(size_t)(c0+8)*ST];
      pn1=P[idx+(size_t)(c0+9)*ST];  sn1=S[idx+(size_t)(c0+9)*ST];
      pn2=P[idx+(size_t)(c0+10)*ST]; sn2=S[idx+(size_t)(c0+10)*ST];
      pn3=P[idx+(size_t)(c0+11)*ST]; sn3=S[idx+(size_t)(c0+11)*ST];
      pn4=P[idx+(size_t)(c0+12)*ST]; sn4=S[idx+(size_t)(c0+12)*ST];
      pn5=P[idx+(size_t)(c0+13)*ST]; sn5=S[idx+(size_t)(c0+13)*ST];
      pn6=P[idx+(size_t)(c0+14)*ST]; sn6=S[idx+(size_t)(c0+14)*ST];
      pn7=P[idx+(size_t)(c0+15)*ST]; sn7=S[idx+(size_t)(c0+15)*ST];
    }
    P[idx+(size_t)(c0+0)*ST] = h; h = pb0*h + sb0;
    P[idx+(size_t)(c0+1)*ST] = h; h = pb1*h + sb1;
    P[idx+(size_t)(c0+2)*ST] = h; h = pb2*h + sb2;
    P[idx+(size_t)(c0+3)*ST] = h; h = pb3*h + sb3;
    P[idx+(size_t)(c0+4)*ST] = h; h = pb4*h + sb4;
    P[idx+(size_t)(c0+5)*ST] = h; h = pb5*h + sb5;
    P[idx+(size_t)(c0+6)*ST] = h; h = pb6*h + sb6;
    P[idx+(size_t)(c0+7)*ST] = h; h = pb7*h + sb7;
    pb0=pn0;sb0=sn0;pb1=pn1;sb1=sn1;pb2=pn2;sb2=sn2;pb3=pn3;sb3=sn3;
    pb4=pn4;sb4=sn4;pb5=pn5;sb5=sn5;pb6=pn6;sb6=sn6;pb7=pn7;sb7=sn7;
  }
}

// ---------------- k5: pass-3 rescan (+D term) -> yl ; then z GEMV (float4 over d-quads) + gate.
// dts/xcs at stride 97 (conflict-free staging from d-major xcg/dtg).
__global__ __launch_bounds__(384) void k5_scan2(const float* __restrict__ dtg,
    const float* __restrict__ xcg, const float* __restrict__ Bmg, const float* __restrict__ Cmg,
    const float* __restrict__ Alog0, const float* __restrict__ Alog1,
    const float* __restrict__ Dp0, const float* __restrict__ Dp1,
    const float* __restrict__ ip0, const float* __restrict__ ip1,
    const float* __restrict__ Vg, const float* __restrict__ Hin, float* __restrict__ yout){
  __shared__ union alignas(16) U5 {
    struct { float dts[32*97]; float xcs[32*97]; } s;   // scan phase, stride 97
    struct { alignas(16) float Wzt[48*96]; float Vgs[32*48]; } e;   // epilogue phase
  } u;
  __shared__ alignas(16) float Bl[32*16], Cl[32*16];
  __shared__ alignas(16) float yl[32*96];
  int task = blockIdx.x;
  int bd = task >> 7, ch = task & 127;
  int t0 = ch*32;
  int tid = threadIdx.x;
  const float* ip   = (bd >= 2) ? ip1 : ip0;
  const float* Alog = (bd >= 2) ? Alog1 : Alog0;
  const float* Dp   = (bd >= 2) ? Dp1 : Dp0;
  // stage from d-major layout: lanes t-minor (coalesced global), LDS write stride 97 (conflict-free)
  for (int i = tid; i < 96*32; i += 384){
    int d = i >> 5, t = i & 31;
    size_t g = ((size_t)(bd*96 + d))*4096 + t0 + t;
    u.s.dts[t*97 + d] = dtg[g];
    u.s.xcs[t*97 + d] = xcg[g];
  }
  for (int i = tid; i < 32*16; i += 384){
    size_t g = ((size_t)bd*4096 + t0)*16 + i;
    Bl[i] = Bmg[g];
    Cl[i] = Cmg[g];
  }
  __syncthreads();
  {
    int d = tid >> 2, q = tid & 3;
    float A0 = -__expf(Alog[d*16 + q*4 + 0]);
    float A1 = -__expf(Alog[d*16 + q*4 + 1]);
    float A2 = -__expf(Alog[d*16 + q*4 + 2]);
    float A3 = -__expf(Alog[d*16 + q*4 + 3]);
    float Dd = Dp[d];
    const float4 h4 = *(const float4*)&Hin[(size_t)task*1536 + d*16 + q*4];
    float h0 = h4.x, h1 = h4.y, h2 = h4.z, h3 = h4.w;
    for (int t = 0; t < 32; t += 2){
      float dtdA = u.s.dts[t*97 + d];
      float xcvA = u.s.xcs[t*97 + d];
      float dtdB = u.s.dts[(t+1)*97 + d];
      float xcvB = u.s.xcs[(t+1)*97 + d];
      float uA = dtdA * xcvA, uB = dtdB * xcvB;
      const float4 b4A = *(const float4*)&Bl[t*16 + q*4];
      const float4 c4A = *(const float4*)&Cl[t*16 + q*4];
      const float4 b4B = *(const float4*)&Bl[(t+1)*16 + q*4];
      const float4 c4B = *(const float4*)&Cl[(t+1)*16 + q*4];
      float a0 = __expf(dtdA*A0), a1 = __expf(dtdA*A1), a2 = __expf(dtdA*A2), a3 = __expf(dtdA*A3);
      float e0 = __expf(dtdB*A0), e1 = __expf(dtdB*A1), e2 = __expf(dtdB*A2), e3 = __expf(dtdB*A3);
      h0 = a0*h0 + uA*b4A.x;
      h1 = a1*h1 + uA*b4A.y;
      h2 = a2*h2 + uA*b4A.z;
      h3 = a3*h3 + uA*b4A.w;
      float pyA = (h0*c4A.x + h1*c4A.y) + (h2*c4A.z + h3*c4A.w);
      h0 = e0*h0 + uB*b4B.x;
      h1 = e1*h1 + uB*b4B.y;
      h2 = e2*h2 + uB*b4B.z;
      h3 = e3*h3 + uB*b4B.w;
      float pyB = (h0*c4B.x + h1*c4B.y) + (h2*c4B.z + h3*c4B.w);
      pyA += __shfl_xor(pyA, 1);  pyB += __shfl_xor(pyB, 1);
      pyA += __shfl_xor(pyA, 2);  pyB += __shfl_xor(pyB, 2);
      if (q == 0){
        yl[t*96 + d]     = pyA + xcvA*Dd;
        yl[(t+1)*96 + d] = pyB + xcvB*Dd;
      }
    }
  }
  __syncthreads();
  for (int i = tid; i < 96*48; i += 384){
    int j = i % 96, c = i / 96;
    u.e.Wzt[c*96 + j] = ip[(96 + j)*48 + c];
  }
  for (int i = tid; i < 32*48; i += 384){
    int t = i / 48, c = i % 48;
    u.e.Vgs[i] = Vg[((size_t)bd*4096 + t0 + t)*48 + c];
  }
  __syncthreads();
  // z GEMV: float4 over d-quads; 32 t x 24 dg = 768 tasks
  for (int it = 0; it < 2; it++){
    int i = tid + it*384;
    int t = i / 24, dg = i % 24;
    float4 z4 = make_float4(0.f,0.f,0.f,0.f);
    #pragma unroll 4
    for (int c = 0; c < 48; c++){
      float vv = u.e.Vgs[t*48 + c];
      const float4 w4 = *(const float4*)&u.e.Wzt[c*96 + dg*4];
      z4.x += vv*w4.x; z4.y += vv*w4.y; z4.z += vv*w4.z; z4.w += vv*w4.w;
    }
    const float4 y4 = *(const float4*)&yl[t*96 + dg*4];
    float4 o4;
    o4.x = y4.x * siluf(z4.x);
    o4.y = y4.y * siluf(z4.y);
    o4.z = y4.z * siluf(z4.z);
    o4.w = y4.w * siluf(z4.w);
    size_t g = ((size_t)bd*4096 + t0 + t)*96 + dg*4;
    *(float4*)&yout[g] = o4;
  }
}

// ---------------- k67: w-split 16 (512 blocks x 384 thr): un-snake + outproj + residual -> xmid ; LN(n2)+pin -> xp
__global__ __launch_bounds__(384) void k67_mid(const float* __restrict__ x,
    const float* __restrict__ y1, const float* __restrict__ y2,
    const float* __restrict__ op1, const float* __restrict__ op2,
    const float* __restrict__ nw, const float* __restrict__ nb,
    const float* __restrict__ pin,
    float* __restrict__ xmid, float* __restrict__ xp){
  __shared__ float bufW[192*49];        // op view: [48][97]; pin view: [192][49]
  __shared__ union UL { float ylds[16*97]; struct { float xl[48*17]; float mu[16]; float rs[16]; } l; } ul;
  int bid = blockIdx.x;                 // b*256 + h*4 + wq
  int b = bid >> 8, h = (bid >> 2) & 63, wq = bid & 3;
  int w0 = wq << 4;
  int tid = threadIdx.x;
  int w = tid & 15, cg = tid >> 4;      // cg 0..23, 2 channels each
  float acc0 = 0.f, acc1 = 0.f;
  for (int pass = 0; pass < 2; pass++){
    __syncthreads();
    const float* op = pass ? op2 : op1;
    const float* y  = pass ? y2  : y1;
    for (int i = tid; i < 48*96; i += 384){
      int c = i / 96, d = i % 96;
      bufW[c*97 + d] = op[i];
    }
    if (pass == 0){
      for (int i = tid; i < 16*96; i += 384){
        int wl_ = i / 96, d = i % 96;
        int wsp = w0 + wl_;
        int wp = (h & 1) ? 63 - wsp : wsp;
        ul.ylds[wl_*97 + d] = y[((size_t)b*4096 + h*64 + wp)*96 + d];
      }
    } else {
      for (int i = tid; i < 16*96; i += 384){
        int wl_ = i / 96, d = i % 96;
        int wsp = w0 + wl_;
        int t = wsp*64 + ((wsp & 1) ? 63 - h : h);
        ul.ylds[wl_*97 + d] = y[((size_t)b*4096 + t)*96 + d];
      }
    }
    __syncthreads();
    #pragma unroll 4
    for (int d = 0; d < 96; d++){
      float yv = ul.ylds[w*97 + d];
      acc0 += yv * bufW[(cg*2+0)*97 + d];
      acc1 += yv * bufW[(cg*2+1)*97 + d];
    }
  }
  __syncthreads();   // GEMVs done: safe to overwrite ylds and bufW
  {
    int c0 = cg*2;
    size_t idx0 = (((size_t)b*48 + c0)*64 + h)*64 + w0 + w;
    float v0 = x[idx0] + acc0;
    xmid[idx0] = v0;
    ul.l.xl[c0*17 + w] = v0;
    size_t idx1 = idx0 + 4096;
    float v1 = x[idx1] + acc1;
    xmid[idx1] = v1;
    ul.l.xl[(c0+1)*17 + w] = v1;
  }
  for (int i = tid; i < 192*48; i += 384){
    int r = i / 48, c = i % 48;
    bufW[r*49 + c] = pin[i];
  }
  __syncthreads();
  if (tid < 128){
    int r = tid >> 3, k = tid & 7;
    float s1 = 0.f, s2 = 0.f;
    #pragma unroll
    for (int cc = 0; cc < 6; cc++){
      float v = ul.l.xl[(k*6+cc)*17 + r];
      s1 += v; s2 += v*v;
    }
    s1 += __shfl_xor(s1,1); s2 += __shfl_xor(s2,1);
    s1 += __shfl_xor(s1,2); s2 += __shfl_xor(s2,2);
    s1 += __shfl_xor(s1,4); s2 += __shfl_xor(s2,4);
    if (k == 0){
      float m = s1*(1.f/48.f);
      ul.l.mu[r] = m;
      ul.l.rs[r] = rsqrtf(s2*(1.f/48.f) - m*m + 1e-5f);
    }
  }
  __syncthreads();
  for (int i = tid; i < 48*16; i += 384){
    int c = i >> 4, ww = i & 15;
    ul.l.xl[c*17 + ww] = (ul.l.xl[c*17 + ww] - ul.l.mu[ww])*ul.l.rs[ww]*nw[c] + nb[c];
  }
  __syncthreads();
  for (int it = 0; it < 2; it++){
    int i = tid + it*384;
    int ww = i & 15, oq = i >> 4;   // oq 0..47
    int o0 = oq*4;
    float a0=0,a1=0,a2=0,a3=0;
    #pragma unroll 4
    for (int c = 0; c < 48; c++){
      float xv = ul.l.xl[c*17 + ww];
      a0 += xv*bufW[(o0+0)*49 + c];
      a1 += xv*bufW[(o0+1)*49 + c];
      a2 += xv*bufW[(o0+2)*49 + c];
      a3 += xv*bufW[(o0+3)*49 + c];
    }
    xp[(((size_t)b*192 + o0+0)*64 + h)*64 + w0 + ww] = a0;
    xp[(((size_t)b*192 + o0+1)*64 + h)*64 + w0 + ww] = a1;
    xp[(((size_t)b*192 + o0+2)*64 + h)*64 + w0 + ww] = a2;
    xp[(((size_t)b*192 + o0+3)*64 + h)*64 + w0 + ww] = a3;
  }
}

// ---------------- K13: depthwise 3x3, pad 1, CH channels, 64x64; 4 outputs/thread along w
__global__ __launch_bounds__(256) void k13_dw(const float* __restrict__ in,
    const float* __restrict__ wgt, float* __restrict__ out, int CH){
  int idx = blockIdx.x*256 + threadIdx.x;
  if (idx >= 2*CH*1024) return;
  int wq = idx & 15, h = (idx >> 4) & 63, c = (idx >> 10) % CH, b = idx / (CH*1024);
  int w0 = wq*4;
  const float* ip = in + ((size_t)b*CH + c)*4096;
  const float* wp = wgt + c*9;
  float a0=0.f,a1=0.f,a2=0.f,a3=0.f;
  #pragma unroll
  for (int ky = 0; ky < 3; ky++){
    int hh = h + ky - 1;
    if (hh < 0 || hh > 63) continue;
    const float* rp = ip + hh*64;
    float v0 = (w0 > 0)  ? rp[w0-1] : 0.f;
    float v1 = rp[w0+0], v2 = rp[w0+1], v3 = rp[w0+2], v4 = rp[w0+3];
    float v5 = (w0 < 60) ? rp[w0+4] : 0.f;
    float k0 = wp[ky*3+0], k1 = wp[ky*3+1], k2 = wp[ky*3+2];
    a0 += k0*v0 + k1*v1 + k2*v2;
    a1 += k0*v1 + k1*v2 + k2*v3;
    a2 += k0*v2 + k1*v3 + k2*v4;
    a3 += k0*v3 + k1*v4 + k2*v5;
  }
  float* op = out + (((size_t)b*CH + c)*64 + h)*64 + w0;
  op[0]=a0; op[1]=a1; op[2]=a2; op[3]=a3;
}

// ---------------- K14: w-split 32 (512 blocks x 256 thr): 1x1 f_fus over concat(xd[:96], up(relu(ln(cv2)))) -> x1
__global__ __launch_bounds__(256) void k14_fus(const float* __restrict__ xd,
    const float* __restrict__ cv2, const float* __restrict__ lnw, const float* __restrict__ lnb,
    const float* __restrict__ fus, float* __restrict__ x1){
  __shared__ float wl[48*144];
  __shared__ float al[96*33];
  __shared__ float yl[48*17];
  __shared__ float muy[16], rsy[16];
  int bid = blockIdx.x;              // ((b*2 + oh)*64 + h)*2 + wh
  int wh = bid & 1, h = (bid >> 1) & 63, oh = (bid >> 7) & 1, b = bid >> 8;
  int w0 = wh << 5;
  int tid = threadIdx.x;
  for (int i = tid; i < 48*144; i += 256) wl[i] = fus[(size_t)oh*48*144 + i];
  for (int i = tid; i < 96*32; i += 256){
    int ci = i >> 5, w = i & 31;
    al[ci*33 + w] = xd[(((size_t)b*192 + ci)*64 + h)*64 + w0 + w];
  }
  {
    int hp = h >> 1, j0 = w0 >> 1;
    for (int i = tid; i < 48*16; i += 256){
      int cj = i >> 4, jl = i & 15;
      yl[cj*17 + jl] = cv2[(((size_t)b*48 + cj)*32 + hp)*32 + j0 + jl];
    }
  }
  __syncthreads();
  if (tid < 16){
    float s1 = 0.f, s2 = 0.f;
    #pragma unroll 4
    for (int cj = 0; cj < 48; cj++){ float v = yl[cj*17 + tid]; s1 += v; s2 += v*v; }
    float m = s1*(1.f/48.f);
    muy[tid] = m;
    rsy[tid] = rsqrtf(s2*(1.f/48.f) - m*m + 1e-5f);
  }
  __syncthreads();
  for (int i = tid; i < 48*16; i += 256){
    int cj = i >> 4, jl = i & 15;
    yl[cj*17 + jl] = fmaxf((yl[cj*17 + jl] - muy[jl])*rsy[jl]*lnw[cj] + lnb[cj], 0.f);
  }
  __syncthreads();
  for (int it = 0; it < 2; it++){
    int i = tid + it*256;
    int w = i & 31, og = i >> 5;   // og 0..15, 3 outputs each
    int o0 = og*3;
    float a0=0.f, a1=0.f, a2=0.f;
    #pragma unroll 4
    for (int ci = 0; ci < 96; ci++){
      float xv = al[ci*33 + w];
      a0 += xv * wl[(o0+0)*144 + ci];
      a1 += xv * wl[(o0+1)*144 + ci];
      a2 += xv * wl[(o0+2)*144 + ci];
    }
    int jl = w >> 1;
    #pragma unroll 4
    for (int cj = 0; cj < 48; cj++){
      float yv = yl[cj*17 + jl];
      a0 += yv * wl[(o0+0)*144 + 96 + cj];
      a1 += yv * wl[(o0+1)*144 + 96 + cj];
      a2 += yv * wl[(o0+2)*144 + 96 + cj];
    }
    x1[(((size_t)b*96 + oh*48 + o0+0)*64 + h)*64 + w0 + w] = a0;
    x1[(((size_t)b*96 + oh*48 + o0+1)*64 + h)*64 + w0 + w] = a1;
    x1[(((size_t)b*96 + oh*48 + o0+2)*64 + h)*64 + w0 + w] = a2;
  }
}

// ---------------- K16: w-split 16 (512 blocks x 384 thr): fused dwa 3x3 on x1 -> gelu * x2 -> pout GEMV -> + xmid -> out
__global__ __launch_bounds__(384) void k16_out(const float* __restrict__ x1,
    const float* __restrict__ xd, const float* __restrict__ dww,
    const float* __restrict__ pout, const float* __restrict__ xmid, float* __restrict__ out){
  __shared__ float wl[48*97];        // padded pout
  __shared__ float xs[96*54];        // [ch][ky 0..2][jx 0..17]
  __shared__ float gl[96*17];
  __shared__ float dwl[96*9];
  int bid = blockIdx.x;              // b*256 + h*4 + wq
  int b = bid >> 8, h = (bid >> 2) & 63, wq = bid & 3;
  int w0 = wq << 4;
  int tid = threadIdx.x;
  for (int i = tid; i < 48*96; i += 384){
    int r = i / 96, c = i % 96;
    wl[r*97 + c] = pout[i];
  }
  for (int i = tid; i < 96*9; i += 384) dwl[i] = dww[i];
  for (int i = tid; i < 96*54; i += 384){
    int jx = i % 18, ky = (i/18) % 3, ch = i/54;
    int hh = h + ky - 1, ww_ = w0 + jx - 1;
    float v = 0.f;
    if (hh >= 0 && hh < 64 && ww_ >= 0 && ww_ < 64)
      v = x1[(((size_t)b*96 + ch)*64 + hh)*64 + ww_];
    xs[i] = v;
  }
  __syncthreads();
  for (int i = tid; i < 96*16; i += 384){
    int ch = i >> 4, ww = i & 15;
    const float* wp = dwl + ch*9;
    const float* sp = xs + ch*54;
    float a = 0.f;
    #pragma unroll
    for (int ky = 0; ky < 3; ky++)
      #pragma unroll
      for (int kx = 0; kx < 3; kx++)
        a += sp[ky*18 + ww + kx] * wp[ky*3 + kx];
    float x2 = xd[(((size_t)b*192 + 96 + ch)*64 + h)*64 + w0 + ww];
    gl[ch*17 + ww] = geluf(a) * x2;
  }
  __syncthreads();
  int ww = tid & 15, cg = tid >> 4;  // cg 0..23, 2 channels each
  float a0=0.f, a1=0.f;
  #pragma unroll 4
  for (int ch = 0; ch < 96; ch++){
    float gv = gl[ch*17 + ww];
    a0 += gv * wl[(cg*2+0)*97 + ch];
    a1 += gv * wl[(cg*2+1)*97 + ch];
  }
  {
    int c0 = cg*2;
    size_t idx0 = (((size_t)b*48 + c0)*64 + h)*64 + w0 + ww;
    out[idx0] = xmid[idx0] + a0;
    size_t idx1 = idx0 + 4096;
    out[idx1] = xmid[idx1] + a1;
  }
}

extern "C" void kernel_launch(void* const* d_in, const int* in_sizes, int n_in,
                              void* d_out, int out_size, void* d_ws, size_t ws_size,
                              hipStream_t stream){
  (void)in_sizes; (void)n_in; (void)out_size; (void)ws_size;
  const float* x    = (const float*)d_in[0];
  const float* n1w  = (const float*)d_in[1];
  const float* n1b  = (const float*)d_in[2];
  const float* n2w  = (const float*)d_in[3];
  const float* n2b  = (const float*)d_in[4];
  const float* mlnw[2] = {(const float*)d_in[5], (const float*)d_in[7]};
  const float* mlnb[2] = {(const float*)d_in[6], (const float*)d_in[8]};
  const float* fln1w = (const float*)d_in[9];
  const float* fln1b = (const float*)d_in[10];
  const float* fln2w = (const float*)d_in[11];
  const float* fln2b = (const float*)d_in[12];
  const float* inproj[2]  = {(const float*)d_in[13], (const float*)d_in[22]};
  const float* convw[2]   = {(const float*)d_in[14], (const float*)d_in[23]};
  const float* convb[2]   = {(const float*)d_in[15], (const float*)d_in[24]};
  const float* xproj[2]   = {(const float*)d_in[16], (const float*)d_in[25]};
  const float* dtw[2]     = {(const float*)d_in[17], (const float*)d_in[26]};
  const float* dtbp[2]    = {(const float*)d_in[18], (const float*)d_in[27]};
  const float* Alog[2]    = {(const float*)d_in[19], (const float*)d_in[28]};
  const float* Dp[2]      = {(const float*)d_in[20], (const float*)d_in[29]};
  const float* outproj[2] = {(const float*)d_in[21], (const float*)d_in[30]};
  const float* fpin  = (const float*)d_in[31];
  const float* fdw   = (const float*)d_in[32];
  const float* ffus  = (const float*)d_in[33];
  const float* fdwa  = (const float*)d_in[34];
  const float* fpout = (const float*)d_in[35];
  const float* fc1w  = (const float*)d_in[36];
  const float* fc1b  = (const float*)d_in[37];
  const float* fc2w  = (const float*)d_in[38];
  const float* fc2b  = (const float*)d_in[39];

  // workspace (floats), total 7,995,392 (= 32.0 MB)
  float* ws = (float*)d_ws;
  float* xmg = ws + 0;         // (4,4096,96)  -> later yall
  float* Vgb = ws + 1572864;   // (4,4096,48)
  float* xcg = ws + 2359296;   // (4,96,4096)  d-major -> later xpb (B,192,64,64)
  float* dtg = ws + 3932160;   // (4,96,4096)  d-major -> later xdb
  float* Bmg = ws + 5505024;   // (4,4096,16)
  float* Cmg = ws + 5767168;   // (4,4096,16)
  float* Pb  = ws + 6029312;   // (512,1536)   -> Hin in-place, later x1b
  float* Sb  = ws + 6815744;   // (512,1536)
  float* xmid= ws + 7602176;   // (B,48,64,64)
  float* yall = xmg;
  float* Hin  = Pb;
  float* xpb  = xcg;
  float* xdb  = dtg;
  float* x1b  = Pb;
  // conv-chain temporaries live in d_out (dead until the final k16 write):
  float* outf = (float*)d_out;
  float* ta   = outf;            // (B,48,32,32) = 98,304 floats
  float* tbuf = outf + 98304;    // (B,48,32,32)

  kA9<<<768,256,0,stream>>>(x, n1w, n1b,
      mlnw[0], mlnb[0], mlnw[1], mlnb[1], inproj[0], inproj[1],
      fc1w, fc1b, xmg, Vgb, ta);
  kB9<<<768,384,0,stream>>>(xmg,
      convw[0], convw[1], convb[0], convb[1], xproj[0], xproj[1],
      dtw[0], dtw[1], dtbp[0], dtbp[1], Alog[0], Alog[1],
      ta, fc2w, fc2b, fln1w, fln1b,
      xcg, dtg, Bmg, Cmg, Pb, Sb, tbuf);
  k4_comb  <<<96,64,0,stream>>>(Pb, Sb);
  k5_scan2 <<<512,384,0,stream>>>(dtg, xcg, Bmg, Cmg, Alog[0], Alog[1],
      Dp[0], Dp[1], inproj[0], inproj[1], Vgb, Hin, yall);
  k67_mid  <<<512,384,0,stream>>>(x, yall, yall + 786432, outproj[0], outproj[1],
      n2w, n2b, fpin, xmid, xpb);
  k13_dw   <<<1536,256,0,stream>>>(xpb, fdw, xdb, 192);
  k14_fus  <<<512,256,0,stream>>>(xdb, tbuf, fln2w, fln2b, ffus, x1b);
  k16_out  <<<512,384,0,stream>>>(x1b, xdb, fdwa, fpout, xmid, (float*)d_out);
}